// Round 7
// baseline (257.159 us; speedup 1.0000x reference)
//
#include <hip/hip_runtime.h>
#include <cstddef>

// Problem constants
constexpr int kB   = 2;
constexpr int kS   = 2048;
constexpr int kHID = 2048;
constexpr int kH   = 16;
constexpr int kHKV = 4;
constexpr int kD   = 128;
constexpr int kL   = 64;
constexpr int kTok = kB * kS;             // 4096 tokens
constexpr int kNQKV = kH * kD + 2 * kHKV * kD;  // 3072 fused QKV cols

typedef __attribute__((ext_vector_type(8))) short bf16x8;
typedef __attribute__((ext_vector_type(4))) float f32x4;

static __device__ __forceinline__ short f2bf(float f) {
  union { float f; unsigned u; } v{f};
  const unsigned r = (v.u + 0x7fff + ((v.u >> 16) & 1)) >> 16;
  return (short)r;
}

static __device__ __forceinline__ bf16x8 pack8(float4 a, float4 b) {
  bf16x8 r;
  r[0] = f2bf(a.x); r[1] = f2bf(a.y); r[2] = f2bf(a.z); r[3] = f2bf(a.w);
  r[4] = f2bf(b.x); r[5] = f2bf(b.y); r[6] = f2bf(b.z); r[7] = f2bf(b.w);
  return r;
}

// packed fp32x2 -> bf16x2 (exact RTN) — no builtin on gfx950, inline asm
static __device__ __forceinline__ unsigned cvt_pk_bf16(float lo, float hi) {
  unsigned r;
  asm("v_cvt_pk_bf16_f32 %0, %1, %2" : "=v"(r) : "v"(lo), "v"(hi));
  return r;
}

// async global->LDS, 16B per lane. LDS dest must be wave-uniform base + lane*16.
typedef __attribute__((address_space(3))) void       lds_void;
typedef __attribute__((address_space(1))) const void gm_void;
static __device__ __forceinline__ void gload16(const void* g, void* l) {
  __builtin_amdgcn_global_load_lds((gm_void*)g, (lds_void*)l, 16, 0, 0);
}

// ---------------------------------------------------------------------------
// fp32 -> bf16 elementwise (8 elems / thread)
// ---------------------------------------------------------------------------
__global__ __launch_bounds__(256) void cvt_bf16(const float* __restrict__ in,
                                                short* __restrict__ out, int n8) {
  const int i = blockIdx.x * 256 + threadIdx.x;
  if (i >= n8) return;
  const float4 a = *(const float4*)&in[i * 8];
  const float4 b = *(const float4*)&in[i * 8 + 4];
  *(bf16x8*)&out[i * 8] = pack8(a, b);
}

// ---------------------------------------------------------------------------
// Per-token RoPE cos/sin table
// ---------------------------------------------------------------------------
__global__ __launch_bounds__(256) void trig_table(const int* __restrict__ pos,
                                                  float* __restrict__ tbl) {
  const int idx = blockIdx.x * 256 + threadIdx.x;
  if (idx >= kTok * 64) return;
  const int i = idx & 63, t = idx >> 6;
  const float p = (float)pos[t];
  const float inv_freq = expf(-(float)i * (9.210340371976184f / 64.0f));
  const float ang = p * inv_freq;
  tbl[t * 128 + i]      = cosf(ang);
  tbl[t * 128 + 64 + i] = sinf(ang);
}

// ---------------------------------------------------------------------------
// Transpose + convert + scale: out[row_off+n][k] (bf16, ld) = in[rmap(k)][n]*scale
// ---------------------------------------------------------------------------
template <bool REMAP>
__global__ __launch_bounds__(256) void transpose_cvt(
    const float* __restrict__ in, short* __restrict__ out,
    int Nin, int out_ld, int row_off, float scale) {
  __shared__ float T[64][65];
  const int tid = threadIdx.x;
  const int k0 = blockIdx.y * 64, n0 = blockIdx.x * 64;
  const int rr = tid >> 4;
  const int cc = tid & 15;
#pragma unroll
  for (int ii = 0; ii < 4; ++ii) {
    const int kr = rr + ii * 16;
    int gr = k0 + kr;
    if (REMAP) gr = ((gr >> 6) << 7) + (gr & 63);
    const float4 v = *(const float4*)&in[(size_t)gr * Nin + n0 + cc * 4];
    T[kr][cc * 4 + 0] = v.x * scale; T[kr][cc * 4 + 1] = v.y * scale;
    T[kr][cc * 4 + 2] = v.z * scale; T[kr][cc * 4 + 3] = v.w * scale;
  }
  __syncthreads();
#pragma unroll
  for (int ii = 0; ii < 4; ++ii) {
    const int n = rr + ii * 16;
    const short4 s4 = make_short4(f2bf(T[cc * 4 + 0][n]), f2bf(T[cc * 4 + 1][n]),
                                  f2bf(T[cc * 4 + 2][n]), f2bf(T[cc * 4 + 3][n]));
    *(short4*)&out[(size_t)(row_off + n0 + n) * out_ld + k0 + cc * 4] = s4;
  }
}

// ---------------------------------------------------------------------------
// 256x256 8-phase bf16 MFMA GEMM (T2 swizzle + T3/T4 counted vmcnt + T5).
// C[M,N] = A[M,K] @ Bt[N,K]^T. 512 threads = 8 waves (2M x 4N); per-wave
// output 128x64. BK=64, LDS 128 KB (2-dbuf x [256][64] for A and B).
// Swizzle: 16B block index blk ^= (row&7) — applied on the gload16 global
// SOURCE (LDS stays linear: rule #21) and on the ds_read address.
// Counted vmcnt(2) once per K-tile; raw s_barrier (no implicit drain).
// Epilogue splits QKV by block column (block-uniform).
// ---------------------------------------------------------------------------
__global__ __launch_bounds__(512) void gemm_mfma8(
    const short* __restrict__ A, const short* __restrict__ Bt,
    float* __restrict__ C0, float* __restrict__ C1, float* __restrict__ C2,
    int M, int N, int K) {
  __shared__ short As[2][256 * 64];
  __shared__ short Bs[2][256 * 64];
  const int tid = threadIdx.x;
  const int lane = tid & 63, w = tid >> 6;
  const int lr = lane & 15, lk = lane >> 4;
  const int wm = w >> 2, wn = w & 3;
  const int row0 = blockIdx.y * 256, col0 = blockIdx.x * 256;
  const int NT = K >> 6;

  // stage one half-tile (128 rows x 64 k) of K-tile kt: h=0,1 -> A; 2,3 -> B
  auto stage_half = [&](int kt, int h) {
    const int b = kt & 1;
    const int k0 = kt * 64;
#pragma unroll
    for (int j = 0; j < 2; ++j) {
      const int idx = j * 512 + tid;
      const int row = idx >> 3, blk = idx & 7;
      const int gcol = k0 + ((blk ^ (row & 7)) << 3);   // inverse-swizzled src
      if (h < 2) {
        gload16(A + (size_t)(row0 + h * 128 + row) * K + gcol,
                &As[b][(h * 128 + row) * 64 + blk * 8]);
      } else {
        gload16(Bt + (size_t)(col0 + (h - 2) * 128 + row) * K + gcol,
                &Bs[b][((h - 2) * 128 + row) * 64 + blk * 8]);
      }
    }
  };

  f32x4 acc[8][4] = {};

  // prologue: stage K-tile 0 fully (4 half-tiles, 8 loads/thread)
#pragma unroll
  for (int h = 0; h < 4; ++h) stage_half(0, h);

  for (int t = 0; t < NT; ++t) {
    const int b = t & 1;
    bf16x8 a[4][2], bfr[2][2];
#pragma unroll
    for (int ph = 0; ph < 4; ++ph) {          // quadrant (qm,qn)
      const int qm = ph >> 1, qn = ph & 1;
      if (t + 1 < NT) stage_half(t + 1, ph);  // 1 half-tile prefetch / phase
      if (ph == 0) {
        if (t + 1 < NT) asm volatile("s_waitcnt vmcnt(2)" ::: "memory");
        else            asm volatile("s_waitcnt vmcnt(0)" ::: "memory");
        __builtin_amdgcn_s_barrier();         // tile-t data ready, all waves
      }
      if (qn == 0) {                          // A-frags reused across qn
#pragma unroll
        for (int j = 0; j < 4; ++j) {
          const int row = wm * 128 + (qm * 4 + j) * 16 + lr;
#pragma unroll
          for (int ch = 0; ch < 2; ++ch) {
            const int blk = (ch * 4 + lk) ^ (row & 7);
            a[j][ch] = *(const bf16x8*)&As[b][row * 64 + blk * 8];
          }
        }
      }
#pragma unroll
      for (int n = 0; n < 2; ++n) {
        const int row = wn * 64 + (qn * 2 + n) * 16 + lr;
#pragma unroll
        for (int ch = 0; ch < 2; ++ch) {
          const int blk = (ch * 4 + lk) ^ (row & 7);
          bfr[n][ch] = *(const bf16x8*)&Bs[b][row * 64 + blk * 8];
        }
      }
      __builtin_amdgcn_s_barrier();           // phase align
      __builtin_amdgcn_s_setprio(1);
#pragma unroll
      for (int j = 0; j < 4; ++j)
#pragma unroll
        for (int n = 0; n < 2; ++n)
#pragma unroll
          for (int ch = 0; ch < 2; ++ch)
            acc[qm * 4 + j][qn * 2 + n] = __builtin_amdgcn_mfma_f32_16x16x32_bf16(
                a[j][ch], bfr[n][ch], acc[qm * 4 + j][qn * 2 + n], 0, 0, 0);
      __builtin_amdgcn_s_setprio(0);
      __builtin_amdgcn_s_barrier();           // phase end
    }
  }

  // epilogue: QKV split by block col (block-uniform)
  float* dst; int ld, cb;
  if (col0 < 2048)      { dst = C0; ld = 2048; cb = col0; }
  else if (col0 < 2560) { dst = C1; ld = 512;  cb = col0 - 2048; }
  else                  { dst = C2; ld = 512;  cb = col0 - 2560; }
  const int crow0 = row0 + wm * 128 + lk * 4;
  const int ccol0 = cb + wn * 64 + lr;
#pragma unroll
  for (int mf = 0; mf < 8; ++mf)
#pragma unroll
    for (int nf = 0; nf < 4; ++nf)
#pragma unroll
      for (int r = 0; r < 4; ++r)
        dst[(size_t)(crow0 + mf * 16 + r) * ld + ccol0 + nf * 16] = acc[mf][nf][r];
}

// ---------------------------------------------------------------------------
// bf16 MFMA GEMM, m97 structure (kept for the K=1024 output GEMM).
// ---------------------------------------------------------------------------
__global__ __launch_bounds__(256) void gemm_mfma(
    const short* __restrict__ A, const short* __restrict__ Bt,
    float* __restrict__ C0, int M, int N, int K) {
  __shared__ short As[128 * 32];
  __shared__ short Bs[128 * 32];
  const int tid = threadIdx.x;
  const int l = tid & 63, w = tid >> 6;
  const int lr = l & 15, lk = l >> 4;
  const int wm = w >> 1, wn = w & 1;
  const int row0 = blockIdx.y * 128, col0 = blockIdx.x * 128;

  f32x4 acc[4][4] = {};

  for (int k0 = 0; k0 < K; k0 += 32) {
    __syncthreads();
#pragma unroll
    for (int j = 0; j < 2; ++j) {
      const int idx = j * 256 + tid;
      const int r = idx >> 2, c = idx & 3;
      gload16(A  + (size_t)(row0 + r) * K + k0 + c * 8, &As[idx * 8]);
      gload16(Bt + (size_t)(col0 + r) * K + k0 + c * 8, &Bs[idx * 8]);
    }
    __syncthreads();
    bf16x8 af[4], bfr[4];
#pragma unroll
    for (int m = 0; m < 4; ++m)
      af[m] = *(const bf16x8*)&As[(wm * 64 + m * 16 + lr) * 32 + lk * 8];
#pragma unroll
    for (int n = 0; n < 4; ++n)
      bfr[n] = *(const bf16x8*)&Bs[(wn * 64 + n * 16 + lr) * 32 + lk * 8];
#pragma unroll
    for (int m = 0; m < 4; ++m)
#pragma unroll
      for (int n = 0; n < 4; ++n)
        acc[m][n] = __builtin_amdgcn_mfma_f32_16x16x32_bf16(af[m], bfr[n],
                                                            acc[m][n], 0, 0, 0);
  }

  const int crow0 = row0 + wm * 64 + lk * 4;
  const int ccol0 = col0 + wn * 64 + lr;
#pragma unroll
  for (int m = 0; m < 4; ++m)
#pragma unroll
    for (int n = 0; n < 4; ++n)
#pragma unroll
      for (int rr = 0; rr < 4; ++rr)
        C0[(size_t)(crow0 + m * 16 + rr) * N + ccol0 + n * 16] = acc[m][n][rr];
}

// ---------------------------------------------------------------------------
// Fused RoPE + latent projection (MFMA). See R4 comments.
// ---------------------------------------------------------------------------
template <bool ROPE, bool TR>
__global__ __launch_bounds__(256) void rope_latent(
    const float* __restrict__ in, const short* __restrict__ WT,
    const float* __restrict__ tbl, short* __restrict__ out, int nh) {
  __shared__ short Tw[4][1280];
  const int tid = threadIdx.x;
  const int lane = tid & 63;
  const int w = tid >> 6;
  const int lr = lane & 15;
  const int lk = lane >> 4;
  const int bh = blockIdx.y;
  const int b = bh / nh, h = bh % nh;
  const int s0 = blockIdx.x * 64;
  const int srow = s0 + w * 16 + lr;
  const int tok = b * kS + srow;

  const float* ip = in + ((size_t)tok * nh + h) * kD + lk * 8;
  float4 a[4][2];
#pragma unroll
  for (int ch = 0; ch < 4; ++ch) {
    a[ch][0] = *(const float4*)(ip + ch * 32);
    a[ch][1] = *(const float4*)(ip + ch * 32 + 4);
  }
  if (ROPE) {
    const float* tb = tbl + (size_t)tok * 128;
    float4 c0[2], c1[2], sn0[2], sn1[2];
    c0[0]  = *(const float4*)(tb + lk * 8);        c0[1]  = *(const float4*)(tb + lk * 8 + 4);
    c1[0]  = *(const float4*)(tb + 32 + lk * 8);   c1[1]  = *(const float4*)(tb + 32 + lk * 8 + 4);
    sn0[0] = *(const float4*)(tb + 64 + lk * 8);   sn0[1] = *(const float4*)(tb + 64 + lk * 8 + 4);
    sn1[0] = *(const float4*)(tb + 96 + lk * 8);   sn1[1] = *(const float4*)(tb + 96 + lk * 8 + 4);
#pragma unroll
    for (int q = 0; q < 2; ++q) {
      const float4 t0 = a[0][q], t1 = a[1][q], t2 = a[2][q], t3 = a[3][q];
      a[0][q].x = t0.x * c0[q].x - t2.x * sn0[q].x;
      a[0][q].y = t0.y * c0[q].y - t2.y * sn0[q].y;
      a[0][q].z = t0.z * c0[q].z - t2.z * sn0[q].z;
      a[0][q].w = t0.w * c0[q].w - t2.w * sn0[q].w;
      a[2][q].x = t2.x * c0[q].x + t0.x * sn0[q].x;
      a[2][q].y = t2.y * c0[q].y + t0.y * sn0[q].y;
      a[2][q].z = t2.z * c0[q].z + t0.z * sn0[q].z;
      a[2][q].w = t2.w * c0[q].w + t0.w * sn0[q].w;
      a[1][q].x = t1.x * c1[q].x - t3.x * sn1[q].x;
      a[1][q].y = t1.y * c1[q].y - t3.y * sn1[q].y;
      a[1][q].z = t1.z * c1[q].z - t3.z * sn1[q].z;
      a[1][q].w = t1.w * c1[q].w - t3.w * sn1[q].w;
      a[3][q].x = t3.x * c1[q].x + t1.x * sn1[q].x;
      a[3][q].y = t3.y * c1[q].y + t1.y * sn1[q].y;
      a[3][q].z = t3.z * c1[q].z + t1.z * sn1[q].z;
      a[3][q].w = t3.w * c1[q].w + t1.w * sn1[q].w;
    }
  }
  bf16x8 af[4];
#pragma unroll
  for (int ch = 0; ch < 4; ++ch) af[ch] = pack8(a[ch][0], a[ch][1]);

  f32x4 acc[4] = {};
#pragma unroll
  for (int cb = 0; cb < 4; ++cb) {
#pragma unroll
    for (int ch = 0; ch < 4; ++ch) {
      const bf16x8 bfrag =
          *(const bf16x8*)&WT[(size_t)(cb * 16 + lr) * kD + ch * 32 + lk * 8];
      acc[cb] = __builtin_amdgcn_mfma_f32_16x16x32_bf16(af[ch], bfrag,
                                                        acc[cb], 0, 0, 0);
    }
  }

  short* T = Tw[w];
  if (!TR) {
#pragma unroll
    for (int cb = 0; cb < 4; ++cb)
#pragma unroll
      for (int r = 0; r < 4; ++r)
        T[(lk * 4 + r) * 72 + cb * 16 + lr] = f2bf(acc[cb][r]);
    asm volatile("s_waitcnt lgkmcnt(0)" ::: "memory");
#pragma unroll
    for (int it = 0; it < 2; ++it) {
      const int idx = it * 64 + lane;
      const int row = idx >> 3, c8 = (idx & 7) << 3;
      *(bf16x8*)&out[((size_t)bh * kS + s0 + w * 16 + row) * kL + c8] =
          *(const bf16x8*)&T[row * 72 + c8];
    }
  } else {
#pragma unroll
    for (int cb = 0; cb < 4; ++cb)
#pragma unroll
      for (int r = 0; r < 4; ++r)
        T[(cb * 16 + lr) * 20 + lk * 4 + r] = f2bf(acc[cb][r]);
    asm volatile("s_waitcnt lgkmcnt(0)" ::: "memory");
    const size_t orow = ((size_t)bh * kL + lane) * kS + s0 + w * 16;
#pragma unroll
    for (int c = 0; c < 4; ++c)
      *(short4*)&out[orow + c * 4] = *(const short4*)&T[lane * 20 + c * 4];
  }
}

// ---------------------------------------------------------------------------
// MFMA flash attention, causal, bf16 in/out (fp32 accumulate).
// Block = 512 threads (8 waves) = 128 q rows of one (b,h).
// grid = (B*H, S/128) with bx remap pairing heavy+light blocks per CU.
// T13 defer-max (THR=8) skips the O-rescale when max growth is small.
// ---------------------------------------------------------------------------
__global__ __launch_bounds__(512) void flash_attn_mfma(
    const short* __restrict__ ql, const short* __restrict__ kl,
    const short* __restrict__ vlT, short* __restrict__ attn_out) {
  constexpr int LDK = 72;
  __shared__ short Kt[64 * LDK];
  __shared__ short Vt[64 * LDK];               // row = latent l, col = key
  __shared__ short Pt[128 * LDK];

  const int tid = threadIdx.x;
  const int lane = tid & 63;
  const int w = tid >> 6;
  const int lr = lane & 15;
  const int lk = lane >> 4;
  const int bid = blockIdx.y;
  const int bx = (bid < 8) ? (2 * bid) : (31 - 2 * bid);   // load-balance remap
  const int q0 = bx * 128;
  const int bh = blockIdx.x;
  const int b = bh >> 4, h = bh & 15;
  const int hk = h >> 2;
  const int wrow = q0 + w * 16;

  const short* qrow = ql + ((size_t)bh * kS + wrow + lr) * kL;
  bf16x8 qf[2];
  qf[0] = *(const bf16x8*)(qrow + lk * 8);
  qf[1] = *(const bf16x8*)(qrow + 32 + lk * 8);

  f32x4 Of[4] = {};
  float m_r[4], l_r[4];
#pragma unroll
  for (int r = 0; r < 4; ++r) { m_r[r] = -3.0e38f; l_r[r] = 0.f; }

  const size_t kbase = (size_t)(b * kHKV + hk) * kS * kL;
  const size_t vbase = (size_t)(b * kHKV + hk) * kL * kS;
  const int ntiles = q0 / 64 + 2;
  const int sr = tid >> 3, sc8 = (tid & 7) << 3;

  for (int t = 0; t < ntiles; ++t) {
    const int j0 = t * 64;
    __syncthreads();
    *(bf16x8*)&Kt[sr * LDK + sc8] =
        *(const bf16x8*)(kl + kbase + (size_t)(j0 + sr) * kL + sc8);
    *(bf16x8*)&Vt[sr * LDK + sc8] =
        *(const bf16x8*)(vlT + vbase + (size_t)sr * kS + j0 + sc8);
    __syncthreads();

    if (j0 > wrow + 15) continue;

    f32x4 Sf[4];
    __builtin_amdgcn_s_setprio(1);
#pragma unroll
    for (int cb = 0; cb < 4; ++cb) {
      f32x4 acc = {};
#pragma unroll
      for (int ch = 0; ch < 2; ++ch) {
        const bf16x8 kf = *(const bf16x8*)&Kt[(cb * 16 + lr) * LDK + ch * 32 + lk * 8];
        acc = __builtin_amdgcn_mfma_f32_16x16x32_bf16(qf[ch], kf, acc, 0, 0, 0);
      }
      Sf[cb] = acc;
    }
    __builtin_amdgcn_s_setprio(0);

    const bool diag = (j0 + 63 > wrow);
    float mt[4] = {-3.0e38f, -3.0e38f, -3.0e38f, -3.0e38f};
#pragma unroll
    for (int cb = 0; cb < 4; ++cb)
#pragma unroll
      for (int r = 0; r < 4; ++r) {
        float s = Sf[cb][r];
        if (diag && (j0 + cb * 16 + lr) > (wrow + lk * 4 + r)) s = -3.0e38f;
        Sf[cb][r] = s;
        mt[r] = fmaxf(mt[r], s);
      }
#pragma unroll
    for (int d = 1; d < 16; d <<= 1)
#pragma unroll
      for (int r = 0; r < 4; ++r) mt[r] = fmaxf(mt[r], __shfl_xor(mt[r], d));

    const bool need = (mt[0] > m_r[0] + 8.f) || (mt[1] > m_r[1] + 8.f) ||
                      (mt[2] > m_r[2] + 8.f) || (mt[3] > m_r[3] + 8.f);
    const bool resc = __any((int)need);
    float corr[4] = {1.f, 1.f, 1.f, 1.f};
    if (resc) {
#pragma unroll
      for (int r = 0; r < 4; ++r) {
        const float mnew = fmaxf(m_r[r], mt[r]);
        corr[r] = __expf(m_r[r] - mnew);
        m_r[r] = mnew;
        l_r[r] *= corr[r];
      }
    }
#pragma unroll
    for (int cb = 0; cb < 4; ++cb) {
      const float p0 = __expf(Sf[cb][0] - m_r[0]);
      const float p1 = __expf(Sf[cb][1] - m_r[1]);
      const float p2 = __expf(Sf[cb][2] - m_r[2]);
      const float p3 = __expf(Sf[cb][3] - m_r[3]);
      l_r[0] += p0; l_r[1] += p1; l_r[2] += p2; l_r[3] += p3;
      const unsigned pk01 = cvt_pk_bf16(p0, p1);
      const unsigned pk23 = cvt_pk_bf16(p2, p3);
      short* prow = &Pt[(w * 16 + lk * 4) * LDK + cb * 16 + lr];
      prow[0 * LDK] = (short)(pk01 & 0xffff);
      prow[1 * LDK] = (short)(pk01 >> 16);
      prow[2 * LDK] = (short)(pk23 & 0xffff);
      prow[3 * LDK] = (short)(pk23 >> 16);
    }
    asm volatile("s_waitcnt lgkmcnt(0)" ::: "memory");

    __builtin_amdgcn_s_setprio(1);
#pragma unroll
    for (int cb = 0; cb < 4; ++cb) {
      f32x4 acc = Of[cb];
      if (resc) {
#pragma unroll
        for (int r = 0; r < 4; ++r) acc[r] *= corr[r];
      }
#pragma unroll
      for (int ch = 0; ch < 2; ++ch) {
        const bf16x8 pf = *(const bf16x8*)&Pt[(w * 16 + lr) * LDK + ch * 32 + lk * 8];
        const bf16x8 vf = *(const bf16x8*)&Vt[(cb * 16 + lr) * LDK + ch * 32 + lk * 8];
        acc = __builtin_amdgcn_mfma_f32_16x16x32_bf16(pf, vf, acc, 0, 0, 0);
      }
      Of[cb] = acc;
    }
    __builtin_amdgcn_s_setprio(0);
  }

#pragma unroll
  for (int d = 1; d < 16; d <<= 1)
#pragma unroll
    for (int r = 0; r < 4; ++r) l_r[r] += __shfl_xor(l_r[r], d);

#pragma unroll
  for (int r = 0; r < 4; ++r) {
    const float inv = 1.f / l_r[r];
    const size_t row = (size_t)(b * kS + wrow + lk * 4 + r) * (kH * kL);
#pragma unroll
    for (int cb = 0; cb < 4; ++cb)
      attn_out[row + h * kL + cb * 16 + lr] = f2bf(Of[cb][r] * inv);
  }
}

// ---------------------------------------------------------------------------
extern "C" void kernel_launch(void* const* d_in, const int* in_sizes, int n_in,
                              void* d_out, int out_size, void* d_ws, size_t ws_size,
                              hipStream_t stream) {
  const float* x    = (const float*)d_in[0];
  const int*   pos  = (const int*)d_in[1];
  const float* Wq   = (const float*)d_in[3];
  const float* Wk   = (const float*)d_in[4];
  const float* Wv   = (const float*)d_in[5];
  const float* Wql  = (const float*)d_in[6];
  const float* Wkl  = (const float*)d_in[7];
  const float* Wvl  = (const float*)d_in[8];
  const float* Wo   = (const float*)d_in[9];
  float* out = (float*)d_out;

  // Workspace carve
  char* p = (char*)d_ws;
  short* x_bf  = (short*)p; p += (size_t)kTok * kHID * 2;        // 16 MB
  short* Wqkv  = (short*)p; p += (size_t)kNQKV * kHID * 2;       // 12.6 MB
  short* WoT   = (short*)p; p += (size_t)kHID * (kH * kL) * 2;   // 4 MB
  short* WqlT  = (short*)p; p += (size_t)kL * kD * 2;            // 16 KB
  short* WklT  = (short*)p; p += (size_t)kL * kD * 2;
  short* WvlT  = (short*)p; p += (size_t)kL * kD * 2;
  float* tbl   = (float*)p; p += (size_t)kTok * 128 * 4;         // 2 MB
  float* k_buf = (float*)p; p += (size_t)kTok * kHKV * kD * 4;   // 8 MB
  float* v_buf = (float*)p; p += (size_t)kTok * kHKV * kD * 4;   // 8 MB
  short* q_l   = (short*)p; p += (size_t)kB * kH * kS * kL * 2;  // 8 MB
  short* k_l   = (short*)p; p += (size_t)kB * kHKV * kS * kL * 2;
  short* v_lT  = (short*)p; p += (size_t)kB * kHKV * kS * kL * 2;
  short* attn  = (short*)p;                                      // 8 MB
  float* q_buf = (float*)d_out;   // scratch until final GEMM

  // 0) dtype prep
  cvt_bf16<<<kTok * kHID / 8 / 256, 256, 0, stream>>>(x, x_bf, kTok * kHID / 8);
  trig_table<<<kTok * 64 / 256, 256, 0, stream>>>(pos, tbl);
  transpose_cvt<false><<<dim3(kH * kD / 64, kHID / 64), 256, 0, stream>>>(
      Wq, Wqkv, kH * kD, kHID, 0, 1.0f);
  transpose_cvt<false><<<dim3(kHKV * kD / 64, kHID / 64), 256, 0, stream>>>(
      Wk, Wqkv, kHKV * kD, kHID, kH * kD, 1.0f);
  transpose_cvt<false><<<dim3(kHKV * kD / 64, kHID / 64), 256, 0, stream>>>(
      Wv, Wqkv, kHKV * kD, kHID, kH * kD + kHKV * kD, 1.0f);
  transpose_cvt<true><<<dim3(kHID / 64, (kH * kL) / 64), 256, 0, stream>>>(
      Wo, WoT, kHID, kH * kL, 0, 1.0f);
  transpose_cvt<false><<<dim3(1, kD / 64), 256, 0, stream>>>(
      Wql, WqlT, kL, kD, 0, 0.125f);            // fold 1/sqrt(L)
  transpose_cvt<false><<<dim3(1, kD / 64), 256, 0, stream>>>(
      Wkl, WklT, kL, kD, 0, 1.0f);
  transpose_cvt<false><<<dim3(1, kD / 64), 256, 0, stream>>>(
      Wvl, WvlT, kL, kD, 0, 1.0f);

  // 1) Fused QKV projection — 256² 8-phase MFMA GEMM
  gemm_mfma8<<<dim3(kNQKV / 256, kTok / 256), 512, 0, stream>>>(
      x_bf, Wqkv, q_buf, k_buf, v_buf, kTok, kNQKV, kHID);

  // 2) Fused RoPE + latent projections (MFMA)
  rope_latent<true,  false><<<dim3(kS / 64, kB * kH), 256, 0, stream>>>(
      q_buf, WqlT, tbl, q_l, kH);
  rope_latent<true,  false><<<dim3(kS / 64, kB * kHKV), 256, 0, stream>>>(
      k_buf, WklT, tbl, k_l, kHKV);
  rope_latent<false, true><<<dim3(kS / 64, kB * kHKV), 256, 0, stream>>>(
      v_buf, WvlT, tbl, v_lT, kHKV);

  // 3) MFMA flash attention (128 q-rows/block, 8 waves, balanced grid)
  flash_attn_mfma<<<dim3(kB * kH, kS / 128), 512, 0, stream>>>(
      q_l, k_l, v_lT, attn);

  // 4) Output GEMM (MFMA, m97): [4096x1024] @ WoT^T -> d_out
  gemm_mfma<<<dim3(kHID / 128, kTok / 128), 256, 0, stream>>>(
      attn, WoT, out, kTok, kHID, kH * kL);
}

// Round 8
// 228.685 us; speedup vs baseline: 1.1245x; 1.1245x over previous
//
#include <hip/hip_runtime.h>
#include <cstddef>

// Problem constants
constexpr int kB   = 2;
constexpr int kS   = 2048;
constexpr int kHID = 2048;
constexpr int kH   = 16;
constexpr int kHKV = 4;
constexpr int kD   = 128;
constexpr int kL   = 64;
constexpr int kTok = kB * kS;             // 4096 tokens
constexpr int kNQKV = kH * kD + 2 * kHKV * kD;  // 3072 fused QKV cols

typedef __attribute__((ext_vector_type(8))) short bf16x8;
typedef __attribute__((ext_vector_type(4))) float f32x4;

static __device__ __forceinline__ short f2bf(float f) {
  union { float f; unsigned u; } v{f};
  const unsigned r = (v.u + 0x7fff + ((v.u >> 16) & 1)) >> 16;
  return (short)r;
}
static __device__ __forceinline__ float bf2f(short s) {
  union { unsigned u; float f; } v;
  v.u = ((unsigned)(unsigned short)s) << 16;
  return v.f;
}

static __device__ __forceinline__ bf16x8 pack8(float4 a, float4 b) {
  bf16x8 r;
  r[0] = f2bf(a.x); r[1] = f2bf(a.y); r[2] = f2bf(a.z); r[3] = f2bf(a.w);
  r[4] = f2bf(b.x); r[5] = f2bf(b.y); r[6] = f2bf(b.z); r[7] = f2bf(b.w);
  return r;
}

// packed fp32x2 -> bf16x2 (exact RTN) — no builtin on gfx950, inline asm
static __device__ __forceinline__ unsigned cvt_pk_bf16(float lo, float hi) {
  unsigned r;
  asm("v_cvt_pk_bf16_f32 %0, %1, %2" : "=v"(r) : "v"(lo), "v"(hi));
  return r;
}

// async global->LDS, 16B per lane. LDS dest must be wave-uniform base + lane*16.
typedef __attribute__((address_space(3))) void       lds_void;
typedef __attribute__((address_space(1))) const void gm_void;
static __device__ __forceinline__ void gload16(const void* g, void* l) {
  __builtin_amdgcn_global_load_lds((gm_void*)g, (lds_void*)l, 16, 0, 0);
}

// T1: bijective XCD-aware block swizzle (requires nwg % 8 == 0)
static __device__ __forceinline__ int2 xcd_swz(int nx, int ny) {
  int wg = blockIdx.y * nx + blockIdx.x;
  const int cpx = (nx * ny) >> 3;
  wg = (wg & 7) * cpx + (wg >> 3);
  int2 r; r.x = wg % nx; r.y = wg / nx;
  return r;
}

// ---------------------------------------------------------------------------
// fp32 -> bf16 elementwise (8 elems / thread)
// ---------------------------------------------------------------------------
__global__ __launch_bounds__(256) void cvt_bf16(const float* __restrict__ in,
                                                short* __restrict__ out, int n8) {
  const int i = blockIdx.x * 256 + threadIdx.x;
  if (i >= n8) return;
  const float4 a = *(const float4*)&in[i * 8];
  const float4 b = *(const float4*)&in[i * 8 + 4];
  *(bf16x8*)&out[i * 8] = pack8(a, b);
}

// ---------------------------------------------------------------------------
// Per-token RoPE cos/sin table
// ---------------------------------------------------------------------------
__global__ __launch_bounds__(256) void trig_table(const int* __restrict__ pos,
                                                  float* __restrict__ tbl) {
  const int idx = blockIdx.x * 256 + threadIdx.x;
  if (idx >= kTok * 64) return;
  const int i = idx & 63, t = idx >> 6;
  const float p = (float)pos[t];
  const float inv_freq = expf(-(float)i * (9.210340371976184f / 64.0f));
  const float ang = p * inv_freq;
  tbl[t * 128 + i]      = cosf(ang);
  tbl[t * 128 + 64 + i] = sinf(ang);
}

// ---------------------------------------------------------------------------
// Transpose + convert + scale: out[row_off+n][k] (bf16, ld) = in[rmap(k)][n]*scale
// ---------------------------------------------------------------------------
template <bool REMAP>
__global__ __launch_bounds__(256) void transpose_cvt(
    const float* __restrict__ in, short* __restrict__ out,
    int Nin, int out_ld, int row_off, float scale) {
  __shared__ float T[64][65];
  const int tid = threadIdx.x;
  const int k0 = blockIdx.y * 64, n0 = blockIdx.x * 64;
  const int rr = tid >> 4;
  const int cc = tid & 15;
#pragma unroll
  for (int ii = 0; ii < 4; ++ii) {
    const int kr = rr + ii * 16;
    int gr = k0 + kr;
    if (REMAP) gr = ((gr >> 6) << 7) + (gr & 63);
    const float4 v = *(const float4*)&in[(size_t)gr * Nin + n0 + cc * 4];
    T[kr][cc * 4 + 0] = v.x * scale; T[kr][cc * 4 + 1] = v.y * scale;
    T[kr][cc * 4 + 2] = v.z * scale; T[kr][cc * 4 + 3] = v.w * scale;
  }
  __syncthreads();
#pragma unroll
  for (int ii = 0; ii < 4; ++ii) {
    const int n = rr + ii * 16;
    const short4 s4 = make_short4(f2bf(T[cc * 4 + 0][n]), f2bf(T[cc * 4 + 1][n]),
                                  f2bf(T[cc * 4 + 2][n]), f2bf(T[cc * 4 + 3][n]));
    *(short4*)&out[(size_t)(row_off + n0 + n) * out_ld + k0 + cc * 4] = s4;
  }
}

// ---------------------------------------------------------------------------
// bf16 MFMA GEMM (m97): QKV variant — bf16 output split q/k/v by block col.
// C[M,N] = A[M,K] @ Bt[N,K]^T. 128x128 tile, BK=32, 256 threads.
// ---------------------------------------------------------------------------
__global__ __launch_bounds__(256) void gemm_qkv(
    const short* __restrict__ A, const short* __restrict__ Bt,
    short* __restrict__ C0, short* __restrict__ C1, short* __restrict__ C2,
    int K) {
  __shared__ short As[128 * 32];
  __shared__ short Bs[128 * 32];
  const int tid = threadIdx.x;
  const int l = tid & 63, w = tid >> 6;
  const int lr = l & 15, lk = l >> 4;
  const int wm = w >> 1, wn = w & 1;
  const int2 sw = xcd_swz(kNQKV / 128, kTok / 128);   // 24 x 32 = 768 blocks
  const int row0 = sw.y * 128, col0 = sw.x * 128;

  f32x4 acc[4][4] = {};

  for (int k0 = 0; k0 < K; k0 += 32) {
    __syncthreads();
#pragma unroll
    for (int j = 0; j < 2; ++j) {
      const int idx = j * 256 + tid;
      const int r = idx >> 2, c = idx & 3;
      gload16(A  + (size_t)(row0 + r) * K + k0 + c * 8, &As[idx * 8]);
      gload16(Bt + (size_t)(col0 + r) * K + k0 + c * 8, &Bs[idx * 8]);
    }
    __syncthreads();
    bf16x8 af[4], bfr[4];
#pragma unroll
    for (int m = 0; m < 4; ++m)
      af[m] = *(const bf16x8*)&As[(wm * 64 + m * 16 + lr) * 32 + lk * 8];
#pragma unroll
    for (int n = 0; n < 4; ++n)
      bfr[n] = *(const bf16x8*)&Bs[(wn * 64 + n * 16 + lr) * 32 + lk * 8];
#pragma unroll
    for (int m = 0; m < 4; ++m)
#pragma unroll
      for (int n = 0; n < 4; ++n)
        acc[m][n] = __builtin_amdgcn_mfma_f32_16x16x32_bf16(af[m], bfr[n],
                                                            acc[m][n], 0, 0, 0);
  }

  short* dst; int ld, cb;
  if (col0 < 2048)      { dst = C0; ld = 2048; cb = col0; }
  else if (col0 < 2560) { dst = C1; ld = 512;  cb = col0 - 2048; }
  else                  { dst = C2; ld = 512;  cb = col0 - 2560; }
  const int crow0 = row0 + wm * 64 + lk * 4;
  const int ccol0 = cb + wn * 64 + lr;
#pragma unroll
  for (int m = 0; m < 4; ++m)
#pragma unroll
    for (int n = 0; n < 4; ++n)
#pragma unroll
      for (int rr = 0; rr < 4; ++rr)
        dst[(size_t)(crow0 + m * 16 + rr) * ld + ccol0 + n * 16] =
            f2bf(acc[m][n][rr]);
}

// ---------------------------------------------------------------------------
// bf16 MFMA GEMM (m97): fp32-output variant for the final K=1024 GEMM.
// ---------------------------------------------------------------------------
__global__ __launch_bounds__(256) void gemm_mfma(
    const short* __restrict__ A, const short* __restrict__ Bt,
    float* __restrict__ C0, int M, int N, int K) {
  __shared__ short As[128 * 32];
  __shared__ short Bs[128 * 32];
  const int tid = threadIdx.x;
  const int l = tid & 63, w = tid >> 6;
  const int lr = l & 15, lk = l >> 4;
  const int wm = w >> 1, wn = w & 1;
  const int2 sw = xcd_swz(N / 128, M / 128);
  const int row0 = sw.y * 128, col0 = sw.x * 128;

  f32x4 acc[4][4] = {};

  for (int k0 = 0; k0 < K; k0 += 32) {
    __syncthreads();
#pragma unroll
    for (int j = 0; j < 2; ++j) {
      const int idx = j * 256 + tid;
      const int r = idx >> 2, c = idx & 3;
      gload16(A  + (size_t)(row0 + r) * K + k0 + c * 8, &As[idx * 8]);
      gload16(Bt + (size_t)(col0 + r) * K + k0 + c * 8, &Bs[idx * 8]);
    }
    __syncthreads();
    bf16x8 af[4], bfr[4];
#pragma unroll
    for (int m = 0; m < 4; ++m)
      af[m] = *(const bf16x8*)&As[(wm * 64 + m * 16 + lr) * 32 + lk * 8];
#pragma unroll
    for (int n = 0; n < 4; ++n)
      bfr[n] = *(const bf16x8*)&Bs[(wn * 64 + n * 16 + lr) * 32 + lk * 8];
#pragma unroll
    for (int m = 0; m < 4; ++m)
#pragma unroll
      for (int n = 0; n < 4; ++n)
        acc[m][n] = __builtin_amdgcn_mfma_f32_16x16x32_bf16(af[m], bfr[n],
                                                            acc[m][n], 0, 0, 0);
  }

  const int crow0 = row0 + wm * 64 + lk * 4;
  const int ccol0 = col0 + wn * 64 + lr;
#pragma unroll
  for (int m = 0; m < 4; ++m)
#pragma unroll
    for (int n = 0; n < 4; ++n)
#pragma unroll
      for (int rr = 0; rr < 4; ++rr)
        C0[(size_t)(crow0 + m * 16 + rr) * N + ccol0 + n * 16] = acc[m][n][rr];
}

// ---------------------------------------------------------------------------
// Fused RoPE + latent projection (MFMA), bf16 input, all three tensors in
// one dispatch. grid = (kS/64, 48): y<32 -> q (ROPE), y<40 -> k (ROPE),
// y>=40 -> v (no RoPE, transposed [l][S] output). Branches block-uniform.
// ---------------------------------------------------------------------------
__global__ __launch_bounds__(256) void rope_latent_all(
    const short* __restrict__ qb, const short* __restrict__ kb,
    const short* __restrict__ vb, const short* __restrict__ WqlT,
    const short* __restrict__ WklT, const short* __restrict__ WvlT,
    const float* __restrict__ tbl, short* __restrict__ q_l,
    short* __restrict__ k_l, short* __restrict__ v_lT) {
  __shared__ short Tw[4][1280];
  const int yz = blockIdx.y;
  const short* in; const short* WT; short* out; int nh; bool ROPE, TR;
  int bh;
  if (yz < 32)      { in = qb; WT = WqlT; out = q_l;  nh = kH;   ROPE = true;  TR = false; bh = yz; }
  else if (yz < 40) { in = kb; WT = WklT; out = k_l;  nh = kHKV; ROPE = true;  TR = false; bh = yz - 32; }
  else              { in = vb; WT = WvlT; out = v_lT; nh = kHKV; ROPE = false; TR = true;  bh = yz - 40; }

  const int tid = threadIdx.x;
  const int lane = tid & 63;
  const int w = tid >> 6;
  const int lr = lane & 15;
  const int lk = lane >> 4;
  const int b = bh / nh, h = bh % nh;
  const int s0 = blockIdx.x * 64;
  const int srow = s0 + w * 16 + lr;
  const int tok = b * kS + srow;

  const short* ip = in + ((size_t)tok * nh + h) * kD + lk * 8;
  bf16x8 raw[4];
#pragma unroll
  for (int ch = 0; ch < 4; ++ch) raw[ch] = *(const bf16x8*)(ip + ch * 32);

  bf16x8 af[4];
  if (ROPE) {
    float a[4][8];
#pragma unroll
    for (int ch = 0; ch < 4; ++ch)
#pragma unroll
      for (int i = 0; i < 8; ++i) a[ch][i] = bf2f(raw[ch][i]);
    const float* tb = tbl + (size_t)tok * 128;
    float c[2][8], sn[2][8];
#pragma unroll
    for (int g = 0; g < 2; ++g) {
      const float4 cA = *(const float4*)(tb + g * 32 + lk * 8);
      const float4 cB = *(const float4*)(tb + g * 32 + lk * 8 + 4);
      const float4 sA = *(const float4*)(tb + 64 + g * 32 + lk * 8);
      const float4 sB = *(const float4*)(tb + 64 + g * 32 + lk * 8 + 4);
      c[g][0] = cA.x; c[g][1] = cA.y; c[g][2] = cA.z; c[g][3] = cA.w;
      c[g][4] = cB.x; c[g][5] = cB.y; c[g][6] = cB.z; c[g][7] = cB.w;
      sn[g][0] = sA.x; sn[g][1] = sA.y; sn[g][2] = sA.z; sn[g][3] = sA.w;
      sn[g][4] = sB.x; sn[g][5] = sB.y; sn[g][6] = sB.z; sn[g][7] = sB.w;
    }
    float o[4][8];
#pragma unroll
    for (int g = 0; g < 2; ++g)
#pragma unroll
      for (int i = 0; i < 8; ++i) {
        o[g][i]     = a[g][i]     * c[g][i] - a[g + 2][i] * sn[g][i];
        o[g + 2][i] = a[g + 2][i] * c[g][i] + a[g][i]     * sn[g][i];
      }
#pragma unroll
    for (int ch = 0; ch < 4; ++ch)
#pragma unroll
      for (int i = 0; i < 8; ++i) af[ch][i] = f2bf(o[ch][i]);
  } else {
#pragma unroll
    for (int ch = 0; ch < 4; ++ch) af[ch] = raw[ch];
  }

  f32x4 acc[4] = {};
#pragma unroll
  for (int cb = 0; cb < 4; ++cb) {
#pragma unroll
    for (int ch = 0; ch < 4; ++ch) {
      const bf16x8 bfrag =
          *(const bf16x8*)&WT[(size_t)(cb * 16 + lr) * kD + ch * 32 + lk * 8];
      acc[cb] = __builtin_amdgcn_mfma_f32_16x16x32_bf16(af[ch], bfrag,
                                                        acc[cb], 0, 0, 0);
    }
  }

  short* T = Tw[w];
  if (!TR) {
#pragma unroll
    for (int cb = 0; cb < 4; ++cb)
#pragma unroll
      for (int r = 0; r < 4; ++r)
        T[(lk * 4 + r) * 72 + cb * 16 + lr] = f2bf(acc[cb][r]);
    asm volatile("s_waitcnt lgkmcnt(0)" ::: "memory");
#pragma unroll
    for (int it = 0; it < 2; ++it) {
      const int idx = it * 64 + lane;
      const int row = idx >> 3, c8 = (idx & 7) << 3;
      *(bf16x8*)&out[((size_t)bh * kS + s0 + w * 16 + row) * kL + c8] =
          *(const bf16x8*)&T[row * 72 + c8];
    }
  } else {
#pragma unroll
    for (int cb = 0; cb < 4; ++cb)
#pragma unroll
      for (int r = 0; r < 4; ++r)
        T[(cb * 16 + lr) * 20 + lk * 4 + r] = f2bf(acc[cb][r]);
    asm volatile("s_waitcnt lgkmcnt(0)" ::: "memory");
    const size_t orow = ((size_t)bh * kL + lane) * kS + s0 + w * 16;
#pragma unroll
    for (int c = 0; c < 4; ++c)
      *(short4*)&out[orow + c * 4] = *(const short4*)&T[lane * 20 + c * 4];
  }
}

// ---------------------------------------------------------------------------
// MFMA flash attention, causal, bf16 in/out (fp32 accumulate).
// Block = 512 threads (8 waves) = 128 q rows of one (b,h).
// grid = (B*H, S/128) with bx remap pairing heavy+light blocks per CU.
// T13 defer-max (THR=8) skips the O-rescale when max growth is small.
// ---------------------------------------------------------------------------
__global__ __launch_bounds__(512) void flash_attn_mfma(
    const short* __restrict__ ql, const short* __restrict__ kl,
    const short* __restrict__ vlT, short* __restrict__ attn_out) {
  constexpr int LDK = 72;
  __shared__ short Kt[64 * LDK];
  __shared__ short Vt[64 * LDK];               // row = latent l, col = key
  __shared__ short Pt[128 * LDK];

  const int tid = threadIdx.x;
  const int lane = tid & 63;
  const int w = tid >> 6;
  const int lr = lane & 15;
  const int lk = lane >> 4;
  const int bid = blockIdx.y;
  const int bx = (bid < 8) ? (2 * bid) : (31 - 2 * bid);   // load-balance remap
  const int q0 = bx * 128;
  const int bh = blockIdx.x;
  const int b = bh >> 4, h = bh & 15;
  const int hk = h >> 2;
  const int wrow = q0 + w * 16;

  const short* qrow = ql + ((size_t)bh * kS + wrow + lr) * kL;
  bf16x8 qf[2];
  qf[0] = *(const bf16x8*)(qrow + lk * 8);
  qf[1] = *(const bf16x8*)(qrow + 32 + lk * 8);

  f32x4 Of[4] = {};
  float m_r[4], l_r[4];
#pragma unroll
  for (int r = 0; r < 4; ++r) { m_r[r] = -3.0e38f; l_r[r] = 0.f; }

  const size_t kbase = (size_t)(b * kHKV + hk) * kS * kL;
  const size_t vbase = (size_t)(b * kHKV + hk) * kL * kS;
  const int ntiles = q0 / 64 + 2;
  const int sr = tid >> 3, sc8 = (tid & 7) << 3;

  for (int t = 0; t < ntiles; ++t) {
    const int j0 = t * 64;
    __syncthreads();
    *(bf16x8*)&Kt[sr * LDK + sc8] =
        *(const bf16x8*)(kl + kbase + (size_t)(j0 + sr) * kL + sc8);
    *(bf16x8*)&Vt[sr * LDK + sc8] =
        *(const bf16x8*)(vlT + vbase + (size_t)sr * kS + j0 + sc8);
    __syncthreads();

    if (j0 > wrow + 15) continue;

    f32x4 Sf[4];
    __builtin_amdgcn_s_setprio(1);
#pragma unroll
    for (int cb = 0; cb < 4; ++cb) {
      f32x4 acc = {};
#pragma unroll
      for (int ch = 0; ch < 2; ++ch) {
        const bf16x8 kf = *(const bf16x8*)&Kt[(cb * 16 + lr) * LDK + ch * 32 + lk * 8];
        acc = __builtin_amdgcn_mfma_f32_16x16x32_bf16(qf[ch], kf, acc, 0, 0, 0);
      }
      Sf[cb] = acc;
    }
    __builtin_amdgcn_s_setprio(0);

    const bool diag = (j0 + 63 > wrow);
    float mt[4] = {-3.0e38f, -3.0e38f, -3.0e38f, -3.0e38f};
#pragma unroll
    for (int cb = 0; cb < 4; ++cb)
#pragma unroll
      for (int r = 0; r < 4; ++r) {
        float s = Sf[cb][r];
        if (diag && (j0 + cb * 16 + lr) > (wrow + lk * 4 + r)) s = -3.0e38f;
        Sf[cb][r] = s;
        mt[r] = fmaxf(mt[r], s);
      }
#pragma unroll
    for (int d = 1; d < 16; d <<= 1)
#pragma unroll
      for (int r = 0; r < 4; ++r) mt[r] = fmaxf(mt[r], __shfl_xor(mt[r], d));

    const bool need = (mt[0] > m_r[0] + 8.f) || (mt[1] > m_r[1] + 8.f) ||
                      (mt[2] > m_r[2] + 8.f) || (mt[3] > m_r[3] + 8.f);
    const bool resc = __any((int)need);
    float corr[4] = {1.f, 1.f, 1.f, 1.f};
    if (resc) {
#pragma unroll
      for (int r = 0; r < 4; ++r) {
        const float mnew = fmaxf(m_r[r], mt[r]);
        corr[r] = __expf(m_r[r] - mnew);
        m_r[r] = mnew;
        l_r[r] *= corr[r];
      }
    }
#pragma unroll
    for (int cb = 0; cb < 4; ++cb) {
      const float p0 = __expf(Sf[cb][0] - m_r[0]);
      const float p1 = __expf(Sf[cb][1] - m_r[1]);
      const float p2 = __expf(Sf[cb][2] - m_r[2]);
      const float p3 = __expf(Sf[cb][3] - m_r[3]);
      l_r[0] += p0; l_r[1] += p1; l_r[2] += p2; l_r[3] += p3;
      const unsigned pk01 = cvt_pk_bf16(p0, p1);
      const unsigned pk23 = cvt_pk_bf16(p2, p3);
      short* prow = &Pt[(w * 16 + lk * 4) * LDK + cb * 16 + lr];
      prow[0 * LDK] = (short)(pk01 & 0xffff);
      prow[1 * LDK] = (short)(pk01 >> 16);
      prow[2 * LDK] = (short)(pk23 & 0xffff);
      prow[3 * LDK] = (short)(pk23 >> 16);
    }
    asm volatile("s_waitcnt lgkmcnt(0)" ::: "memory");

    __builtin_amdgcn_s_setprio(1);
#pragma unroll
    for (int cb = 0; cb < 4; ++cb) {
      f32x4 acc = Of[cb];
      if (resc) {
#pragma unroll
        for (int r = 0; r < 4; ++r) acc[r] *= corr[r];
      }
#pragma unroll
      for (int ch = 0; ch < 2; ++ch) {
        const bf16x8 pf = *(const bf16x8*)&Pt[(w * 16 + lr) * LDK + ch * 32 + lk * 8];
        const bf16x8 vf = *(const bf16x8*)&Vt[(cb * 16 + lr) * LDK + ch * 32 + lk * 8];
        acc = __builtin_amdgcn_mfma_f32_16x16x32_bf16(pf, vf, acc, 0, 0, 0);
      }
      Of[cb] = acc;
    }
    __builtin_amdgcn_s_setprio(0);
  }

#pragma unroll
  for (int d = 1; d < 16; d <<= 1)
#pragma unroll
    for (int r = 0; r < 4; ++r) l_r[r] += __shfl_xor(l_r[r], d);

#pragma unroll
  for (int r = 0; r < 4; ++r) {
    const float inv = 1.f / l_r[r];
    const size_t row = (size_t)(b * kS + wrow + lk * 4 + r) * (kH * kL);
#pragma unroll
    for (int cb = 0; cb < 4; ++cb)
      attn_out[row + h * kL + cb * 16 + lr] = f2bf(Of[cb][r] * inv);
  }
}

// ---------------------------------------------------------------------------
extern "C" void kernel_launch(void* const* d_in, const int* in_sizes, int n_in,
                              void* d_out, int out_size, void* d_ws, size_t ws_size,
                              hipStream_t stream) {
  const float* x    = (const float*)d_in[0];
  const int*   pos  = (const int*)d_in[1];
  const float* Wq   = (const float*)d_in[3];
  const float* Wk   = (const float*)d_in[4];
  const float* Wv   = (const float*)d_in[5];
  const float* Wql  = (const float*)d_in[6];
  const float* Wkl  = (const float*)d_in[7];
  const float* Wvl  = (const float*)d_in[8];
  const float* Wo   = (const float*)d_in[9];
  float* out = (float*)d_out;

  // Workspace carve (q_buf bf16 reuses d_out: 16 MB of its 32 MB)
  char* p = (char*)d_ws;
  short* x_bf  = (short*)p; p += (size_t)kTok * kHID * 2;        // 16 MB
  short* Wqkv  = (short*)p; p += (size_t)kNQKV * kHID * 2;       // 12.6 MB
  short* WoT   = (short*)p; p += (size_t)kHID * (kH * kL) * 2;   // 4 MB
  short* WqlT  = (short*)p; p += (size_t)kL * kD * 2;            // 16 KB
  short* WklT  = (short*)p; p += (size_t)kL * kD * 2;
  short* WvlT  = (short*)p; p += (size_t)kL * kD * 2;
  float* tbl   = (float*)p; p += (size_t)kTok * 128 * 4;         // 2 MB
  short* k_buf = (short*)p; p += (size_t)kTok * kHKV * kD * 2;   // 4 MB
  short* v_buf = (short*)p; p += (size_t)kTok * kHKV * kD * 2;   // 4 MB
  short* q_l   = (short*)p; p += (size_t)kB * kH * kS * kL * 2;  // 8 MB
  short* k_l   = (short*)p; p += (size_t)kB * kHKV * kS * kL * 2;
  short* v_lT  = (short*)p; p += (size_t)kB * kHKV * kS * kL * 2;
  short* attn  = (short*)p;                                      // 8 MB
  short* q_buf = (short*)d_out;   // bf16 scratch until final GEMM

  // 0) dtype prep
  cvt_bf16<<<kTok * kHID / 8 / 256, 256, 0, stream>>>(x, x_bf, kTok * kHID / 8);
  trig_table<<<kTok * 64 / 256, 256, 0, stream>>>(pos, tbl);
  transpose_cvt<false><<<dim3(kH * kD / 64, kHID / 64), 256, 0, stream>>>(
      Wq, Wqkv, kH * kD, kHID, 0, 1.0f);
  transpose_cvt<false><<<dim3(kHKV * kD / 64, kHID / 64), 256, 0, stream>>>(
      Wk, Wqkv, kHKV * kD, kHID, kH * kD, 1.0f);
  transpose_cvt<false><<<dim3(kHKV * kD / 64, kHID / 64), 256, 0, stream>>>(
      Wv, Wqkv, kHKV * kD, kHID, kH * kD + kHKV * kD, 1.0f);
  transpose_cvt<true><<<dim3(kHID / 64, (kH * kL) / 64), 256, 0, stream>>>(
      Wo, WoT, kHID, kH * kL, 0, 1.0f);
  transpose_cvt<false><<<dim3(1, kD / 64), 256, 0, stream>>>(
      Wql, WqlT, kL, kD, 0, 0.125f);            // fold 1/sqrt(L)
  transpose_cvt<false><<<dim3(1, kD / 64), 256, 0, stream>>>(
      Wkl, WklT, kL, kD, 0, 1.0f);
  transpose_cvt<false><<<dim3(1, kD / 64), 256, 0, stream>>>(
      Wvl, WvlT, kL, kD, 0, 1.0f);

  // 1) Fused QKV projection (m97 MFMA, bf16 out, XCD swizzle)
  gemm_qkv<<<dim3(kNQKV / 128, kTok / 128), 256, 0, stream>>>(
      x_bf, Wqkv, q_buf, k_buf, v_buf, kHID);

  // 2) Fused RoPE + latent projections — single dispatch
  rope_latent_all<<<dim3(kS / 64, 48), 256, 0, stream>>>(
      q_buf, k_buf, v_buf, WqlT, WklT, WvlT, tbl, q_l, k_l, v_lT);

  // 3) MFMA flash attention (128 q-rows/block, 8 waves, balanced grid)
  flash_attn_mfma<<<dim3(kB * kH, kS / 128), 512, 0, stream>>>(
      q_l, k_l, v_lT, attn);

  // 4) Output GEMM (m97 MFMA, fp32 out, XCD swizzle)
  gemm_mfma<<<dim3(kHID / 128, kTok / 128), 256, 0, stream>>>(
      attn, WoT, out, kTok, kHID, kH * kL);
}

// Round 9
// 223.181 us; speedup vs baseline: 1.1522x; 1.0247x over previous
//
#include <hip/hip_runtime.h>
#include <cstddef>

// Problem constants
constexpr int kB   = 2;
constexpr int kS   = 2048;
constexpr int kHID = 2048;
constexpr int kH   = 16;
constexpr int kHKV = 4;
constexpr int kD   = 128;
constexpr int kL   = 64;
constexpr int kTok = kB * kS;             // 4096 tokens
constexpr int kNQKV = kH * kD + 2 * kHKV * kD;  // 3072 fused QKV cols

typedef __attribute__((ext_vector_type(8))) short bf16x8;
typedef __attribute__((ext_vector_type(4))) float f32x4;

static __device__ __forceinline__ short f2bf(float f) {
  union { float f; unsigned u; } v{f};
  const unsigned r = (v.u + 0x7fff + ((v.u >> 16) & 1)) >> 16;
  return (short)r;
}
static __device__ __forceinline__ float bf2f(short s) {
  union { unsigned u; float f; } v;
  v.u = ((unsigned)(unsigned short)s) << 16;
  return v.f;
}

static __device__ __forceinline__ bf16x8 pack8(float4 a, float4 b) {
  bf16x8 r;
  r[0] = f2bf(a.x); r[1] = f2bf(a.y); r[2] = f2bf(a.z); r[3] = f2bf(a.w);
  r[4] = f2bf(b.x); r[5] = f2bf(b.y); r[6] = f2bf(b.z); r[7] = f2bf(b.w);
  return r;
}

// packed fp32x2 -> bf16x2 (exact RTN) — no builtin on gfx950, inline asm
static __device__ __forceinline__ unsigned cvt_pk_bf16(float lo, float hi) {
  unsigned r;
  asm("v_cvt_pk_bf16_f32 %0, %1, %2" : "=v"(r) : "v"(lo), "v"(hi));
  return r;
}

// async global->LDS, 16B per lane. LDS dest must be wave-uniform base + lane*16.
typedef __attribute__((address_space(3))) void       lds_void;
typedef __attribute__((address_space(1))) const void gm_void;
static __device__ __forceinline__ void gload16(const void* g, void* l) {
  __builtin_amdgcn_global_load_lds((gm_void*)g, (lds_void*)l, 16, 0, 0);
}

// T1: bijective XCD-aware block swizzle (requires nwg % 8 == 0)
static __device__ __forceinline__ int2 xcd_swz(int nx, int ny) {
  int wg = blockIdx.y * nx + blockIdx.x;
  const int cpx = (nx * ny) >> 3;
  wg = (wg & 7) * cpx + (wg >> 3);
  int2 r; r.x = wg % nx; r.y = wg / nx;
  return r;
}

// ---------------------------------------------------------------------------
// fp32 -> bf16 elementwise (8 elems / thread)
// ---------------------------------------------------------------------------
__global__ __launch_bounds__(256) void cvt_bf16(const float* __restrict__ in,
                                                short* __restrict__ out, int n8) {
  const int i = blockIdx.x * 256 + threadIdx.x;
  if (i >= n8) return;
  const float4 a = *(const float4*)&in[i * 8];
  const float4 b = *(const float4*)&in[i * 8 + 4];
  *(bf16x8*)&out[i * 8] = pack8(a, b);
}

// ---------------------------------------------------------------------------
// Per-token RoPE cos/sin table
// ---------------------------------------------------------------------------
__global__ __launch_bounds__(256) void trig_table(const int* __restrict__ pos,
                                                  float* __restrict__ tbl) {
  const int idx = blockIdx.x * 256 + threadIdx.x;
  if (idx >= kTok * 64) return;
  const int i = idx & 63, t = idx >> 6;
  const float p = (float)pos[t];
  const float inv_freq = expf(-(float)i * (9.210340371976184f / 64.0f));
  const float ang = p * inv_freq;
  tbl[t * 128 + i]      = cosf(ang);
  tbl[t * 128 + 64 + i] = sinf(ang);
}

// ---------------------------------------------------------------------------
// Transpose + convert + scale: out[row_off+n][k] (bf16, ld) = in[rmap(k)][n]*scale
// ---------------------------------------------------------------------------
template <bool REMAP>
__global__ __launch_bounds__(256) void transpose_cvt(
    const float* __restrict__ in, short* __restrict__ out,
    int Nin, int out_ld, int row_off, float scale) {
  __shared__ float T[64][65];
  const int tid = threadIdx.x;
  const int k0 = blockIdx.y * 64, n0 = blockIdx.x * 64;
  const int rr = tid >> 4;
  const int cc = tid & 15;
#pragma unroll
  for (int ii = 0; ii < 4; ++ii) {
    const int kr = rr + ii * 16;
    int gr = k0 + kr;
    if (REMAP) gr = ((gr >> 6) << 7) + (gr & 63);
    const float4 v = *(const float4*)&in[(size_t)gr * Nin + n0 + cc * 4];
    T[kr][cc * 4 + 0] = v.x * scale; T[kr][cc * 4 + 1] = v.y * scale;
    T[kr][cc * 4 + 2] = v.z * scale; T[kr][cc * 4 + 3] = v.w * scale;
  }
  __syncthreads();
#pragma unroll
  for (int ii = 0; ii < 4; ++ii) {
    const int n = rr + ii * 16;
    const short4 s4 = make_short4(f2bf(T[cc * 4 + 0][n]), f2bf(T[cc * 4 + 1][n]),
                                  f2bf(T[cc * 4 + 2][n]), f2bf(T[cc * 4 + 3][n]));
    *(short4*)&out[(size_t)(row_off + n0 + n) * out_ld + k0 + cc * 4] = s4;
  }
}

// ---------------------------------------------------------------------------
// bf16 MFMA GEMM (m97): QKV variant — bf16 output split q/k/v by block col.
// ---------------------------------------------------------------------------
__global__ __launch_bounds__(256) void gemm_qkv(
    const short* __restrict__ A, const short* __restrict__ Bt,
    short* __restrict__ C0, short* __restrict__ C1, short* __restrict__ C2,
    int K) {
  __shared__ short As[128 * 32];
  __shared__ short Bs[128 * 32];
  const int tid = threadIdx.x;
  const int l = tid & 63, w = tid >> 6;
  const int lr = l & 15, lk = l >> 4;
  const int wm = w >> 1, wn = w & 1;
  const int2 sw = xcd_swz(kNQKV / 128, kTok / 128);   // 24 x 32 = 768 blocks
  const int row0 = sw.y * 128, col0 = sw.x * 128;

  f32x4 acc[4][4] = {};

  for (int k0 = 0; k0 < K; k0 += 32) {
    __syncthreads();
#pragma unroll
    for (int j = 0; j < 2; ++j) {
      const int idx = j * 256 + tid;
      const int r = idx >> 2, c = idx & 3;
      gload16(A  + (size_t)(row0 + r) * K + k0 + c * 8, &As[idx * 8]);
      gload16(Bt + (size_t)(col0 + r) * K + k0 + c * 8, &Bs[idx * 8]);
    }
    __syncthreads();
    bf16x8 af[4], bfr[4];
#pragma unroll
    for (int m = 0; m < 4; ++m)
      af[m] = *(const bf16x8*)&As[(wm * 64 + m * 16 + lr) * 32 + lk * 8];
#pragma unroll
    for (int n = 0; n < 4; ++n)
      bfr[n] = *(const bf16x8*)&Bs[(wn * 64 + n * 16 + lr) * 32 + lk * 8];
#pragma unroll
    for (int m = 0; m < 4; ++m)
#pragma unroll
      for (int n = 0; n < 4; ++n)
        acc[m][n] = __builtin_amdgcn_mfma_f32_16x16x32_bf16(af[m], bfr[n],
                                                            acc[m][n], 0, 0, 0);
  }

  short* dst; int ld, cb;
  if (col0 < 2048)      { dst = C0; ld = 2048; cb = col0; }
  else if (col0 < 2560) { dst = C1; ld = 512;  cb = col0 - 2048; }
  else                  { dst = C2; ld = 512;  cb = col0 - 2560; }
  const int crow0 = row0 + wm * 64 + lk * 4;
  const int ccol0 = cb + wn * 64 + lr;
#pragma unroll
  for (int m = 0; m < 4; ++m)
#pragma unroll
    for (int n = 0; n < 4; ++n)
#pragma unroll
      for (int rr = 0; rr < 4; ++rr)
        dst[(size_t)(crow0 + m * 16 + rr) * ld + ccol0 + n * 16] =
            f2bf(acc[m][n][rr]);
}

// ---------------------------------------------------------------------------
// bf16 MFMA GEMM (m97): fp32-output variant for the final K=1024 GEMM.
// ---------------------------------------------------------------------------
__global__ __launch_bounds__(256) void gemm_mfma(
    const short* __restrict__ A, const short* __restrict__ Bt,
    float* __restrict__ C0, int M, int N, int K) {
  __shared__ short As[128 * 32];
  __shared__ short Bs[128 * 32];
  const int tid = threadIdx.x;
  const int l = tid & 63, w = tid >> 6;
  const int lr = l & 15, lk = l >> 4;
  const int wm = w >> 1, wn = w & 1;
  const int2 sw = xcd_swz(N / 128, M / 128);
  const int row0 = sw.y * 128, col0 = sw.x * 128;

  f32x4 acc[4][4] = {};

  for (int k0 = 0; k0 < K; k0 += 32) {
    __syncthreads();
#pragma unroll
    for (int j = 0; j < 2; ++j) {
      const int idx = j * 256 + tid;
      const int r = idx >> 2, c = idx & 3;
      gload16(A  + (size_t)(row0 + r) * K + k0 + c * 8, &As[idx * 8]);
      gload16(Bt + (size_t)(col0 + r) * K + k0 + c * 8, &Bs[idx * 8]);
    }
    __syncthreads();
    bf16x8 af[4], bfr[4];
#pragma unroll
    for (int m = 0; m < 4; ++m)
      af[m] = *(const bf16x8*)&As[(wm * 64 + m * 16 + lr) * 32 + lk * 8];
#pragma unroll
    for (int n = 0; n < 4; ++n)
      bfr[n] = *(const bf16x8*)&Bs[(wn * 64 + n * 16 + lr) * 32 + lk * 8];
#pragma unroll
    for (int m = 0; m < 4; ++m)
#pragma unroll
      for (int n = 0; n < 4; ++n)
        acc[m][n] = __builtin_amdgcn_mfma_f32_16x16x32_bf16(af[m], bfr[n],
                                                            acc[m][n], 0, 0, 0);
  }

  const int crow0 = row0 + wm * 64 + lk * 4;
  const int ccol0 = col0 + wn * 64 + lr;
#pragma unroll
  for (int m = 0; m < 4; ++m)
#pragma unroll
    for (int n = 0; n < 4; ++n)
#pragma unroll
      for (int rr = 0; rr < 4; ++rr)
        C0[(size_t)(crow0 + m * 16 + rr) * N + ccol0 + n * 16] = acc[m][n][rr];
}

// ---------------------------------------------------------------------------
// Fused RoPE + latent projection (MFMA), bf16 input, all three tensors in
// one dispatch. grid = (kS/64, 48): y<32 -> q (ROPE), y<40 -> k (ROPE),
// y>=40 -> v (no RoPE, transposed [l][S] output). Branches block-uniform.
// ---------------------------------------------------------------------------
__global__ __launch_bounds__(256) void rope_latent_all(
    const short* __restrict__ qb, const short* __restrict__ kb,
    const short* __restrict__ vb, const short* __restrict__ WqlT,
    const short* __restrict__ WklT, const short* __restrict__ WvlT,
    const float* __restrict__ tbl, short* __restrict__ q_l,
    short* __restrict__ k_l, short* __restrict__ v_lT) {
  __shared__ short Tw[4][1280];
  const int yz = blockIdx.y;
  const short* in; const short* WT; short* out; int nh; bool ROPE, TR;
  int bh;
  if (yz < 32)      { in = qb; WT = WqlT; out = q_l;  nh = kH;   ROPE = true;  TR = false; bh = yz; }
  else if (yz < 40) { in = kb; WT = WklT; out = k_l;  nh = kHKV; ROPE = true;  TR = false; bh = yz - 32; }
  else              { in = vb; WT = WvlT; out = v_lT; nh = kHKV; ROPE = false; TR = true;  bh = yz - 40; }

  const int tid = threadIdx.x;
  const int lane = tid & 63;
  const int w = tid >> 6;
  const int lr = lane & 15;
  const int lk = lane >> 4;
  const int b = bh / nh, h = bh % nh;
  const int s0 = blockIdx.x * 64;
  const int srow = s0 + w * 16 + lr;
  const int tok = b * kS + srow;

  const short* ip = in + ((size_t)tok * nh + h) * kD + lk * 8;
  bf16x8 raw[4];
#pragma unroll
  for (int ch = 0; ch < 4; ++ch) raw[ch] = *(const bf16x8*)(ip + ch * 32);

  bf16x8 af[4];
  if (ROPE) {
    float a[4][8];
#pragma unroll
    for (int ch = 0; ch < 4; ++ch)
#pragma unroll
      for (int i = 0; i < 8; ++i) a[ch][i] = bf2f(raw[ch][i]);
    const float* tb = tbl + (size_t)tok * 128;
    float c[2][8], sn[2][8];
#pragma unroll
    for (int g = 0; g < 2; ++g) {
      const float4 cA = *(const float4*)(tb + g * 32 + lk * 8);
      const float4 cB = *(const float4*)(tb + g * 32 + lk * 8 + 4);
      const float4 sA = *(const float4*)(tb + 64 + g * 32 + lk * 8);
      const float4 sB = *(const float4*)(tb + 64 + g * 32 + lk * 8 + 4);
      c[g][0] = cA.x; c[g][1] = cA.y; c[g][2] = cA.z; c[g][3] = cA.w;
      c[g][4] = cB.x; c[g][5] = cB.y; c[g][6] = cB.z; c[g][7] = cB.w;
      sn[g][0] = sA.x; sn[g][1] = sA.y; sn[g][2] = sA.z; sn[g][3] = sA.w;
      sn[g][4] = sB.x; sn[g][5] = sB.y; sn[g][6] = sB.z; sn[g][7] = sB.w;
    }
    float o[4][8];
#pragma unroll
    for (int g = 0; g < 2; ++g)
#pragma unroll
      for (int i = 0; i < 8; ++i) {
        o[g][i]     = a[g][i]     * c[g][i] - a[g + 2][i] * sn[g][i];
        o[g + 2][i] = a[g + 2][i] * c[g][i] + a[g][i]     * sn[g][i];
      }
#pragma unroll
    for (int ch = 0; ch < 4; ++ch)
#pragma unroll
      for (int i = 0; i < 8; ++i) af[ch][i] = f2bf(o[ch][i]);
  } else {
#pragma unroll
    for (int ch = 0; ch < 4; ++ch) af[ch] = raw[ch];
  }

  f32x4 acc[4] = {};
#pragma unroll
  for (int cb = 0; cb < 4; ++cb) {
#pragma unroll
    for (int ch = 0; ch < 4; ++ch) {
      const bf16x8 bfrag =
          *(const bf16x8*)&WT[(size_t)(cb * 16 + lr) * kD + ch * 32 + lk * 8];
      acc[cb] = __builtin_amdgcn_mfma_f32_16x16x32_bf16(af[ch], bfrag,
                                                        acc[cb], 0, 0, 0);
    }
  }

  short* T = Tw[w];
  if (!TR) {
#pragma unroll
    for (int cb = 0; cb < 4; ++cb)
#pragma unroll
      for (int r = 0; r < 4; ++r)
        T[(lk * 4 + r) * 72 + cb * 16 + lr] = f2bf(acc[cb][r]);
    asm volatile("s_waitcnt lgkmcnt(0)" ::: "memory");
#pragma unroll
    for (int it = 0; it < 2; ++it) {
      const int idx = it * 64 + lane;
      const int row = idx >> 3, c8 = (idx & 7) << 3;
      *(bf16x8*)&out[((size_t)bh * kS + s0 + w * 16 + row) * kL + c8] =
          *(const bf16x8*)&T[row * 72 + c8];
    }
  } else {
#pragma unroll
    for (int cb = 0; cb < 4; ++cb)
#pragma unroll
      for (int r = 0; r < 4; ++r)
        T[(cb * 16 + lr) * 20 + lk * 4 + r] = f2bf(acc[cb][r]);
    asm volatile("s_waitcnt lgkmcnt(0)" ::: "memory");
    const size_t orow = ((size_t)bh * kL + lane) * kS + s0 + w * 16;
#pragma unroll
    for (int c = 0; c < 4; ++c)
      *(short4*)&out[orow + c * 4] = *(const short4*)&T[lane * 20 + c * 4];
  }
}

// ---------------------------------------------------------------------------
// MFMA flash attention, causal, bf16 in/out (fp32 accumulate).
// Block = 512 threads (8 waves) = 128 q rows of one (b,h).
// grid = (B*H, S/128) with bx remap pairing heavy+light blocks per CU.
// T14 async-stage + double-buffered K/V: tile t+1's global loads are issued
// into registers BEFORE tile t's compute (latency hides under MFMAs), then
// written to the alternate LDS buffer after compute; ONE barrier per tile.
// T13 defer-max (THR=8) skips the O-rescale when max growth is small.
// ---------------------------------------------------------------------------
__global__ __launch_bounds__(512) void flash_attn_mfma(
    const short* __restrict__ ql, const short* __restrict__ kl,
    const short* __restrict__ vlT, short* __restrict__ attn_out) {
  constexpr int LDK = 72;
  __shared__ short Kt[2][64 * LDK];
  __shared__ short Vt[2][64 * LDK];            // row = latent l, col = key
  __shared__ short Pt[128 * LDK];

  const int tid = threadIdx.x;
  const int lane = tid & 63;
  const int w = tid >> 6;
  const int lr = lane & 15;
  const int lk = lane >> 4;
  const int bid = blockIdx.y;
  const int bx = (bid < 8) ? (2 * bid) : (31 - 2 * bid);   // load-balance remap
  const int q0 = bx * 128;
  const int bh = blockIdx.x;
  const int b = bh >> 4, h = bh & 15;
  const int hk = h >> 2;
  const int wrow = q0 + w * 16;

  const short* qrow = ql + ((size_t)bh * kS + wrow + lr) * kL;
  bf16x8 qf[2];
  qf[0] = *(const bf16x8*)(qrow + lk * 8);
  qf[1] = *(const bf16x8*)(qrow + 32 + lk * 8);

  f32x4 Of[4] = {};
  float m_r[4], l_r[4];
#pragma unroll
  for (int r = 0; r < 4; ++r) { m_r[r] = -3.0e38f; l_r[r] = 0.f; }

  const size_t kbase = (size_t)(b * kHKV + hk) * kS * kL;
  const size_t vbase = (size_t)(b * kHKV + hk) * kL * kS;
  const int ntiles = q0 / 64 + 2;
  const int sr = tid >> 3, sc8 = (tid & 7) << 3;
  const short* kp = kl + kbase + (size_t)sr * kL + sc8;    // + j0*kL walks tiles
  const short* vp = vlT + vbase + (size_t)sr * kS + sc8;   // + j0 walks tiles

  // prologue: stage tile 0 into buffer 0
  *(bf16x8*)&Kt[0][sr * LDK + sc8] = *(const bf16x8*)kp;
  *(bf16x8*)&Vt[0][sr * LDK + sc8] = *(const bf16x8*)vp;
  __syncthreads();

  int cur = 0;
  for (int t = 0; t < ntiles; ++t) {
    const int j0 = t * 64;
    const bool pre = (t + 1 < ntiles);
    bf16x8 krn, vrn;
    if (pre) {                                 // issue next-tile loads EARLY
      krn = *(const bf16x8*)(kp + (size_t)(j0 + 64) * kL);
      vrn = *(const bf16x8*)(vp + (j0 + 64));
    }

    if (j0 <= wrow) {                          // wave-uniform causal skip
      const short* Kc = &Kt[cur][0];
      const short* Vc = &Vt[cur][0];

      f32x4 Sf[4];
      __builtin_amdgcn_s_setprio(1);
#pragma unroll
      for (int cb = 0; cb < 4; ++cb) {
        f32x4 acc = {};
#pragma unroll
        for (int ch = 0; ch < 2; ++ch) {
          const bf16x8 kf = *(const bf16x8*)&Kc[(cb * 16 + lr) * LDK + ch * 32 + lk * 8];
          acc = __builtin_amdgcn_mfma_f32_16x16x32_bf16(qf[ch], kf, acc, 0, 0, 0);
        }
        Sf[cb] = acc;
      }
      __builtin_amdgcn_s_setprio(0);

      const bool diag = (j0 + 63 > wrow);
      float mt[4] = {-3.0e38f, -3.0e38f, -3.0e38f, -3.0e38f};
#pragma unroll
      for (int cb = 0; cb < 4; ++cb)
#pragma unroll
        for (int r = 0; r < 4; ++r) {
          float s = Sf[cb][r];
          if (diag && (j0 + cb * 16 + lr) > (wrow + lk * 4 + r)) s = -3.0e38f;
          Sf[cb][r] = s;
          mt[r] = fmaxf(mt[r], s);
        }
#pragma unroll
      for (int d = 1; d < 16; d <<= 1)
#pragma unroll
        for (int r = 0; r < 4; ++r) mt[r] = fmaxf(mt[r], __shfl_xor(mt[r], d));

      const bool need = (mt[0] > m_r[0] + 8.f) || (mt[1] > m_r[1] + 8.f) ||
                        (mt[2] > m_r[2] + 8.f) || (mt[3] > m_r[3] + 8.f);
      const bool resc = __any((int)need);
      float corr[4] = {1.f, 1.f, 1.f, 1.f};
      if (resc) {
#pragma unroll
        for (int r = 0; r < 4; ++r) {
          const float mnew = fmaxf(m_r[r], mt[r]);
          corr[r] = __expf(m_r[r] - mnew);
          m_r[r] = mnew;
          l_r[r] *= corr[r];
        }
      }
#pragma unroll
      for (int cb = 0; cb < 4; ++cb) {
        const float p0 = __expf(Sf[cb][0] - m_r[0]);
        const float p1 = __expf(Sf[cb][1] - m_r[1]);
        const float p2 = __expf(Sf[cb][2] - m_r[2]);
        const float p3 = __expf(Sf[cb][3] - m_r[3]);
        l_r[0] += p0; l_r[1] += p1; l_r[2] += p2; l_r[3] += p3;
        const unsigned pk01 = cvt_pk_bf16(p0, p1);
        const unsigned pk23 = cvt_pk_bf16(p2, p3);
        short* prow = &Pt[(w * 16 + lk * 4) * LDK + cb * 16 + lr];
        prow[0 * LDK] = (short)(pk01 & 0xffff);
        prow[1 * LDK] = (short)(pk01 >> 16);
        prow[2 * LDK] = (short)(pk23 & 0xffff);
        prow[3 * LDK] = (short)(pk23 >> 16);
      }
      // same-wave LDS write->read (cross-lane): drain before A-frag reads
      asm volatile("s_waitcnt lgkmcnt(0)" ::: "memory");

      __builtin_amdgcn_s_setprio(1);
#pragma unroll
      for (int cb = 0; cb < 4; ++cb) {
        f32x4 acc = Of[cb];
        if (resc) {
#pragma unroll
          for (int r = 0; r < 4; ++r) acc[r] *= corr[r];
        }
#pragma unroll
        for (int ch = 0; ch < 2; ++ch) {
          const bf16x8 pf = *(const bf16x8*)&Pt[(w * 16 + lr) * LDK + ch * 32 + lk * 8];
          const bf16x8 vf = *(const bf16x8*)&Vc[(cb * 16 + lr) * LDK + ch * 32 + lk * 8];
          acc = __builtin_amdgcn_mfma_f32_16x16x32_bf16(pf, vf, acc, 0, 0, 0);
        }
        Of[cb] = acc;
      }
      __builtin_amdgcn_s_setprio(0);
    }

    if (pre) {                                 // write-late into other buffer
      *(bf16x8*)&Kt[cur ^ 1][sr * LDK + sc8] = krn;
      *(bf16x8*)&Vt[cur ^ 1][sr * LDK + sc8] = vrn;
    }
    __syncthreads();                           // single barrier per tile
    cur ^= 1;
  }

#pragma unroll
  for (int d = 1; d < 16; d <<= 1)
#pragma unroll
    for (int r = 0; r < 4; ++r) l_r[r] += __shfl_xor(l_r[r], d);

#pragma unroll
  for (int r = 0; r < 4; ++r) {
    const float inv = 1.f / l_r[r];
    const size_t row = (size_t)(b * kS + wrow + lk * 4 + r) * (kH * kL);
#pragma unroll
    for (int cb = 0; cb < 4; ++cb)
      attn_out[row + h * kL + cb * 16 + lr] = f2bf(Of[cb][r] * inv);
  }
}

// ---------------------------------------------------------------------------
extern "C" void kernel_launch(void* const* d_in, const int* in_sizes, int n_in,
                              void* d_out, int out_size, void* d_ws, size_t ws_size,
                              hipStream_t stream) {
  const float* x    = (const float*)d_in[0];
  const int*   pos  = (const int*)d_in[1];
  const float* Wq   = (const float*)d_in[3];
  const float* Wk   = (const float*)d_in[4];
  const float* Wv   = (const float*)d_in[5];
  const float* Wql  = (const float*)d_in[6];
  const float* Wkl  = (const float*)d_in[7];
  const float* Wvl  = (const float*)d_in[8];
  const float* Wo   = (const float*)d_in[9];
  float* out = (float*)d_out;

  // Workspace carve (q_buf bf16 reuses d_out: 16 MB of its 32 MB)
  char* p = (char*)d_ws;
  short* x_bf  = (short*)p; p += (size_t)kTok * kHID * 2;        // 16 MB
  short* Wqkv  = (short*)p; p += (size_t)kNQKV * kHID * 2;       // 12.6 MB
  short* WoT   = (short*)p; p += (size_t)kHID * (kH * kL) * 2;   // 4 MB
  short* WqlT  = (short*)p; p += (size_t)kL * kD * 2;            // 16 KB
  short* WklT  = (short*)p; p += (size_t)kL * kD * 2;
  short* WvlT  = (short*)p; p += (size_t)kL * kD * 2;
  float* tbl   = (float*)p; p += (size_t)kTok * 128 * 4;         // 2 MB
  short* k_buf = (short*)p; p += (size_t)kTok * kHKV * kD * 2;   // 4 MB
  short* v_buf = (short*)p; p += (size_t)kTok * kHKV * kD * 2;   // 4 MB
  short* q_l   = (short*)p; p += (size_t)kB * kH * kS * kL * 2;  // 8 MB
  short* k_l   = (short*)p; p += (size_t)kB * kHKV * kS * kL * 2;
  short* v_lT  = (short*)p; p += (size_t)kB * kHKV * kS * kL * 2;
  short* attn  = (short*)p;                                      // 8 MB
  short* q_buf = (short*)d_out;   // bf16 scratch until final GEMM

  // 0) dtype prep
  cvt_bf16<<<kTok * kHID / 8 / 256, 256, 0, stream>>>(x, x_bf, kTok * kHID / 8);
  trig_table<<<kTok * 64 / 256, 256, 0, stream>>>(pos, tbl);
  transpose_cvt<false><<<dim3(kH * kD / 64, kHID / 64), 256, 0, stream>>>(
      Wq, Wqkv, kH * kD, kHID, 0, 1.0f);
  transpose_cvt<false><<<dim3(kHKV * kD / 64, kHID / 64), 256, 0, stream>>>(
      Wk, Wqkv, kHKV * kD, kHID, kH * kD, 1.0f);
  transpose_cvt<false><<<dim3(kHKV * kD / 64, kHID / 64), 256, 0, stream>>>(
      Wv, Wqkv, kHKV * kD, kHID, kH * kD + kHKV * kD, 1.0f);
  transpose_cvt<true><<<dim3(kHID / 64, (kH * kL) / 64), 256, 0, stream>>>(
      Wo, WoT, kHID, kH * kL, 0, 1.0f);
  transpose_cvt<false><<<dim3(1, kD / 64), 256, 0, stream>>>(
      Wql, WqlT, kL, kD, 0, 0.125f);            // fold 1/sqrt(L)
  transpose_cvt<false><<<dim3(1, kD / 64), 256, 0, stream>>>(
      Wkl, WklT, kL, kD, 0, 1.0f);
  transpose_cvt<false><<<dim3(1, kD / 64), 256, 0, stream>>>(
      Wvl, WvlT, kL, kD, 0, 1.0f);

  // 1) Fused QKV projection (m97 MFMA, bf16 out, XCD swizzle)
  gemm_qkv<<<dim3(kNQKV / 128, kTok / 128), 256, 0, stream>>>(
      x_bf, Wqkv, q_buf, k_buf, v_buf, kHID);

  // 2) Fused RoPE + latent projections — single dispatch
  rope_latent_all<<<dim3(kS / 64, 48), 256, 0, stream>>>(
      q_buf, k_buf, v_buf, WqlT, WklT, WvlT, tbl, q_l, k_l, v_lT);

  // 3) MFMA flash attention (T14 async dbuf, 1 barrier/tile)
  flash_attn_mfma<<<dim3(kB * kH, kS / 128), 512, 0, stream>>>(
      q_l, k_l, v_lT, attn);

  // 4) Output GEMM (m97 MFMA, fp32 out, XCD swizzle)
  gemm_mfma<<<dim3(kHID / 128, kTok / 128), 256, 0, stream>>>(
      attn, WoT, out, kTok, kHID, kH * kL);
}

// Round 10
// 217.131 us; speedup vs baseline: 1.1843x; 1.0279x over previous
//
#include <hip/hip_runtime.h>
#include <cstddef>

// Problem constants
constexpr int kB   = 2;
constexpr int kS   = 2048;
constexpr int kHID = 2048;
constexpr int kH   = 16;
constexpr int kHKV = 4;
constexpr int kD   = 128;
constexpr int kL   = 64;
constexpr int kTok = kB * kS;             // 4096 tokens
constexpr int kNQKV = kH * kD + 2 * kHKV * kD;  // 3072 fused QKV cols

typedef __attribute__((ext_vector_type(8))) short bf16x8;
typedef __attribute__((ext_vector_type(4))) float f32x4;

static __device__ __forceinline__ short f2bf(float f) {
  union { float f; unsigned u; } v{f};
  const unsigned r = (v.u + 0x7fff + ((v.u >> 16) & 1)) >> 16;
  return (short)r;
}
static __device__ __forceinline__ float bf2f(short s) {
  union { unsigned u; float f; } v;
  v.u = ((unsigned)(unsigned short)s) << 16;
  return v.f;
}

static __device__ __forceinline__ bf16x8 pack8(float4 a, float4 b) {
  bf16x8 r;
  r[0] = f2bf(a.x); r[1] = f2bf(a.y); r[2] = f2bf(a.z); r[3] = f2bf(a.w);
  r[4] = f2bf(b.x); r[5] = f2bf(b.y); r[6] = f2bf(b.z); r[7] = f2bf(b.w);
  return r;
}

// packed fp32x2 -> bf16x2 (exact RTN) — no builtin on gfx950, inline asm
static __device__ __forceinline__ unsigned cvt_pk_bf16(float lo, float hi) {
  unsigned r;
  asm("v_cvt_pk_bf16_f32 %0, %1, %2" : "=v"(r) : "v"(lo), "v"(hi));
  return r;
}

// async global->LDS, 16B per lane. LDS dest must be wave-uniform base + lane*16.
typedef __attribute__((address_space(3))) void       lds_void;
typedef __attribute__((address_space(1))) const void gm_void;
static __device__ __forceinline__ void gload16(const void* g, void* l) {
  __builtin_amdgcn_global_load_lds((gm_void*)g, (lds_void*)l, 16, 0, 0);
}

// T1: bijective XCD-aware block swizzle (requires nwg % 8 == 0)
static __device__ __forceinline__ int2 xcd_swz(int nx, int ny) {
  int wg = blockIdx.y * nx + blockIdx.x;
  const int cpx = (nx * ny) >> 3;
  wg = (wg & 7) * cpx + (wg >> 3);
  int2 r; r.x = wg % nx; r.y = wg / nx;
  return r;
}

// ---------------------------------------------------------------------------
// fp32 -> bf16 elementwise (8 elems / thread)
// ---------------------------------------------------------------------------
__global__ __launch_bounds__(256) void cvt_bf16(const float* __restrict__ in,
                                                short* __restrict__ out, int n8) {
  const int i = blockIdx.x * 256 + threadIdx.x;
  if (i >= n8) return;
  const float4 a = *(const float4*)&in[i * 8];
  const float4 b = *(const float4*)&in[i * 8 + 4];
  *(bf16x8*)&out[i * 8] = pack8(a, b);
}

// ---------------------------------------------------------------------------
// Per-token RoPE cos/sin table
// ---------------------------------------------------------------------------
__global__ __launch_bounds__(256) void trig_table(const int* __restrict__ pos,
                                                  float* __restrict__ tbl) {
  const int idx = blockIdx.x * 256 + threadIdx.x;
  if (idx >= kTok * 64) return;
  const int i = idx & 63, t = idx >> 6;
  const float p = (float)pos[t];
  const float inv_freq = expf(-(float)i * (9.210340371976184f / 64.0f));
  const float ang = p * inv_freq;
  tbl[t * 128 + i]      = cosf(ang);
  tbl[t * 128 + 64 + i] = sinf(ang);
}

// ---------------------------------------------------------------------------
// Transpose + convert + scale: out[row_off+n][k] (bf16, ld) = in[rmap(k)][n]*scale
// ---------------------------------------------------------------------------
template <bool REMAP>
__global__ __launch_bounds__(256) void transpose_cvt(
    const float* __restrict__ in, short* __restrict__ out,
    int Nin, int out_ld, int row_off, float scale) {
  __shared__ float T[64][65];
  const int tid = threadIdx.x;
  const int k0 = blockIdx.y * 64, n0 = blockIdx.x * 64;
  const int rr = tid >> 4;
  const int cc = tid & 15;
#pragma unroll
  for (int ii = 0; ii < 4; ++ii) {
    const int kr = rr + ii * 16;
    int gr = k0 + kr;
    if (REMAP) gr = ((gr >> 6) << 7) + (gr & 63);
    const float4 v = *(const float4*)&in[(size_t)gr * Nin + n0 + cc * 4];
    T[kr][cc * 4 + 0] = v.x * scale; T[kr][cc * 4 + 1] = v.y * scale;
    T[kr][cc * 4 + 2] = v.z * scale; T[kr][cc * 4 + 3] = v.w * scale;
  }
  __syncthreads();
#pragma unroll
  for (int ii = 0; ii < 4; ++ii) {
    const int n = rr + ii * 16;
    const short4 s4 = make_short4(f2bf(T[cc * 4 + 0][n]), f2bf(T[cc * 4 + 1][n]),
                                  f2bf(T[cc * 4 + 2][n]), f2bf(T[cc * 4 + 3][n]));
    *(short4*)&out[(size_t)(row_off + n0 + n) * out_ld + k0 + cc * 4] = s4;
  }
}

// ---------------------------------------------------------------------------
// Three small latent-weight transposes (128x64 each) in one dispatch.
// grid = (1, kD/64, 3); z selects (Wql*0.125, Wkl, Wvl).
// ---------------------------------------------------------------------------
__global__ __launch_bounds__(256) void transpose_lat3(
    const float* __restrict__ Wql, const float* __restrict__ Wkl,
    const float* __restrict__ Wvl, short* __restrict__ WqlT,
    short* __restrict__ WklT, short* __restrict__ WvlT) {
  __shared__ float T[64][65];
  const float* in; short* out; float scale;
  if (blockIdx.z == 0)      { in = Wql; out = WqlT; scale = 0.125f; }
  else if (blockIdx.z == 1) { in = Wkl; out = WklT; scale = 1.0f; }
  else                      { in = Wvl; out = WvlT; scale = 1.0f; }
  const int tid = threadIdx.x;
  const int k0 = blockIdx.y * 64;
  const int rr = tid >> 4, cc = tid & 15;
#pragma unroll
  for (int ii = 0; ii < 4; ++ii) {
    const int kr = rr + ii * 16;
    const float4 v = *(const float4*)&in[(size_t)(k0 + kr) * kL + cc * 4];
    T[kr][cc * 4 + 0] = v.x * scale; T[kr][cc * 4 + 1] = v.y * scale;
    T[kr][cc * 4 + 2] = v.z * scale; T[kr][cc * 4 + 3] = v.w * scale;
  }
  __syncthreads();
#pragma unroll
  for (int ii = 0; ii < 4; ++ii) {
    const int n = rr + ii * 16;
    const short4 s4 = make_short4(f2bf(T[cc * 4 + 0][n]), f2bf(T[cc * 4 + 1][n]),
                                  f2bf(T[cc * 4 + 2][n]), f2bf(T[cc * 4 + 3][n]));
    *(short4*)&out[(size_t)n * kD + k0 + cc * 4] = s4;
  }
}

// ---------------------------------------------------------------------------
// 256x256 2-deep pipelined bf16 MFMA GEMM for QKV (T2 swizzle + counted
// vmcnt + T5 setprio). C = A[M,K] @ Bt[N,K]^T, bf16 out split q/k/v.
// 512 threads = 8 waves (2M x 4N); per-wave 128x64 output; BK=64.
// Pipeline: at tile t's start, issue ALL of tile t+1 (8 gload16/thread,
// into the buffer last read at tile t-1, sealed by the bottom barrier),
// then s_waitcnt vmcnt(8) (tile t's loads drain; t+1's 8 stay in flight)
// + raw s_barrier (per-wave vmcnt + barrier => collective completeness).
// No vmcnt(0) drain in the loop. Issue distance = one full K-tile (~640cy).
// Swizzle: 16B block blk ^= row&7 on the global SOURCE (LDS linear) and on
// the ds_read address (both-sides rule); fragment indexing refcheck'd in R6.
// ---------------------------------------------------------------------------
__global__ __launch_bounds__(512) void gemm_qkv8(
    const short* __restrict__ A, const short* __restrict__ Bt,
    short* __restrict__ C0, short* __restrict__ C1, short* __restrict__ C2,
    int K) {
  __shared__ short As[2][256 * 64];
  __shared__ short Bs[2][256 * 64];
  const int tid = threadIdx.x;
  const int lane = tid & 63, w = tid >> 6;
  const int lr = lane & 15, lk = lane >> 4;
  const int wm = w >> 2, wn = w & 3;
  const int2 sw = xcd_swz(kNQKV / 256, kTok / 256);   // 12 x 16 = 192 blocks
  const int row0 = sw.y * 256, col0 = sw.x * 256;
  const int NT = K >> 6;                               // 32

  auto stage = [&](int kt) {
    const int b = kt & 1;
    const int k0 = kt << 6;
#pragma unroll
    for (int j = 0; j < 4; ++j) {
      const int idx = j * 512 + tid;
      const int row = idx >> 3, blk = idx & 7;
      const int gcol = k0 + ((blk ^ (row & 7)) << 3);
      gload16(A + (size_t)(row0 + row) * K + gcol, &As[b][row * 64 + blk * 8]);
    }
#pragma unroll
    for (int j = 0; j < 4; ++j) {
      const int idx = j * 512 + tid;
      const int row = idx >> 3, blk = idx & 7;
      const int gcol = k0 + ((blk ^ (row & 7)) << 3);
      gload16(Bt + (size_t)(col0 + row) * K + gcol, &Bs[b][row * 64 + blk * 8]);
    }
  };

  f32x4 acc[8][4] = {};

  stage(0);
  for (int t = 0; t < NT; ++t) {
    const int b = t & 1;
    if (t + 1 < NT) {
      stage(t + 1);                                     // 2-deep prefetch
      asm volatile("s_waitcnt vmcnt(8)" ::: "memory");  // tile t drained
    } else {
      asm volatile("s_waitcnt vmcnt(0)" ::: "memory");
    }
    __builtin_amdgcn_s_barrier();                       // collective ready

#pragma unroll
    for (int q = 0; q < 4; ++q) {                       // quadrant phases
      const int qm = q >> 1, qn = q & 1;
      bf16x8 a[4][2], bb[2][2];
#pragma unroll
      for (int j = 0; j < 4; ++j) {
        const int row = wm * 128 + (qm * 4 + j) * 16 + lr;
#pragma unroll
        for (int ch = 0; ch < 2; ++ch) {
          const int blk = (ch * 4 + lk) ^ (row & 7);
          a[j][ch] = *(const bf16x8*)&As[b][row * 64 + blk * 8];
        }
      }
#pragma unroll
      for (int n = 0; n < 2; ++n) {
        const int row = wn * 64 + (qn * 2 + n) * 16 + lr;
#pragma unroll
        for (int ch = 0; ch < 2; ++ch) {
          const int blk = (ch * 4 + lk) ^ (row & 7);
          bb[n][ch] = *(const bf16x8*)&Bs[b][row * 64 + blk * 8];
        }
      }
      __builtin_amdgcn_s_setprio(1);
#pragma unroll
      for (int j = 0; j < 4; ++j)
#pragma unroll
        for (int n = 0; n < 2; ++n)
#pragma unroll
          for (int ch = 0; ch < 2; ++ch)
            acc[qm * 4 + j][qn * 2 + n] = __builtin_amdgcn_mfma_f32_16x16x32_bf16(
                a[j][ch], bb[n][ch], acc[qm * 4 + j][qn * 2 + n], 0, 0, 0);
      __builtin_amdgcn_s_setprio(0);
    }
    __builtin_amdgcn_s_barrier();   // all waves done reading buf b
  }

  // epilogue: bf16 out, QKV split by block col (block-uniform)
  short* dst; int ld, cb;
  if (col0 < 2048)      { dst = C0; ld = 2048; cb = col0; }
  else if (col0 < 2560) { dst = C1; ld = 512;  cb = col0 - 2048; }
  else                  { dst = C2; ld = 512;  cb = col0 - 2560; }
  const int crow0 = row0 + wm * 128 + lk * 4;
  const int ccol0 = cb + wn * 64 + lr;
#pragma unroll
  for (int mf = 0; mf < 8; ++mf)
#pragma unroll
    for (int nf = 0; nf < 4; ++nf)
#pragma unroll
      for (int r = 0; r < 4; ++r)
        dst[(size_t)(crow0 + mf * 16 + r) * ld + ccol0 + nf * 16] =
            f2bf(acc[mf][nf][r]);
}

// ---------------------------------------------------------------------------
// bf16 MFMA GEMM (m97): fp32-output variant for the final K=1024 GEMM.
// ---------------------------------------------------------------------------
__global__ __launch_bounds__(256) void gemm_mfma(
    const short* __restrict__ A, const short* __restrict__ Bt,
    float* __restrict__ C0, int M, int N, int K) {
  __shared__ short As[128 * 32];
  __shared__ short Bs[128 * 32];
  const int tid = threadIdx.x;
  const int l = tid & 63, w = tid >> 6;
  const int lr = l & 15, lk = l >> 4;
  const int wm = w >> 1, wn = w & 1;
  const int2 sw = xcd_swz(N / 128, M / 128);
  const int row0 = sw.y * 128, col0 = sw.x * 128;

  f32x4 acc[4][4] = {};

  for (int k0 = 0; k0 < K; k0 += 32) {
    __syncthreads();
#pragma unroll
    for (int j = 0; j < 2; ++j) {
      const int idx = j * 256 + tid;
      const int r = idx >> 2, c = idx & 3;
      gload16(A  + (size_t)(row0 + r) * K + k0 + c * 8, &As[idx * 8]);
      gload16(Bt + (size_t)(col0 + r) * K + k0 + c * 8, &Bs[idx * 8]);
    }
    __syncthreads();
    bf16x8 af[4], bfr[4];
#pragma unroll
    for (int m = 0; m < 4; ++m)
      af[m] = *(const bf16x8*)&As[(wm * 64 + m * 16 + lr) * 32 + lk * 8];
#pragma unroll
    for (int n = 0; n < 4; ++n)
      bfr[n] = *(const bf16x8*)&Bs[(wn * 64 + n * 16 + lr) * 32 + lk * 8];
#pragma unroll
    for (int m = 0; m < 4; ++m)
#pragma unroll
      for (int n = 0; n < 4; ++n)
        acc[m][n] = __builtin_amdgcn_mfma_f32_16x16x32_bf16(af[m], bfr[n],
                                                            acc[m][n], 0, 0, 0);
  }

  const int crow0 = row0 + wm * 64 + lk * 4;
  const int ccol0 = col0 + wn * 64 + lr;
#pragma unroll
  for (int m = 0; m < 4; ++m)
#pragma unroll
    for (int n = 0; n < 4; ++n)
#pragma unroll
      for (int rr = 0; rr < 4; ++rr)
        C0[(size_t)(crow0 + m * 16 + rr) * N + ccol0 + n * 16] = acc[m][n][rr];
}

// ---------------------------------------------------------------------------
// Fused RoPE + latent projection (MFMA), bf16 input, all three tensors in
// one dispatch. grid = (kS/64, 48): y<32 -> q (ROPE), y<40 -> k (ROPE),
// y>=40 -> v (no RoPE, transposed [l][S] output). Branches block-uniform.
// ---------------------------------------------------------------------------
__global__ __launch_bounds__(256) void rope_latent_all(
    const short* __restrict__ qb, const short* __restrict__ kb,
    const short* __restrict__ vb, const short* __restrict__ WqlT,
    const short* __restrict__ WklT, const short* __restrict__ WvlT,
    const float* __restrict__ tbl, short* __restrict__ q_l,
    short* __restrict__ k_l, short* __restrict__ v_lT) {
  __shared__ short Tw[4][1280];
  const int yz = blockIdx.y;
  const short* in; const short* WT; short* out; int nh; bool ROPE, TR;
  int bh;
  if (yz < 32)      { in = qb; WT = WqlT; out = q_l;  nh = kH;   ROPE = true;  TR = false; bh = yz; }
  else if (yz < 40) { in = kb; WT = WklT; out = k_l;  nh = kHKV; ROPE = true;  TR = false; bh = yz - 32; }
  else              { in = vb; WT = WvlT; out = v_lT; nh = kHKV; ROPE = false; TR = true;  bh = yz - 40; }

  const int tid = threadIdx.x;
  const int lane = tid & 63;
  const int w = tid >> 6;
  const int lr = lane & 15;
  const int lk = lane >> 4;
  const int b = bh / nh, h = bh % nh;
  const int s0 = blockIdx.x * 64;
  const int srow = s0 + w * 16 + lr;
  const int tok = b * kS + srow;

  const short* ip = in + ((size_t)tok * nh + h) * kD + lk * 8;
  bf16x8 raw[4];
#pragma unroll
  for (int ch = 0; ch < 4; ++ch) raw[ch] = *(const bf16x8*)(ip + ch * 32);

  bf16x8 af[4];
  if (ROPE) {
    float a[4][8];
#pragma unroll
    for (int ch = 0; ch < 4; ++ch)
#pragma unroll
      for (int i = 0; i < 8; ++i) a[ch][i] = bf2f(raw[ch][i]);
    const float* tb = tbl + (size_t)tok * 128;
    float c[2][8], sn[2][8];
#pragma unroll
    for (int g = 0; g < 2; ++g) {
      const float4 cA = *(const float4*)(tb + g * 32 + lk * 8);
      const float4 cB = *(const float4*)(tb + g * 32 + lk * 8 + 4);
      const float4 sA = *(const float4*)(tb + 64 + g * 32 + lk * 8);
      const float4 sB = *(const float4*)(tb + 64 + g * 32 + lk * 8 + 4);
      c[g][0] = cA.x; c[g][1] = cA.y; c[g][2] = cA.z; c[g][3] = cA.w;
      c[g][4] = cB.x; c[g][5] = cB.y; c[g][6] = cB.z; c[g][7] = cB.w;
      sn[g][0] = sA.x; sn[g][1] = sA.y; sn[g][2] = sA.z; sn[g][3] = sA.w;
      sn[g][4] = sB.x; sn[g][5] = sB.y; sn[g][6] = sB.z; sn[g][7] = sB.w;
    }
    float o[4][8];
#pragma unroll
    for (int g = 0; g < 2; ++g)
#pragma unroll
      for (int i = 0; i < 8; ++i) {
        o[g][i]     = a[g][i]     * c[g][i] - a[g + 2][i] * sn[g][i];
        o[g + 2][i] = a[g + 2][i] * c[g][i] + a[g][i]     * sn[g][i];
      }
#pragma unroll
    for (int ch = 0; ch < 4; ++ch)
#pragma unroll
      for (int i = 0; i < 8; ++i) af[ch][i] = f2bf(o[ch][i]);
  } else {
#pragma unroll
    for (int ch = 0; ch < 4; ++ch) af[ch] = raw[ch];
  }

  f32x4 acc[4] = {};
#pragma unroll
  for (int cb = 0; cb < 4; ++cb) {
#pragma unroll
    for (int ch = 0; ch < 4; ++ch) {
      const bf16x8 bfrag =
          *(const bf16x8*)&WT[(size_t)(cb * 16 + lr) * kD + ch * 32 + lk * 8];
      acc[cb] = __builtin_amdgcn_mfma_f32_16x16x32_bf16(af[ch], bfrag,
                                                        acc[cb], 0, 0, 0);
    }
  }

  short* T = Tw[w];
  if (!TR) {
#pragma unroll
    for (int cb = 0; cb < 4; ++cb)
#pragma unroll
      for (int r = 0; r < 4; ++r)
        T[(lk * 4 + r) * 72 + cb * 16 + lr] = f2bf(acc[cb][r]);
    asm volatile("s_waitcnt lgkmcnt(0)" ::: "memory");
#pragma unroll
    for (int it = 0; it < 2; ++it) {
      const int idx = it * 64 + lane;
      const int row = idx >> 3, c8 = (idx & 7) << 3;
      *(bf16x8*)&out[((size_t)bh * kS + s0 + w * 16 + row) * kL + c8] =
          *(const bf16x8*)&T[row * 72 + c8];
    }
  } else {
#pragma unroll
    for (int cb = 0; cb < 4; ++cb)
#pragma unroll
      for (int r = 0; r < 4; ++r)
        T[(cb * 16 + lr) * 20 + lk * 4 + r] = f2bf(acc[cb][r]);
    asm volatile("s_waitcnt lgkmcnt(0)" ::: "memory");
    const size_t orow = ((size_t)bh * kL + lane) * kS + s0 + w * 16;
#pragma unroll
    for (int c = 0; c < 4; ++c)
      *(short4*)&out[orow + c * 4] = *(const short4*)&T[lane * 20 + c * 4];
  }
}

// ---------------------------------------------------------------------------
// MFMA flash attention, causal, bf16 in/out (fp32 accumulate).
// T14 async dbuf, 1 barrier/tile; T13 defer-max; load-balanced grid.
// ---------------------------------------------------------------------------
__global__ __launch_bounds__(512) void flash_attn_mfma(
    const short* __restrict__ ql, const short* __restrict__ kl,
    const short* __restrict__ vlT, short* __restrict__ attn_out) {
  constexpr int LDK = 72;
  __shared__ short Kt[2][64 * LDK];
  __shared__ short Vt[2][64 * LDK];            // row = latent l, col = key
  __shared__ short Pt[128 * LDK];

  const int tid = threadIdx.x;
  const int lane = tid & 63;
  const int w = tid >> 6;
  const int lr = lane & 15;
  const int lk = lane >> 4;
  const int bid = blockIdx.y;
  const int bx = (bid < 8) ? (2 * bid) : (31 - 2 * bid);   // load-balance remap
  const int q0 = bx * 128;
  const int bh = blockIdx.x;
  const int b = bh >> 4, h = bh & 15;
  const int hk = h >> 2;
  const int wrow = q0 + w * 16;

  const short* qrow = ql + ((size_t)bh * kS + wrow + lr) * kL;
  bf16x8 qf[2];
  qf[0] = *(const bf16x8*)(qrow + lk * 8);
  qf[1] = *(const bf16x8*)(qrow + 32 + lk * 8);

  f32x4 Of[4] = {};
  float m_r[4], l_r[4];
#pragma unroll
  for (int r = 0; r < 4; ++r) { m_r[r] = -3.0e38f; l_r[r] = 0.f; }

  const size_t kbase = (size_t)(b * kHKV + hk) * kS * kL;
  const size_t vbase = (size_t)(b * kHKV + hk) * kL * kS;
  const int ntiles = q0 / 64 + 2;
  const int sr = tid >> 3, sc8 = (tid & 7) << 3;
  const short* kp = kl + kbase + (size_t)sr * kL + sc8;
  const short* vp = vlT + vbase + (size_t)sr * kS + sc8;

  *(bf16x8*)&Kt[0][sr * LDK + sc8] = *(const bf16x8*)kp;
  *(bf16x8*)&Vt[0][sr * LDK + sc8] = *(const bf16x8*)vp;
  __syncthreads();

  int cur = 0;
  for (int t = 0; t < ntiles; ++t) {
    const int j0 = t * 64;
    const bool pre = (t + 1 < ntiles);
    bf16x8 krn, vrn;
    if (pre) {
      krn = *(const bf16x8*)(kp + (size_t)(j0 + 64) * kL);
      vrn = *(const bf16x8*)(vp + (j0 + 64));
    }

    if (j0 <= wrow) {
      const short* Kc = &Kt[cur][0];
      const short* Vc = &Vt[cur][0];

      f32x4 Sf[4];
      __builtin_amdgcn_s_setprio(1);
#pragma unroll
      for (int cb = 0; cb < 4; ++cb) {
        f32x4 acc = {};
#pragma unroll
        for (int ch = 0; ch < 2; ++ch) {
          const bf16x8 kf = *(const bf16x8*)&Kc[(cb * 16 + lr) * LDK + ch * 32 + lk * 8];
          acc = __builtin_amdgcn_mfma_f32_16x16x32_bf16(qf[ch], kf, acc, 0, 0, 0);
        }
        Sf[cb] = acc;
      }
      __builtin_amdgcn_s_setprio(0);

      const bool diag = (j0 + 63 > wrow);
      float mt[4] = {-3.0e38f, -3.0e38f, -3.0e38f, -3.0e38f};
#pragma unroll
      for (int cb = 0; cb < 4; ++cb)
#pragma unroll
        for (int r = 0; r < 4; ++r) {
          float s = Sf[cb][r];
          if (diag && (j0 + cb * 16 + lr) > (wrow + lk * 4 + r)) s = -3.0e38f;
          Sf[cb][r] = s;
          mt[r] = fmaxf(mt[r], s);
        }
#pragma unroll
      for (int d = 1; d < 16; d <<= 1)
#pragma unroll
        for (int r = 0; r < 4; ++r) mt[r] = fmaxf(mt[r], __shfl_xor(mt[r], d));

      const bool need = (mt[0] > m_r[0] + 8.f) || (mt[1] > m_r[1] + 8.f) ||
                        (mt[2] > m_r[2] + 8.f) || (mt[3] > m_r[3] + 8.f);
      const bool resc = __any((int)need);
      float corr[4] = {1.f, 1.f, 1.f, 1.f};
      if (resc) {
#pragma unroll
        for (int r = 0; r < 4; ++r) {
          const float mnew = fmaxf(m_r[r], mt[r]);
          corr[r] = __expf(m_r[r] - mnew);
          m_r[r] = mnew;
          l_r[r] *= corr[r];
        }
      }
#pragma unroll
      for (int cb = 0; cb < 4; ++cb) {
        const float p0 = __expf(Sf[cb][0] - m_r[0]);
        const float p1 = __expf(Sf[cb][1] - m_r[1]);
        const float p2 = __expf(Sf[cb][2] - m_r[2]);
        const float p3 = __expf(Sf[cb][3] - m_r[3]);
        l_r[0] += p0; l_r[1] += p1; l_r[2] += p2; l_r[3] += p3;
        const unsigned pk01 = cvt_pk_bf16(p0, p1);
        const unsigned pk23 = cvt_pk_bf16(p2, p3);
        short* prow = &Pt[(w * 16 + lk * 4) * LDK + cb * 16 + lr];
        prow[0 * LDK] = (short)(pk01 & 0xffff);
        prow[1 * LDK] = (short)(pk01 >> 16);
        prow[2 * LDK] = (short)(pk23 & 0xffff);
        prow[3 * LDK] = (short)(pk23 >> 16);
      }
      asm volatile("s_waitcnt lgkmcnt(0)" ::: "memory");

      __builtin_amdgcn_s_setprio(1);
#pragma unroll
      for (int cb = 0; cb < 4; ++cb) {
        f32x4 acc = Of[cb];
        if (resc) {
#pragma unroll
          for (int r = 0; r < 4; ++r) acc[r] *= corr[r];
        }
#pragma unroll
        for (int ch = 0; ch < 2; ++ch) {
          const bf16x8 pf = *(const bf16x8*)&Pt[(w * 16 + lr) * LDK + ch * 32 + lk * 8];
          const bf16x8 vf = *(const bf16x8*)&Vc[(cb * 16 + lr) * LDK + ch * 32 + lk * 8];
          acc = __builtin_amdgcn_mfma_f32_16x16x32_bf16(pf, vf, acc, 0, 0, 0);
        }
        Of[cb] = acc;
      }
      __builtin_amdgcn_s_setprio(0);
    }

    if (pre) {
      *(bf16x8*)&Kt[cur ^ 1][sr * LDK + sc8] = krn;
      *(bf16x8*)&Vt[cur ^ 1][sr * LDK + sc8] = vrn;
    }
    __syncthreads();
    cur ^= 1;
  }

#pragma unroll
  for (int d = 1; d < 16; d <<= 1)
#pragma unroll
    for (int r = 0; r < 4; ++r) l_r[r] += __shfl_xor(l_r[r], d);

#pragma unroll
  for (int r = 0; r < 4; ++r) {
    const float inv = 1.f / l_r[r];
    const size_t row = (size_t)(b * kS + wrow + lk * 4 + r) * (kH * kL);
#pragma unroll
    for (int cb = 0; cb < 4; ++cb)
      attn_out[row + h * kL + cb * 16 + lr] = f2bf(Of[cb][r] * inv);
  }
}

// ---------------------------------------------------------------------------
extern "C" void kernel_launch(void* const* d_in, const int* in_sizes, int n_in,
                              void* d_out, int out_size, void* d_ws, size_t ws_size,
                              hipStream_t stream) {
  const float* x    = (const float*)d_in[0];
  const int*   pos  = (const int*)d_in[1];
  const float* Wq   = (const float*)d_in[3];
  const float* Wk   = (const float*)d_in[4];
  const float* Wv   = (const float*)d_in[5];
  const float* Wql  = (const float*)d_in[6];
  const float* Wkl  = (const float*)d_in[7];
  const float* Wvl  = (const float*)d_in[8];
  const float* Wo   = (const float*)d_in[9];
  float* out = (float*)d_out;

  // Workspace carve (q_buf bf16 reuses d_out: 16 MB of its 32 MB)
  char* p = (char*)d_ws;
  short* x_bf  = (short*)p; p += (size_t)kTok * kHID * 2;        // 16 MB
  short* Wqkv  = (short*)p; p += (size_t)kNQKV * kHID * 2;       // 12.6 MB
  short* WoT   = (short*)p; p += (size_t)kHID * (kH * kL) * 2;   // 4 MB
  short* WqlT  = (short*)p; p += (size_t)kL * kD * 2;            // 16 KB
  short* WklT  = (short*)p; p += (size_t)kL * kD * 2;
  short* WvlT  = (short*)p; p += (size_t)kL * kD * 2;
  float* tbl   = (float*)p; p += (size_t)kTok * 128 * 4;         // 2 MB
  short* k_buf = (short*)p; p += (size_t)kTok * kHKV * kD * 2;   // 4 MB
  short* v_buf = (short*)p; p += (size_t)kTok * kHKV * kD * 2;   // 4 MB
  short* q_l   = (short*)p; p += (size_t)kB * kH * kS * kL * 2;  // 8 MB
  short* k_l   = (short*)p; p += (size_t)kB * kHKV * kS * kL * 2;
  short* v_lT  = (short*)p; p += (size_t)kB * kHKV * kS * kL * 2;
  short* attn  = (short*)p;                                      // 8 MB
  short* q_buf = (short*)d_out;   // bf16 scratch until final GEMM

  // 0) dtype prep
  cvt_bf16<<<kTok * kHID / 8 / 256, 256, 0, stream>>>(x, x_bf, kTok * kHID / 8);
  trig_table<<<kTok * 64 / 256, 256, 0, stream>>>(pos, tbl);
  transpose_cvt<false><<<dim3(kH * kD / 64, kHID / 64), 256, 0, stream>>>(
      Wq, Wqkv, kH * kD, kHID, 0, 1.0f);
  transpose_cvt<false><<<dim3(kHKV * kD / 64, kHID / 64), 256, 0, stream>>>(
      Wk, Wqkv, kHKV * kD, kHID, kH * kD, 1.0f);
  transpose_cvt<false><<<dim3(kHKV * kD / 64, kHID / 64), 256, 0, stream>>>(
      Wv, Wqkv, kHKV * kD, kHID, kH * kD + kHKV * kD, 1.0f);
  transpose_cvt<true><<<dim3(kHID / 64, (kH * kL) / 64), 256, 0, stream>>>(
      Wo, WoT, kHID, kH * kL, 0, 1.0f);
  transpose_lat3<<<dim3(1, kD / 64, 3), 256, 0, stream>>>(
      Wql, Wkl, Wvl, WqlT, WklT, WvlT);

  // 1) Fused QKV projection — 256² 2-deep counted-vmcnt MFMA GEMM
  gemm_qkv8<<<dim3(kNQKV / 256, kTok / 256), 512, 0, stream>>>(
      x_bf, Wqkv, q_buf, k_buf, v_buf, kHID);

  // 2) Fused RoPE + latent projections — single dispatch
  rope_latent_all<<<dim3(kS / 64, 48), 256, 0, stream>>>(
      q_buf, k_buf, v_buf, WqlT, WklT, WvlT, tbl, q_l, k_l, v_lT);

  // 3) MFMA flash attention (T14 async dbuf, 1 barrier/tile)
  flash_attn_mfma<<<dim3(kB * kH, kS / 128), 512, 0, stream>>>(
      q_l, k_l, v_lT, attn);

  // 4) Output GEMM (m97 MFMA, fp32 out, XCD swizzle)
  gemm_mfma<<<dim3(kHID / 128, kTok / 128), 256, 0, stream>>>(
      attn, WoT, out, kTok, kHID, kH * kL);
}

// Round 11
// 211.713 us; speedup vs baseline: 1.2147x; 1.0256x over previous
//
#include <hip/hip_runtime.h>
#include <cstddef>

// Problem constants
constexpr int kB   = 2;
constexpr int kS   = 2048;
constexpr int kHID = 2048;
constexpr int kH   = 16;
constexpr int kHKV = 4;
constexpr int kD   = 128;
constexpr int kL   = 64;
constexpr int kTok = kB * kS;             // 4096 tokens
constexpr int kNQKV = kH * kD + 2 * kHKV * kD;  // 3072 fused QKV cols

typedef __attribute__((ext_vector_type(8))) short bf16x8;
typedef __attribute__((ext_vector_type(4))) float f32x4;

static __device__ __forceinline__ short f2bf(float f) {
  union { float f; unsigned u; } v{f};
  const unsigned r = (v.u + 0x7fff + ((v.u >> 16) & 1)) >> 16;
  return (short)r;
}
static __device__ __forceinline__ float bf2f(short s) {
  union { unsigned u; float f; } v;
  v.u = ((unsigned)(unsigned short)s) << 16;
  return v.f;
}

static __device__ __forceinline__ bf16x8 pack8(float4 a, float4 b) {
  bf16x8 r;
  r[0] = f2bf(a.x); r[1] = f2bf(a.y); r[2] = f2bf(a.z); r[3] = f2bf(a.w);
  r[4] = f2bf(b.x); r[5] = f2bf(b.y); r[6] = f2bf(b.z); r[7] = f2bf(b.w);
  return r;
}

// packed fp32x2 -> bf16x2 (exact RTN) — no builtin on gfx950, inline asm
static __device__ __forceinline__ unsigned cvt_pk_bf16(float lo, float hi) {
  unsigned r;
  asm("v_cvt_pk_bf16_f32 %0, %1, %2" : "=v"(r) : "v"(lo), "v"(hi));
  return r;
}

// async global->LDS, 16B per lane. LDS dest must be wave-uniform base + lane*16.
typedef __attribute__((address_space(3))) void       lds_void;
typedef __attribute__((address_space(1))) const void gm_void;
static __device__ __forceinline__ void gload16(const void* g, void* l) {
  __builtin_amdgcn_global_load_lds((gm_void*)g, (lds_void*)l, 16, 0, 0);
}

// T1: bijective XCD-aware block swizzle (requires nwg % 8 == 0)
static __device__ __forceinline__ int2 xcd_swz(int nx, int ny) {
  int wg = blockIdx.y * nx + blockIdx.x;
  const int cpx = (nx * ny) >> 3;
  wg = (wg & 7) * cpx + (wg >> 3);
  int2 r; r.x = wg % nx; r.y = wg / nx;
  return r;
}

// ---------------------------------------------------------------------------
// fp32 -> bf16 elementwise (8 elems / thread)
// ---------------------------------------------------------------------------
__global__ __launch_bounds__(256) void cvt_bf16(const float* __restrict__ in,
                                                short* __restrict__ out, int n8) {
  const int i = blockIdx.x * 256 + threadIdx.x;
  if (i >= n8) return;
  const float4 a = *(const float4*)&in[i * 8];
  const float4 b = *(const float4*)&in[i * 8 + 4];
  *(bf16x8*)&out[i * 8] = pack8(a, b);
}

// ---------------------------------------------------------------------------
// Per-token RoPE cos/sin table
// ---------------------------------------------------------------------------
__global__ __launch_bounds__(256) void trig_table(const int* __restrict__ pos,
                                                  float* __restrict__ tbl) {
  const int idx = blockIdx.x * 256 + threadIdx.x;
  if (idx >= kTok * 64) return;
  const int i = idx & 63, t = idx >> 6;
  const float p = (float)pos[t];
  const float inv_freq = expf(-(float)i * (9.210340371976184f / 64.0f));
  const float ang = p * inv_freq;
  tbl[t * 128 + i]      = cosf(ang);
  tbl[t * 128 + 64 + i] = sinf(ang);
}

// ---------------------------------------------------------------------------
// Transpose + convert + scale: out[row_off+n][k] (bf16, ld) = in[rmap(k)][n]*scale
// ---------------------------------------------------------------------------
template <bool REMAP>
__global__ __launch_bounds__(256) void transpose_cvt(
    const float* __restrict__ in, short* __restrict__ out,
    int Nin, int out_ld, int row_off, float scale) {
  __shared__ float T[64][65];
  const int tid = threadIdx.x;
  const int k0 = blockIdx.y * 64, n0 = blockIdx.x * 64;
  const int rr = tid >> 4;
  const int cc = tid & 15;
#pragma unroll
  for (int ii = 0; ii < 4; ++ii) {
    const int kr = rr + ii * 16;
    int gr = k0 + kr;
    if (REMAP) gr = ((gr >> 6) << 7) + (gr & 63);
    const float4 v = *(const float4*)&in[(size_t)gr * Nin + n0 + cc * 4];
    T[kr][cc * 4 + 0] = v.x * scale; T[kr][cc * 4 + 1] = v.y * scale;
    T[kr][cc * 4 + 2] = v.z * scale; T[kr][cc * 4 + 3] = v.w * scale;
  }
  __syncthreads();
#pragma unroll
  for (int ii = 0; ii < 4; ++ii) {
    const int n = rr + ii * 16;
    const short4 s4 = make_short4(f2bf(T[cc * 4 + 0][n]), f2bf(T[cc * 4 + 1][n]),
                                  f2bf(T[cc * 4 + 2][n]), f2bf(T[cc * 4 + 3][n]));
    *(short4*)&out[(size_t)(row_off + n0 + n) * out_ld + k0 + cc * 4] = s4;
  }
}

// ---------------------------------------------------------------------------
// Three small latent-weight transposes (128x64 each) in one dispatch.
// ---------------------------------------------------------------------------
__global__ __launch_bounds__(256) void transpose_lat3(
    const float* __restrict__ Wql, const float* __restrict__ Wkl,
    const float* __restrict__ Wvl, short* __restrict__ WqlT,
    short* __restrict__ WklT, short* __restrict__ WvlT) {
  __shared__ float T[64][65];
  const float* in; short* out; float scale;
  if (blockIdx.z == 0)      { in = Wql; out = WqlT; scale = 0.125f; }
  else if (blockIdx.z == 1) { in = Wkl; out = WklT; scale = 1.0f; }
  else                      { in = Wvl; out = WvlT; scale = 1.0f; }
  const int tid = threadIdx.x;
  const int k0 = blockIdx.y * 64;
  const int rr = tid >> 4, cc = tid & 15;
#pragma unroll
  for (int ii = 0; ii < 4; ++ii) {
    const int kr = rr + ii * 16;
    const float4 v = *(const float4*)&in[(size_t)(k0 + kr) * kL + cc * 4];
    T[kr][cc * 4 + 0] = v.x * scale; T[kr][cc * 4 + 1] = v.y * scale;
    T[kr][cc * 4 + 2] = v.z * scale; T[kr][cc * 4 + 3] = v.w * scale;
  }
  __syncthreads();
#pragma unroll
  for (int ii = 0; ii < 4; ++ii) {
    const int n = rr + ii * 16;
    const short4 s4 = make_short4(f2bf(T[cc * 4 + 0][n]), f2bf(T[cc * 4 + 1][n]),
                                  f2bf(T[cc * 4 + 2][n]), f2bf(T[cc * 4 + 3][n]));
    *(short4*)&out[(size_t)n * kD + k0 + cc * 4] = s4;
  }
}

// ---------------------------------------------------------------------------
// 256x256 2-deep pipelined bf16 MFMA GEMM for QKV (T2 swizzle + counted
// vmcnt + T5 setprio + FULL REGISTER BLOCKING). C = A @ Bt^T, bf16 out.
// 512 threads = 8 waves (2M x 4N); per-wave 128x64 output; BK=64.
// LDS-read traffic is the bottleneck (R9 post-mortem): B-fragments are
// loaded ONCE per K-tile and A-fragments ONCE per qm-half — 24 KB/wave/tile,
// the no-redundancy minimum (R9's quadrant loop read 48 KB).
// Pipeline: issue all of tile t+1 at tile t's start; s_waitcnt vmcnt(8)
// (t's loads drained, t+1's 8 in flight) + raw s_barrier. No vmcnt(0) drain.
// ---------------------------------------------------------------------------
__global__ __launch_bounds__(512) void gemm_qkv8(
    const short* __restrict__ A, const short* __restrict__ Bt,
    short* __restrict__ C0, short* __restrict__ C1, short* __restrict__ C2,
    int K) {
  __shared__ short As[2][256 * 64];
  __shared__ short Bs[2][256 * 64];
  const int tid = threadIdx.x;
  const int lane = tid & 63, w = tid >> 6;
  const int lr = lane & 15, lk = lane >> 4;
  const int wm = w >> 2, wn = w & 3;
  const int2 sw = xcd_swz(kNQKV / 256, kTok / 256);   // 12 x 16 = 192 blocks
  const int row0 = sw.y * 256, col0 = sw.x * 256;
  const int NT = K >> 6;                               // 32

  auto stage = [&](int kt) {
    const int b = kt & 1;
    const int k0 = kt << 6;
#pragma unroll
    for (int j = 0; j < 4; ++j) {
      const int idx = j * 512 + tid;
      const int row = idx >> 3, blk = idx & 7;
      const int gcol = k0 + ((blk ^ (row & 7)) << 3);
      gload16(A + (size_t)(row0 + row) * K + gcol, &As[b][row * 64 + blk * 8]);
    }
#pragma unroll
    for (int j = 0; j < 4; ++j) {
      const int idx = j * 512 + tid;
      const int row = idx >> 3, blk = idx & 7;
      const int gcol = k0 + ((blk ^ (row & 7)) << 3);
      gload16(Bt + (size_t)(col0 + row) * K + gcol, &Bs[b][row * 64 + blk * 8]);
    }
  };

  f32x4 acc[8][4] = {};

  stage(0);
  for (int t = 0; t < NT; ++t) {
    const int b = t & 1;
    if (t + 1 < NT) {
      stage(t + 1);                                     // 2-deep prefetch
      asm volatile("s_waitcnt vmcnt(8)" ::: "memory");  // tile t drained
    } else {
      asm volatile("s_waitcnt vmcnt(0)" ::: "memory");
    }
    __builtin_amdgcn_s_barrier();                       // collective ready

    // B-fragments: load ONCE per K-tile (held across both qm halves)
    bf16x8 bb[4][2];
#pragma unroll
    for (int n = 0; n < 4; ++n) {
      const int row = wn * 64 + n * 16 + lr;
#pragma unroll
      for (int ch = 0; ch < 2; ++ch) {
        const int blk = (ch * 4 + lk) ^ (row & 7);
        bb[n][ch] = *(const bf16x8*)&Bs[b][row * 64 + blk * 8];
      }
    }
#pragma unroll
    for (int qm = 0; qm < 2; ++qm) {                    // two m-halves
      bf16x8 a[4][2];
#pragma unroll
      for (int j = 0; j < 4; ++j) {
        const int row = wm * 128 + (qm * 4 + j) * 16 + lr;
#pragma unroll
        for (int ch = 0; ch < 2; ++ch) {
          const int blk = (ch * 4 + lk) ^ (row & 7);
          a[j][ch] = *(const bf16x8*)&As[b][row * 64 + blk * 8];
        }
      }
      __builtin_amdgcn_s_setprio(1);
#pragma unroll
      for (int j = 0; j < 4; ++j)
#pragma unroll
        for (int n = 0; n < 4; ++n)
#pragma unroll
          for (int ch = 0; ch < 2; ++ch)
            acc[qm * 4 + j][n] = __builtin_amdgcn_mfma_f32_16x16x32_bf16(
                a[j][ch], bb[n][ch], acc[qm * 4 + j][n], 0, 0, 0);
      __builtin_amdgcn_s_setprio(0);
    }
    __builtin_amdgcn_s_barrier();   // all waves done reading buf b
  }

  // epilogue: bf16 out, QKV split by block col (block-uniform)
  short* dst; int ld, cb;
  if (col0 < 2048)      { dst = C0; ld = 2048; cb = col0; }
  else if (col0 < 2560) { dst = C1; ld = 512;  cb = col0 - 2048; }
  else                  { dst = C2; ld = 512;  cb = col0 - 2560; }
  const int crow0 = row0 + wm * 128 + lk * 4;
  const int ccol0 = cb + wn * 64 + lr;
#pragma unroll
  for (int mf = 0; mf < 8; ++mf)
#pragma unroll
    for (int nf = 0; nf < 4; ++nf)
#pragma unroll
      for (int r = 0; r < 4; ++r)
        dst[(size_t)(crow0 + mf * 16 + r) * ld + ccol0 + nf * 16] =
            f2bf(acc[mf][nf][r]);
}

// ---------------------------------------------------------------------------
// bf16 MFMA GEMM (m97): fp32-output variant for the final K=1024 GEMM.
// ---------------------------------------------------------------------------
__global__ __launch_bounds__(256) void gemm_mfma(
    const short* __restrict__ A, const short* __restrict__ Bt,
    float* __restrict__ C0, int M, int N, int K) {
  __shared__ short As[128 * 32];
  __shared__ short Bs[128 * 32];
  const int tid = threadIdx.x;
  const int l = tid & 63, w = tid >> 6;
  const int lr = l & 15, lk = l >> 4;
  const int wm = w >> 1, wn = w & 1;
  const int2 sw = xcd_swz(N / 128, M / 128);
  const int row0 = sw.y * 128, col0 = sw.x * 128;

  f32x4 acc[4][4] = {};

  for (int k0 = 0; k0 < K; k0 += 32) {
    __syncthreads();
#pragma unroll
    for (int j = 0; j < 2; ++j) {
      const int idx = j * 256 + tid;
      const int r = idx >> 2, c = idx & 3;
      gload16(A  + (size_t)(row0 + r) * K + k0 + c * 8, &As[idx * 8]);
      gload16(Bt + (size_t)(col0 + r) * K + k0 + c * 8, &Bs[idx * 8]);
    }
    __syncthreads();
    bf16x8 af[4], bfr[4];
#pragma unroll
    for (int m = 0; m < 4; ++m)
      af[m] = *(const bf16x8*)&As[(wm * 64 + m * 16 + lr) * 32 + lk * 8];
#pragma unroll
    for (int n = 0; n < 4; ++n)
      bfr[n] = *(const bf16x8*)&Bs[(wn * 64 + n * 16 + lr) * 32 + lk * 8];
#pragma unroll
    for (int m = 0; m < 4; ++m)
#pragma unroll
      for (int n = 0; n < 4; ++n)
        acc[m][n] = __builtin_amdgcn_mfma_f32_16x16x32_bf16(af[m], bfr[n],
                                                            acc[m][n], 0, 0, 0);
  }

  const int crow0 = row0 + wm * 64 + lk * 4;
  const int ccol0 = col0 + wn * 64 + lr;
#pragma unroll
  for (int m = 0; m < 4; ++m)
#pragma unroll
    for (int n = 0; n < 4; ++n)
#pragma unroll
      for (int rr = 0; rr < 4; ++rr)
        C0[(size_t)(crow0 + m * 16 + rr) * N + ccol0 + n * 16] = acc[m][n][rr];
}

// ---------------------------------------------------------------------------
// Fused RoPE + latent projection (MFMA), bf16 input, all three tensors in
// one dispatch. grid = (kS/64, 48): y<32 -> q (ROPE), y<40 -> k (ROPE),
// y>=40 -> v (no RoPE, transposed [l][S] output). Branches block-uniform.
// ---------------------------------------------------------------------------
__global__ __launch_bounds__(256) void rope_latent_all(
    const short* __restrict__ qb, const short* __restrict__ kb,
    const short* __restrict__ vb, const short* __restrict__ WqlT,
    const short* __restrict__ WklT, const short* __restrict__ WvlT,
    const float* __restrict__ tbl, short* __restrict__ q_l,
    short* __restrict__ k_l, short* __restrict__ v_lT) {
  __shared__ short Tw[4][1280];
  const int yz = blockIdx.y;
  const short* in; const short* WT; short* out; int nh; bool ROPE, TR;
  int bh;
  if (yz < 32)      { in = qb; WT = WqlT; out = q_l;  nh = kH;   ROPE = true;  TR = false; bh = yz; }
  else if (yz < 40) { in = kb; WT = WklT; out = k_l;  nh = kHKV; ROPE = true;  TR = false; bh = yz - 32; }
  else              { in = vb; WT = WvlT; out = v_lT; nh = kHKV; ROPE = false; TR = true;  bh = yz - 40; }

  const int tid = threadIdx.x;
  const int lane = tid & 63;
  const int w = tid >> 6;
  const int lr = lane & 15;
  const int lk = lane >> 4;
  const int b = bh / nh, h = bh % nh;
  const int s0 = blockIdx.x * 64;
  const int srow = s0 + w * 16 + lr;
  const int tok = b * kS + srow;

  const short* ip = in + ((size_t)tok * nh + h) * kD + lk * 8;
  bf16x8 raw[4];
#pragma unroll
  for (int ch = 0; ch < 4; ++ch) raw[ch] = *(const bf16x8*)(ip + ch * 32);

  bf16x8 af[4];
  if (ROPE) {
    float a[4][8];
#pragma unroll
    for (int ch = 0; ch < 4; ++ch)
#pragma unroll
      for (int i = 0; i < 8; ++i) a[ch][i] = bf2f(raw[ch][i]);
    const float* tb = tbl + (size_t)tok * 128;
    float c[2][8], sn[2][8];
#pragma unroll
    for (int g = 0; g < 2; ++g) {
      const float4 cA = *(const float4*)(tb + g * 32 + lk * 8);
      const float4 cB = *(const float4*)(tb + g * 32 + lk * 8 + 4);
      const float4 sA = *(const float4*)(tb + 64 + g * 32 + lk * 8);
      const float4 sB = *(const float4*)(tb + 64 + g * 32 + lk * 8 + 4);
      c[g][0] = cA.x; c[g][1] = cA.y; c[g][2] = cA.z; c[g][3] = cA.w;
      c[g][4] = cB.x; c[g][5] = cB.y; c[g][6] = cB.z; c[g][7] = cB.w;
      sn[g][0] = sA.x; sn[g][1] = sA.y; sn[g][2] = sA.z; sn[g][3] = sA.w;
      sn[g][4] = sB.x; sn[g][5] = sB.y; sn[g][6] = sB.z; sn[g][7] = sB.w;
    }
    float o[4][8];
#pragma unroll
    for (int g = 0; g < 2; ++g)
#pragma unroll
      for (int i = 0; i < 8; ++i) {
        o[g][i]     = a[g][i]     * c[g][i] - a[g + 2][i] * sn[g][i];
        o[g + 2][i] = a[g + 2][i] * c[g][i] + a[g][i]     * sn[g][i];
      }
#pragma unroll
    for (int ch = 0; ch < 4; ++ch)
#pragma unroll
      for (int i = 0; i < 8; ++i) af[ch][i] = f2bf(o[ch][i]);
  } else {
#pragma unroll
    for (int ch = 0; ch < 4; ++ch) af[ch] = raw[ch];
  }

  f32x4 acc[4] = {};
#pragma unroll
  for (int cb = 0; cb < 4; ++cb) {
#pragma unroll
    for (int ch = 0; ch < 4; ++ch) {
      const bf16x8 bfrag =
          *(const bf16x8*)&WT[(size_t)(cb * 16 + lr) * kD + ch * 32 + lk * 8];
      acc[cb] = __builtin_amdgcn_mfma_f32_16x16x32_bf16(af[ch], bfrag,
                                                        acc[cb], 0, 0, 0);
    }
  }

  short* T = Tw[w];
  if (!TR) {
#pragma unroll
    for (int cb = 0; cb < 4; ++cb)
#pragma unroll
      for (int r = 0; r < 4; ++r)
        T[(lk * 4 + r) * 72 + cb * 16 + lr] = f2bf(acc[cb][r]);
    asm volatile("s_waitcnt lgkmcnt(0)" ::: "memory");
#pragma unroll
    for (int it = 0; it < 2; ++it) {
      const int idx = it * 64 + lane;
      const int row = idx >> 3, c8 = (idx & 7) << 3;
      *(bf16x8*)&out[((size_t)bh * kS + s0 + w * 16 + row) * kL + c8] =
          *(const bf16x8*)&T[row * 72 + c8];
    }
  } else {
#pragma unroll
    for (int cb = 0; cb < 4; ++cb)
#pragma unroll
      for (int r = 0; r < 4; ++r)
        T[(cb * 16 + lr) * 20 + lk * 4 + r] = f2bf(acc[cb][r]);
    asm volatile("s_waitcnt lgkmcnt(0)" ::: "memory");
    const size_t orow = ((size_t)bh * kL + lane) * kS + s0 + w * 16;
#pragma unroll
    for (int c = 0; c < 4; ++c)
      *(short4*)&out[orow + c * 4] = *(const short4*)&T[lane * 20 + c * 4];
  }
}

// ---------------------------------------------------------------------------
// MFMA flash attention, causal, bf16 in/out (fp32 accumulate).
// T14 async dbuf, 1 barrier/tile; T13 defer-max; load-balanced grid.
// ---------------------------------------------------------------------------
__global__ __launch_bounds__(512) void flash_attn_mfma(
    const short* __restrict__ ql, const short* __restrict__ kl,
    const short* __restrict__ vlT, short* __restrict__ attn_out) {
  constexpr int LDK = 72;
  __shared__ short Kt[2][64 * LDK];
  __shared__ short Vt[2][64 * LDK];            // row = latent l, col = key
  __shared__ short Pt[128 * LDK];

  const int tid = threadIdx.x;
  const int lane = tid & 63;
  const int w = tid >> 6;
  const int lr = lane & 15;
  const int lk = lane >> 4;
  const int bid = blockIdx.y;
  const int bx = (bid < 8) ? (2 * bid) : (31 - 2 * bid);   // load-balance remap
  const int q0 = bx * 128;
  const int bh = blockIdx.x;
  const int b = bh >> 4, h = bh & 15;
  const int hk = h >> 2;
  const int wrow = q0 + w * 16;

  const short* qrow = ql + ((size_t)bh * kS + wrow + lr) * kL;
  bf16x8 qf[2];
  qf[0] = *(const bf16x8*)(qrow + lk * 8);
  qf[1] = *(const bf16x8*)(qrow + 32 + lk * 8);

  f32x4 Of[4] = {};
  float m_r[4], l_r[4];
#pragma unroll
  for (int r = 0; r < 4; ++r) { m_r[r] = -3.0e38f; l_r[r] = 0.f; }

  const size_t kbase = (size_t)(b * kHKV + hk) * kS * kL;
  const size_t vbase = (size_t)(b * kHKV + hk) * kL * kS;
  const int ntiles = q0 / 64 + 2;
  const int sr = tid >> 3, sc8 = (tid & 7) << 3;
  const short* kp = kl + kbase + (size_t)sr * kL + sc8;
  const short* vp = vlT + vbase + (size_t)sr * kS + sc8;

  *(bf16x8*)&Kt[0][sr * LDK + sc8] = *(const bf16x8*)kp;
  *(bf16x8*)&Vt[0][sr * LDK + sc8] = *(const bf16x8*)vp;
  __syncthreads();

  int cur = 0;
  for (int t = 0; t < ntiles; ++t) {
    const int j0 = t * 64;
    const bool pre = (t + 1 < ntiles);
    bf16x8 krn, vrn;
    if (pre) {
      krn = *(const bf16x8*)(kp + (size_t)(j0 + 64) * kL);
      vrn = *(const bf16x8*)(vp + (j0 + 64));
    }

    if (j0 <= wrow) {
      const short* Kc = &Kt[cur][0];
      const short* Vc = &Vt[cur][0];

      f32x4 Sf[4];
      __builtin_amdgcn_s_setprio(1);
#pragma unroll
      for (int cb = 0; cb < 4; ++cb) {
        f32x4 acc = {};
#pragma unroll
        for (int ch = 0; ch < 2; ++ch) {
          const bf16x8 kf = *(const bf16x8*)&Kc[(cb * 16 + lr) * LDK + ch * 32 + lk * 8];
          acc = __builtin_amdgcn_mfma_f32_16x16x32_bf16(qf[ch], kf, acc, 0, 0, 0);
        }
        Sf[cb] = acc;
      }
      __builtin_amdgcn_s_setprio(0);

      const bool diag = (j0 + 63 > wrow);
      float mt[4] = {-3.0e38f, -3.0e38f, -3.0e38f, -3.0e38f};
#pragma unroll
      for (int cb = 0; cb < 4; ++cb)
#pragma unroll
        for (int r = 0; r < 4; ++r) {
          float s = Sf[cb][r];
          if (diag && (j0 + cb * 16 + lr) > (wrow + lk * 4 + r)) s = -3.0e38f;
          Sf[cb][r] = s;
          mt[r] = fmaxf(mt[r], s);
        }
#pragma unroll
      for (int d = 1; d < 16; d <<= 1)
#pragma unroll
        for (int r = 0; r < 4; ++r) mt[r] = fmaxf(mt[r], __shfl_xor(mt[r], d));

      const bool need = (mt[0] > m_r[0] + 8.f) || (mt[1] > m_r[1] + 8.f) ||
                        (mt[2] > m_r[2] + 8.f) || (mt[3] > m_r[3] + 8.f);
      const bool resc = __any((int)need);
      float corr[4] = {1.f, 1.f, 1.f, 1.f};
      if (resc) {
#pragma unroll
        for (int r = 0; r < 4; ++r) {
          const float mnew = fmaxf(m_r[r], mt[r]);
          corr[r] = __expf(m_r[r] - mnew);
          m_r[r] = mnew;
          l_r[r] *= corr[r];
        }
      }
#pragma unroll
      for (int cb = 0; cb < 4; ++cb) {
        const float p0 = __expf(Sf[cb][0] - m_r[0]);
        const float p1 = __expf(Sf[cb][1] - m_r[1]);
        const float p2 = __expf(Sf[cb][2] - m_r[2]);
        const float p3 = __expf(Sf[cb][3] - m_r[3]);
        l_r[0] += p0; l_r[1] += p1; l_r[2] += p2; l_r[3] += p3;
        const unsigned pk01 = cvt_pk_bf16(p0, p1);
        const unsigned pk23 = cvt_pk_bf16(p2, p3);
        short* prow = &Pt[(w * 16 + lk * 4) * LDK + cb * 16 + lr];
        prow[0 * LDK] = (short)(pk01 & 0xffff);
        prow[1 * LDK] = (short)(pk01 >> 16);
        prow[2 * LDK] = (short)(pk23 & 0xffff);
        prow[3 * LDK] = (short)(pk23 >> 16);
      }
      asm volatile("s_waitcnt lgkmcnt(0)" ::: "memory");

      __builtin_amdgcn_s_setprio(1);
#pragma unroll
      for (int cb = 0; cb < 4; ++cb) {
        f32x4 acc = Of[cb];
        if (resc) {
#pragma unroll
          for (int r = 0; r < 4; ++r) acc[r] *= corr[r];
        }
#pragma unroll
        for (int ch = 0; ch < 2; ++ch) {
          const bf16x8 pf = *(const bf16x8*)&Pt[(w * 16 + lr) * LDK + ch * 32 + lk * 8];
          const bf16x8 vf = *(const bf16x8*)&Vc[(cb * 16 + lr) * LDK + ch * 32 + lk * 8];
          acc = __builtin_amdgcn_mfma_f32_16x16x32_bf16(pf, vf, acc, 0, 0, 0);
        }
        Of[cb] = acc;
      }
      __builtin_amdgcn_s_setprio(0);
    }

    if (pre) {
      *(bf16x8*)&Kt[cur ^ 1][sr * LDK + sc8] = krn;
      *(bf16x8*)&Vt[cur ^ 1][sr * LDK + sc8] = vrn;
    }
    __syncthreads();
    cur ^= 1;
  }

#pragma unroll
  for (int d = 1; d < 16; d <<= 1)
#pragma unroll
    for (int r = 0; r < 4; ++r) l_r[r] += __shfl_xor(l_r[r], d);

#pragma unroll
  for (int r = 0; r < 4; ++r) {
    const float inv = 1.f / l_r[r];
    const size_t row = (size_t)(b * kS + wrow + lk * 4 + r) * (kH * kL);
#pragma unroll
    for (int cb = 0; cb < 4; ++cb)
      attn_out[row + h * kL + cb * 16 + lr] = f2bf(Of[cb][r] * inv);
  }
}

// ---------------------------------------------------------------------------
extern "C" void kernel_launch(void* const* d_in, const int* in_sizes, int n_in,
                              void* d_out, int out_size, void* d_ws, size_t ws_size,
                              hipStream_t stream) {
  const float* x    = (const float*)d_in[0];
  const int*   pos  = (const int*)d_in[1];
  const float* Wq   = (const float*)d_in[3];
  const float* Wk   = (const float*)d_in[4];
  const float* Wv   = (const float*)d_in[5];
  const float* Wql  = (const float*)d_in[6];
  const float* Wkl  = (const float*)d_in[7];
  const float* Wvl  = (const float*)d_in[8];
  const float* Wo   = (const float*)d_in[9];
  float* out = (float*)d_out;

  // Workspace carve (q_buf bf16 reuses d_out: 16 MB of its 32 MB)
  char* p = (char*)d_ws;
  short* x_bf  = (short*)p; p += (size_t)kTok * kHID * 2;        // 16 MB
  short* Wqkv  = (short*)p; p += (size_t)kNQKV * kHID * 2;       // 12.6 MB
  short* WoT   = (short*)p; p += (size_t)kHID * (kH * kL) * 2;   // 4 MB
  short* WqlT  = (short*)p; p += (size_t)kL * kD * 2;            // 16 KB
  short* WklT  = (short*)p; p += (size_t)kL * kD * 2;
  short* WvlT  = (short*)p; p += (size_t)kL * kD * 2;
  float* tbl   = (float*)p; p += (size_t)kTok * 128 * 4;         // 2 MB
  short* k_buf = (short*)p; p += (size_t)kTok * kHKV * kD * 2;   // 4 MB
  short* v_buf = (short*)p; p += (size_t)kTok * kHKV * kD * 2;   // 4 MB
  short* q_l   = (short*)p; p += (size_t)kB * kH * kS * kL * 2;  // 8 MB
  short* k_l   = (short*)p; p += (size_t)kB * kHKV * kS * kL * 2;
  short* v_lT  = (short*)p; p += (size_t)kB * kHKV * kS * kL * 2;
  short* attn  = (short*)p;                                      // 8 MB
  short* q_buf = (short*)d_out;   // bf16 scratch until final GEMM

  // 0) dtype prep
  cvt_bf16<<<kTok * kHID / 8 / 256, 256, 0, stream>>>(x, x_bf, kTok * kHID / 8);
  trig_table<<<kTok * 64 / 256, 256, 0, stream>>>(pos, tbl);
  transpose_cvt<false><<<dim3(kH * kD / 64, kHID / 64), 256, 0, stream>>>(
      Wq, Wqkv, kH * kD, kHID, 0, 1.0f);
  transpose_cvt<false><<<dim3(kHKV * kD / 64, kHID / 64), 256, 0, stream>>>(
      Wk, Wqkv, kHKV * kD, kHID, kH * kD, 1.0f);
  transpose_cvt<false><<<dim3(kHKV * kD / 64, kHID / 64), 256, 0, stream>>>(
      Wv, Wqkv, kHKV * kD, kHID, kH * kD + kHKV * kD, 1.0f);
  transpose_cvt<true><<<dim3(kHID / 64, (kH * kL) / 64), 256, 0, stream>>>(
      Wo, WoT, kHID, kH * kL, 0, 1.0f);
  transpose_lat3<<<dim3(1, kD / 64, 3), 256, 0, stream>>>(
      Wql, Wkl, Wvl, WqlT, WklT, WvlT);

  // 1) Fused QKV projection — 256² 2-deep counted-vmcnt, register-blocked
  gemm_qkv8<<<dim3(kNQKV / 256, kTok / 256), 512, 0, stream>>>(
      x_bf, Wqkv, q_buf, k_buf, v_buf, kHID);

  // 2) Fused RoPE + latent projections — single dispatch
  rope_latent_all<<<dim3(kS / 64, 48), 256, 0, stream>>>(
      q_buf, k_buf, v_buf, WqlT, WklT, WvlT, tbl, q_l, k_l, v_lT);

  // 3) MFMA flash attention (T14 async dbuf, 1 barrier/tile)
  flash_attn_mfma<<<dim3(kB * kH, kS / 128), 512, 0, stream>>>(
      q_l, k_l, v_lT, attn);

  // 4) Output GEMM (m97 MFMA, fp32 out, XCD swizzle)
  gemm_mfma<<<dim3(kHID / 128, kTok / 128), 256, 0, stream>>>(
      attn, WoT, out, kTok, kHID, kH * kL);
}

// Round 12
// 200.079 us; speedup vs baseline: 1.2853x; 1.0581x over previous
//
#include <hip/hip_runtime.h>
#include <cstddef>

// Problem constants
constexpr int kB   = 2;
constexpr int kS   = 2048;
constexpr int kHID = 2048;
constexpr int kH   = 16;
constexpr int kHKV = 4;
constexpr int kD   = 128;
constexpr int kL   = 64;
constexpr int kTok = kB * kS;             // 4096 tokens
constexpr int kNQKV = kH * kD + 2 * kHKV * kD;  // 3072 fused QKV cols

typedef __attribute__((ext_vector_type(8))) short bf16x8;
typedef __attribute__((ext_vector_type(4))) float f32x4;

static __device__ __forceinline__ short f2bf(float f) {
  union { float f; unsigned u; } v{f};
  const unsigned r = (v.u + 0x7fff + ((v.u >> 16) & 1)) >> 16;
  return (short)r;
}
static __device__ __forceinline__ float bf2f(short s) {
  union { unsigned u; float f; } v;
  v.u = ((unsigned)(unsigned short)s) << 16;
  return v.f;
}

static __device__ __forceinline__ bf16x8 pack8(float4 a, float4 b) {
  bf16x8 r;
  r[0] = f2bf(a.x); r[1] = f2bf(a.y); r[2] = f2bf(a.z); r[3] = f2bf(a.w);
  r[4] = f2bf(b.x); r[5] = f2bf(b.y); r[6] = f2bf(b.z); r[7] = f2bf(b.w);
  return r;
}

// packed fp32x2 -> bf16x2 (exact RTN) — no builtin on gfx950, inline asm
static __device__ __forceinline__ unsigned cvt_pk_bf16(float lo, float hi) {
  unsigned r;
  asm("v_cvt_pk_bf16_f32 %0, %1, %2" : "=v"(r) : "v"(lo), "v"(hi));
  return r;
}

// async global->LDS, 16B per lane. LDS dest must be wave-uniform base + lane*16.
typedef __attribute__((address_space(3))) void       lds_void;
typedef __attribute__((address_space(1))) const void gm_void;
static __device__ __forceinline__ void gload16(const void* g, void* l) {
  __builtin_amdgcn_global_load_lds((gm_void*)g, (lds_void*)l, 16, 0, 0);
}

// T1: bijective XCD-aware block swizzle (requires nwg % 8 == 0)
static __device__ __forceinline__ int2 xcd_swz(int nx, int ny) {
  int wg = blockIdx.y * nx + blockIdx.x;
  const int cpx = (nx * ny) >> 3;
  wg = (wg & 7) * cpx + (wg >> 3);
  int2 r; r.x = wg % nx; r.y = wg / nx;
  return r;
}

// ---------------------------------------------------------------------------
// fp32 -> bf16 elementwise (8 elems / thread)
// ---------------------------------------------------------------------------
__global__ __launch_bounds__(256) void cvt_bf16(const float* __restrict__ in,
                                                short* __restrict__ out, int n8) {
  const int i = blockIdx.x * 256 + threadIdx.x;
  if (i >= n8) return;
  const float4 a = *(const float4*)&in[i * 8];
  const float4 b = *(const float4*)&in[i * 8 + 4];
  *(bf16x8*)&out[i * 8] = pack8(a, b);
}

// ---------------------------------------------------------------------------
// Per-token RoPE cos/sin table
// ---------------------------------------------------------------------------
__global__ __launch_bounds__(256) void trig_table(const int* __restrict__ pos,
                                                  float* __restrict__ tbl) {
  const int idx = blockIdx.x * 256 + threadIdx.x;
  if (idx >= kTok * 64) return;
  const int i = idx & 63, t = idx >> 6;
  const float p = (float)pos[t];
  const float inv_freq = expf(-(float)i * (9.210340371976184f / 64.0f));
  const float ang = p * inv_freq;
  tbl[t * 128 + i]      = cosf(ang);
  tbl[t * 128 + 64 + i] = sinf(ang);
}

// ---------------------------------------------------------------------------
// Fused QKV-weight transpose: out[n][k] (bf16, [3072][2048]) from the
// virtual concat(Wq,Wk,Wv, axis=1). 64-col blocks never cross the
// 2048/2560 boundaries -> block-uniform source select. grid (48, 32).
// ---------------------------------------------------------------------------
__global__ __launch_bounds__(256) void transpose_qkv(
    const float* __restrict__ Wq, const float* __restrict__ Wk,
    const float* __restrict__ Wv, short* __restrict__ out) {
  __shared__ float T[64][65];
  const int n0 = blockIdx.x * 64, k0 = blockIdx.y * 64;
  const float* in; int Nin, nl0;
  if (n0 < 2048)      { in = Wq; Nin = 2048; nl0 = n0; }
  else if (n0 < 2560) { in = Wk; Nin = 512;  nl0 = n0 - 2048; }
  else                { in = Wv; Nin = 512;  nl0 = n0 - 2560; }
  const int tid = threadIdx.x;
  const int rr = tid >> 4, cc = tid & 15;
#pragma unroll
  for (int ii = 0; ii < 4; ++ii) {
    const int kr = rr + ii * 16;
    const float4 v = *(const float4*)&in[(size_t)(k0 + kr) * Nin + nl0 + cc * 4];
    T[kr][cc * 4 + 0] = v.x; T[kr][cc * 4 + 1] = v.y;
    T[kr][cc * 4 + 2] = v.z; T[kr][cc * 4 + 3] = v.w;
  }
  __syncthreads();
#pragma unroll
  for (int ii = 0; ii < 4; ++ii) {
    const int n = rr + ii * 16;
    const short4 s4 = make_short4(f2bf(T[cc * 4 + 0][n]), f2bf(T[cc * 4 + 1][n]),
                                  f2bf(T[cc * 4 + 2][n]), f2bf(T[cc * 4 + 3][n]));
    *(short4*)&out[(size_t)(n0 + n) * kHID + k0 + cc * 4] = s4;
  }
}

// ---------------------------------------------------------------------------
// Transpose + convert + scale (kept for WoT): out[n][k] = in[rmap(k)][n]
// ---------------------------------------------------------------------------
template <bool REMAP>
__global__ __launch_bounds__(256) void transpose_cvt(
    const float* __restrict__ in, short* __restrict__ out,
    int Nin, int out_ld, int row_off, float scale) {
  __shared__ float T[64][65];
  const int tid = threadIdx.x;
  const int k0 = blockIdx.y * 64, n0 = blockIdx.x * 64;
  const int rr = tid >> 4;
  const int cc = tid & 15;
#pragma unroll
  for (int ii = 0; ii < 4; ++ii) {
    const int kr = rr + ii * 16;
    int gr = k0 + kr;
    if (REMAP) gr = ((gr >> 6) << 7) + (gr & 63);
    const float4 v = *(const float4*)&in[(size_t)gr * Nin + n0 + cc * 4];
    T[kr][cc * 4 + 0] = v.x * scale; T[kr][cc * 4 + 1] = v.y * scale;
    T[kr][cc * 4 + 2] = v.z * scale; T[kr][cc * 4 + 3] = v.w * scale;
  }
  __syncthreads();
#pragma unroll
  for (int ii = 0; ii < 4; ++ii) {
    const int n = rr + ii * 16;
    const short4 s4 = make_short4(f2bf(T[cc * 4 + 0][n]), f2bf(T[cc * 4 + 1][n]),
                                  f2bf(T[cc * 4 + 2][n]), f2bf(T[cc * 4 + 3][n]));
    *(short4*)&out[(size_t)(row_off + n0 + n) * out_ld + k0 + cc * 4] = s4;
  }
}

// ---------------------------------------------------------------------------
// Three small latent-weight transposes (128x64 each) in one dispatch.
// ---------------------------------------------------------------------------
__global__ __launch_bounds__(256) void transpose_lat3(
    const float* __restrict__ Wql, const float* __restrict__ Wkl,
    const float* __restrict__ Wvl, short* __restrict__ WqlT,
    short* __restrict__ WklT, short* __restrict__ WvlT) {
  __shared__ float T[64][65];
  const float* in; short* out; float scale;
  if (blockIdx.z == 0)      { in = Wql; out = WqlT; scale = 0.125f; }
  else if (blockIdx.z == 1) { in = Wkl; out = WklT; scale = 1.0f; }
  else                      { in = Wvl; out = WvlT; scale = 1.0f; }
  const int tid = threadIdx.x;
  const int k0 = blockIdx.y * 64;
  const int rr = tid >> 4, cc = tid & 15;
#pragma unroll
  for (int ii = 0; ii < 4; ++ii) {
    const int kr = rr + ii * 16;
    const float4 v = *(const float4*)&in[(size_t)(k0 + kr) * kL + cc * 4];
    T[kr][cc * 4 + 0] = v.x * scale; T[kr][cc * 4 + 1] = v.y * scale;
    T[kr][cc * 4 + 2] = v.z * scale; T[kr][cc * 4 + 3] = v.w * scale;
  }
  __syncthreads();
#pragma unroll
  for (int ii = 0; ii < 4; ++ii) {
    const int n = rr + ii * 16;
    const short4 s4 = make_short4(f2bf(T[cc * 4 + 0][n]), f2bf(T[cc * 4 + 1][n]),
                                  f2bf(T[cc * 4 + 2][n]), f2bf(T[cc * 4 + 3][n]));
    *(short4*)&out[(size_t)n * kD + k0 + cc * 4] = s4;
  }
}

// ---------------------------------------------------------------------------
// 256x256 2-deep pipelined bf16 MFMA GEMM for QKV (R10 structure, unchanged).
// ---------------------------------------------------------------------------
__global__ __launch_bounds__(512) void gemm_qkv8(
    const short* __restrict__ A, const short* __restrict__ Bt,
    short* __restrict__ C0, short* __restrict__ C1, short* __restrict__ C2,
    int K) {
  __shared__ short As[2][256 * 64];
  __shared__ short Bs[2][256 * 64];
  const int tid = threadIdx.x;
  const int lane = tid & 63, w = tid >> 6;
  const int lr = lane & 15, lk = lane >> 4;
  const int wm = w >> 2, wn = w & 3;
  const int2 sw = xcd_swz(kNQKV / 256, kTok / 256);   // 12 x 16 = 192 blocks
  const int row0 = sw.y * 256, col0 = sw.x * 256;
  const int NT = K >> 6;                               // 32

  auto stage = [&](int kt) {
    const int b = kt & 1;
    const int k0 = kt << 6;
#pragma unroll
    for (int j = 0; j < 4; ++j) {
      const int idx = j * 512 + tid;
      const int row = idx >> 3, blk = idx & 7;
      const int gcol = k0 + ((blk ^ (row & 7)) << 3);
      gload16(A + (size_t)(row0 + row) * K + gcol, &As[b][row * 64 + blk * 8]);
    }
#pragma unroll
    for (int j = 0; j < 4; ++j) {
      const int idx = j * 512 + tid;
      const int row = idx >> 3, blk = idx & 7;
      const int gcol = k0 + ((blk ^ (row & 7)) << 3);
      gload16(Bt + (size_t)(col0 + row) * K + gcol, &Bs[b][row * 64 + blk * 8]);
    }
  };

  f32x4 acc[8][4] = {};

  stage(0);
  for (int t = 0; t < NT; ++t) {
    const int b = t & 1;
    if (t + 1 < NT) {
      stage(t + 1);                                     // 2-deep prefetch
      asm volatile("s_waitcnt vmcnt(8)" ::: "memory");  // tile t drained
    } else {
      asm volatile("s_waitcnt vmcnt(0)" ::: "memory");
    }
    __builtin_amdgcn_s_barrier();                       // collective ready

    bf16x8 bb[4][2];
#pragma unroll
    for (int n = 0; n < 4; ++n) {
      const int row = wn * 64 + n * 16 + lr;
#pragma unroll
      for (int ch = 0; ch < 2; ++ch) {
        const int blk = (ch * 4 + lk) ^ (row & 7);
        bb[n][ch] = *(const bf16x8*)&Bs[b][row * 64 + blk * 8];
      }
    }
#pragma unroll
    for (int qm = 0; qm < 2; ++qm) {
      bf16x8 a[4][2];
#pragma unroll
      for (int j = 0; j < 4; ++j) {
        const int row = wm * 128 + (qm * 4 + j) * 16 + lr;
#pragma unroll
        for (int ch = 0; ch < 2; ++ch) {
          const int blk = (ch * 4 + lk) ^ (row & 7);
          a[j][ch] = *(const bf16x8*)&As[b][row * 64 + blk * 8];
        }
      }
      __builtin_amdgcn_s_setprio(1);
#pragma unroll
      for (int j = 0; j < 4; ++j)
#pragma unroll
        for (int n = 0; n < 4; ++n)
#pragma unroll
          for (int ch = 0; ch < 2; ++ch)
            acc[qm * 4 + j][n] = __builtin_amdgcn_mfma_f32_16x16x32_bf16(
                a[j][ch], bb[n][ch], acc[qm * 4 + j][n], 0, 0, 0);
      __builtin_amdgcn_s_setprio(0);
    }
    __builtin_amdgcn_s_barrier();
  }

  short* dst; int ld, cb;
  if (col0 < 2048)      { dst = C0; ld = 2048; cb = col0; }
  else if (col0 < 2560) { dst = C1; ld = 512;  cb = col0 - 2048; }
  else                  { dst = C2; ld = 512;  cb = col0 - 2560; }
  const int crow0 = row0 + wm * 128 + lk * 4;
  const int ccol0 = cb + wn * 64 + lr;
#pragma unroll
  for (int mf = 0; mf < 8; ++mf)
#pragma unroll
    for (int nf = 0; nf < 4; ++nf)
#pragma unroll
      for (int r = 0; r < 4; ++r)
        dst[(size_t)(crow0 + mf * 16 + r) * ld + ccol0 + nf * 16] =
            f2bf(acc[mf][nf][r]);
}

// ---------------------------------------------------------------------------
// 256(M)x128(N) 2-deep pipelined bf16 MFMA GEMM for the output projection.
// fp32 C out. grid = (N/128=16, M/256=16) = 256 blocks = exactly 1/CU.
// Same pipeline/swizzle as gemm_qkv8; 6 loads/thread/tile -> vmcnt(6).
// Per-wave output 128x32: acc[8][2]. LDS 96 KB (A 32K + B 16K, x2 dbuf).
// ---------------------------------------------------------------------------
__global__ __launch_bounds__(512) void gemm_out8(
    const short* __restrict__ A, const short* __restrict__ Bt,
    float* __restrict__ C, int M, int N, int K) {
  __shared__ short As[2][256 * 64];
  __shared__ short Bs[2][128 * 64];
  const int tid = threadIdx.x;
  const int lane = tid & 63, w = tid >> 6;
  const int lr = lane & 15, lk = lane >> 4;
  const int wm = w >> 2, wn = w & 3;
  const int2 sw = xcd_swz(N / 128, M / 256);          // 16 x 16 = 256 blocks
  const int row0 = sw.y * 256, col0 = sw.x * 128;
  const int NT = K >> 6;                               // 16

  auto stage = [&](int kt) {
    const int b = kt & 1;
    const int k0 = kt << 6;
#pragma unroll
    for (int j = 0; j < 4; ++j) {
      const int idx = j * 512 + tid;
      const int row = idx >> 3, blk = idx & 7;
      const int gcol = k0 + ((blk ^ (row & 7)) << 3);
      gload16(A + (size_t)(row0 + row) * K + gcol, &As[b][row * 64 + blk * 8]);
    }
#pragma unroll
    for (int j = 0; j < 2; ++j) {
      const int idx = j * 512 + tid;
      const int row = idx >> 3, blk = idx & 7;
      const int gcol = k0 + ((blk ^ (row & 7)) << 3);
      gload16(Bt + (size_t)(col0 + row) * K + gcol, &Bs[b][row * 64 + blk * 8]);
    }
  };

  f32x4 acc[8][2] = {};

  stage(0);
  for (int t = 0; t < NT; ++t) {
    const int b = t & 1;
    if (t + 1 < NT) {
      stage(t + 1);
      asm volatile("s_waitcnt vmcnt(6)" ::: "memory");
    } else {
      asm volatile("s_waitcnt vmcnt(0)" ::: "memory");
    }
    __builtin_amdgcn_s_barrier();

    bf16x8 bb[2][2];
#pragma unroll
    for (int n = 0; n < 2; ++n) {
      const int row = wn * 32 + n * 16 + lr;
#pragma unroll
      for (int ch = 0; ch < 2; ++ch) {
        const int blk = (ch * 4 + lk) ^ (row & 7);
        bb[n][ch] = *(const bf16x8*)&Bs[b][row * 64 + blk * 8];
      }
    }
#pragma unroll
    for (int qm = 0; qm < 2; ++qm) {
      bf16x8 a[4][2];
#pragma unroll
      for (int j = 0; j < 4; ++j) {
        const int row = wm * 128 + (qm * 4 + j) * 16 + lr;
#pragma unroll
        for (int ch = 0; ch < 2; ++ch) {
          const int blk = (ch * 4 + lk) ^ (row & 7);
          a[j][ch] = *(const bf16x8*)&As[b][row * 64 + blk * 8];
        }
      }
      __builtin_amdgcn_s_setprio(1);
#pragma unroll
      for (int j = 0; j < 4; ++j)
#pragma unroll
        for (int n = 0; n < 2; ++n)
#pragma unroll
          for (int ch = 0; ch < 2; ++ch)
            acc[qm * 4 + j][n] = __builtin_amdgcn_mfma_f32_16x16x32_bf16(
                a[j][ch], bb[n][ch], acc[qm * 4 + j][n], 0, 0, 0);
      __builtin_amdgcn_s_setprio(0);
    }
    __builtin_amdgcn_s_barrier();
  }

  const int crow0 = row0 + wm * 128 + lk * 4;
  const int ccol0 = col0 + wn * 32 + lr;
#pragma unroll
  for (int mf = 0; mf < 8; ++mf)
#pragma unroll
    for (int nf = 0; nf < 2; ++nf)
#pragma unroll
      for (int r = 0; r < 4; ++r)
        C[(size_t)(crow0 + mf * 16 + r) * N + ccol0 + nf * 16] = acc[mf][nf][r];
}

// ---------------------------------------------------------------------------
// Fused RoPE + latent projection (MFMA), bf16 input, all three tensors in
// one dispatch. grid = (kS/64, 48). Branches block-uniform.
// ---------------------------------------------------------------------------
__global__ __launch_bounds__(256) void rope_latent_all(
    const short* __restrict__ qb, const short* __restrict__ kb,
    const short* __restrict__ vb, const short* __restrict__ WqlT,
    const short* __restrict__ WklT, const short* __restrict__ WvlT,
    const float* __restrict__ tbl, short* __restrict__ q_l,
    short* __restrict__ k_l, short* __restrict__ v_lT) {
  __shared__ short Tw[4][1280];
  const int yz = blockIdx.y;
  const short* in; const short* WT; short* out; int nh; bool ROPE, TR;
  int bh;
  if (yz < 32)      { in = qb; WT = WqlT; out = q_l;  nh = kH;   ROPE = true;  TR = false; bh = yz; }
  else if (yz < 40) { in = kb; WT = WklT; out = k_l;  nh = kHKV; ROPE = true;  TR = false; bh = yz - 32; }
  else              { in = vb; WT = WvlT; out = v_lT; nh = kHKV; ROPE = false; TR = true;  bh = yz - 40; }

  const int tid = threadIdx.x;
  const int lane = tid & 63;
  const int w = tid >> 6;
  const int lr = lane & 15;
  const int lk = lane >> 4;
  const int b = bh / nh, h = bh % nh;
  const int s0 = blockIdx.x * 64;
  const int srow = s0 + w * 16 + lr;
  const int tok = b * kS + srow;

  const short* ip = in + ((size_t)tok * nh + h) * kD + lk * 8;
  bf16x8 raw[4];
#pragma unroll
  for (int ch = 0; ch < 4; ++ch) raw[ch] = *(const bf16x8*)(ip + ch * 32);

  bf16x8 af[4];
  if (ROPE) {
    float a[4][8];
#pragma unroll
    for (int ch = 0; ch < 4; ++ch)
#pragma unroll
      for (int i = 0; i < 8; ++i) a[ch][i] = bf2f(raw[ch][i]);
    const float* tb = tbl + (size_t)tok * 128;
    float c[2][8], sn[2][8];
#pragma unroll
    for (int g = 0; g < 2; ++g) {
      const float4 cA = *(const float4*)(tb + g * 32 + lk * 8);
      const float4 cB = *(const float4*)(tb + g * 32 + lk * 8 + 4);
      const float4 sA = *(const float4*)(tb + 64 + g * 32 + lk * 8);
      const float4 sB = *(const float4*)(tb + 64 + g * 32 + lk * 8 + 4);
      c[g][0] = cA.x; c[g][1] = cA.y; c[g][2] = cA.z; c[g][3] = cA.w;
      c[g][4] = cB.x; c[g][5] = cB.y; c[g][6] = cB.z; c[g][7] = cB.w;
      sn[g][0] = sA.x; sn[g][1] = sA.y; sn[g][2] = sA.z; sn[g][3] = sA.w;
      sn[g][4] = sB.x; sn[g][5] = sB.y; sn[g][6] = sB.z; sn[g][7] = sB.w;
    }
    float o[4][8];
#pragma unroll
    for (int g = 0; g < 2; ++g)
#pragma unroll
      for (int i = 0; i < 8; ++i) {
        o[g][i]     = a[g][i]     * c[g][i] - a[g + 2][i] * sn[g][i];
        o[g + 2][i] = a[g + 2][i] * c[g][i] + a[g][i]     * sn[g][i];
      }
#pragma unroll
    for (int ch = 0; ch < 4; ++ch)
#pragma unroll
      for (int i = 0; i < 8; ++i) af[ch][i] = f2bf(o[ch][i]);
  } else {
#pragma unroll
    for (int ch = 0; ch < 4; ++ch) af[ch] = raw[ch];
  }

  f32x4 acc[4] = {};
#pragma unroll
  for (int cb = 0; cb < 4; ++cb) {
#pragma unroll
    for (int ch = 0; ch < 4; ++ch) {
      const bf16x8 bfrag =
          *(const bf16x8*)&WT[(size_t)(cb * 16 + lr) * kD + ch * 32 + lk * 8];
      acc[cb] = __builtin_amdgcn_mfma_f32_16x16x32_bf16(af[ch], bfrag,
                                                        acc[cb], 0, 0, 0);
    }
  }

  short* T = Tw[w];
  if (!TR) {
#pragma unroll
    for (int cb = 0; cb < 4; ++cb)
#pragma unroll
      for (int r = 0; r < 4; ++r)
        T[(lk * 4 + r) * 72 + cb * 16 + lr] = f2bf(acc[cb][r]);
    asm volatile("s_waitcnt lgkmcnt(0)" ::: "memory");
#pragma unroll
    for (int it = 0; it < 2; ++it) {
      const int idx = it * 64 + lane;
      const int row = idx >> 3, c8 = (idx & 7) << 3;
      *(bf16x8*)&out[((size_t)bh * kS + s0 + w * 16 + row) * kL + c8] =
          *(const bf16x8*)&T[row * 72 + c8];
    }
  } else {
#pragma unroll
    for (int cb = 0; cb < 4; ++cb)
#pragma unroll
      for (int r = 0; r < 4; ++r)
        T[(cb * 16 + lr) * 20 + lk * 4 + r] = f2bf(acc[cb][r]);
    asm volatile("s_waitcnt lgkmcnt(0)" ::: "memory");
    const size_t orow = ((size_t)bh * kL + lane) * kS + s0 + w * 16;
#pragma unroll
    for (int c = 0; c < 4; ++c)
      *(short4*)&out[orow + c * 4] = *(const short4*)&T[lane * 20 + c * 4];
  }
}

// ---------------------------------------------------------------------------
// MFMA flash attention, causal, bf16 in/out (fp32 accumulate).
// T14 async dbuf, 1 barrier/tile; T13 defer-max; diag-hoisted causal mask;
// load-balanced grid.
// ---------------------------------------------------------------------------
__global__ __launch_bounds__(512) void flash_attn_mfma(
    const short* __restrict__ ql, const short* __restrict__ kl,
    const short* __restrict__ vlT, short* __restrict__ attn_out) {
  constexpr int LDK = 72;
  __shared__ short Kt[2][64 * LDK];
  __shared__ short Vt[2][64 * LDK];            // row = latent l, col = key
  __shared__ short Pt[128 * LDK];

  const int tid = threadIdx.x;
  const int lane = tid & 63;
  const int w = tid >> 6;
  const int lr = lane & 15;
  const int lk = lane >> 4;
  const int bid = blockIdx.y;
  const int bx = (bid < 8) ? (2 * bid) : (31 - 2 * bid);   // load-balance remap
  const int q0 = bx * 128;
  const int bh = blockIdx.x;
  const int b = bh >> 4, h = bh & 15;
  const int hk = h >> 2;
  const int wrow = q0 + w * 16;

  const short* qrow = ql + ((size_t)bh * kS + wrow + lr) * kL;
  bf16x8 qf[2];
  qf[0] = *(const bf16x8*)(qrow + lk * 8);
  qf[1] = *(const bf16x8*)(qrow + 32 + lk * 8);

  f32x4 Of[4] = {};
  float m_r[4], l_r[4];
#pragma unroll
  for (int r = 0; r < 4; ++r) { m_r[r] = -3.0e38f; l_r[r] = 0.f; }

  const size_t kbase = (size_t)(b * kHKV + hk) * kS * kL;
  const size_t vbase = (size_t)(b * kHKV + hk) * kL * kS;
  const int ntiles = q0 / 64 + 2;
  const int sr = tid >> 3, sc8 = (tid & 7) << 3;
  const short* kp = kl + kbase + (size_t)sr * kL + sc8;
  const short* vp = vlT + vbase + (size_t)sr * kS + sc8;

  *(bf16x8*)&Kt[0][sr * LDK + sc8] = *(const bf16x8*)kp;
  *(bf16x8*)&Vt[0][sr * LDK + sc8] = *(const bf16x8*)vp;
  __syncthreads();

  int cur = 0;
  for (int t = 0; t < ntiles; ++t) {
    const int j0 = t * 64;
    const bool pre = (t + 1 < ntiles);
    bf16x8 krn, vrn;
    if (pre) {
      krn = *(const bf16x8*)(kp + (size_t)(j0 + 64) * kL);
      vrn = *(const bf16x8*)(vp + (j0 + 64));
    }

    if (j0 <= wrow) {
      const short* Kc = &Kt[cur][0];
      const short* Vc = &Vt[cur][0];

      f32x4 Sf[4];
      __builtin_amdgcn_s_setprio(1);
#pragma unroll
      for (int cb = 0; cb < 4; ++cb) {
        f32x4 acc = {};
#pragma unroll
        for (int ch = 0; ch < 2; ++ch) {
          const bf16x8 kf = *(const bf16x8*)&Kc[(cb * 16 + lr) * LDK + ch * 32 + lk * 8];
          acc = __builtin_amdgcn_mfma_f32_16x16x32_bf16(qf[ch], kf, acc, 0, 0, 0);
        }
        Sf[cb] = acc;
      }
      __builtin_amdgcn_s_setprio(0);

      // causal mask only on the (wave-uniform) diagonal tile
      float mt[4] = {-3.0e38f, -3.0e38f, -3.0e38f, -3.0e38f};
      if (j0 + 63 > wrow) {
#pragma unroll
        for (int cb = 0; cb < 4; ++cb)
#pragma unroll
          for (int r = 0; r < 4; ++r) {
            float s = Sf[cb][r];
            if ((j0 + cb * 16 + lr) > (wrow + lk * 4 + r)) s = -3.0e38f;
            Sf[cb][r] = s;
            mt[r] = fmaxf(mt[r], s);
          }
      } else {
#pragma unroll
        for (int cb = 0; cb < 4; ++cb)
#pragma unroll
          for (int r = 0; r < 4; ++r) mt[r] = fmaxf(mt[r], Sf[cb][r]);
      }
#pragma unroll
      for (int d = 1; d < 16; d <<= 1)
#pragma unroll
        for (int r = 0; r < 4; ++r) mt[r] = fmaxf(mt[r], __shfl_xor(mt[r], d));

      const bool need = (mt[0] > m_r[0] + 8.f) || (mt[1] > m_r[1] + 8.f) ||
                        (mt[2] > m_r[2] + 8.f) || (mt[3] > m_r[3] + 8.f);
      const bool resc = __any((int)need);
      float corr[4] = {1.f, 1.f, 1.f, 1.f};
      if (resc) {
#pragma unroll
        for (int r = 0; r < 4; ++r) {
          const float mnew = fmaxf(m_r[r], mt[r]);
          corr[r] = __expf(m_r[r] - mnew);
          m_r[r] = mnew;
          l_r[r] *= corr[r];
        }
      }
#pragma unroll
      for (int cb = 0; cb < 4; ++cb) {
        const float p0 = __expf(Sf[cb][0] - m_r[0]);
        const float p1 = __expf(Sf[cb][1] - m_r[1]);
        const float p2 = __expf(Sf[cb][2] - m_r[2]);
        const float p3 = __expf(Sf[cb][3] - m_r[3]);
        l_r[0] += p0; l_r[1] += p1; l_r[2] += p2; l_r[3] += p3;
        const unsigned pk01 = cvt_pk_bf16(p0, p1);
        const unsigned pk23 = cvt_pk_bf16(p2, p3);
        short* prow = &Pt[(w * 16 + lk * 4) * LDK + cb * 16 + lr];
        prow[0 * LDK] = (short)(pk01 & 0xffff);
        prow[1 * LDK] = (short)(pk01 >> 16);
        prow[2 * LDK] = (short)(pk23 & 0xffff);
        prow[3 * LDK] = (short)(pk23 >> 16);
      }
      asm volatile("s_waitcnt lgkmcnt(0)" ::: "memory");

      __builtin_amdgcn_s_setprio(1);
#pragma unroll
      for (int cb = 0; cb < 4; ++cb) {
        f32x4 acc = Of[cb];
        if (resc) {
#pragma unroll
          for (int r = 0; r < 4; ++r) acc[r] *= corr[r];
        }
#pragma unroll
        for (int ch = 0; ch < 2; ++ch) {
          const bf16x8 pf = *(const bf16x8*)&Pt[(w * 16 + lr) * LDK + ch * 32 + lk * 8];
          const bf16x8 vf = *(const bf16x8*)&Vc[(cb * 16 + lr) * LDK + ch * 32 + lk * 8];
          acc = __builtin_amdgcn_mfma_f32_16x16x32_bf16(pf, vf, acc, 0, 0, 0);
        }
        Of[cb] = acc;
      }
      __builtin_amdgcn_s_setprio(0);
    }

    if (pre) {
      *(bf16x8*)&Kt[cur ^ 1][sr * LDK + sc8] = krn;
      *(bf16x8*)&Vt[cur ^ 1][sr * LDK + sc8] = vrn;
    }
    __syncthreads();
    cur ^= 1;
  }

#pragma unroll
  for (int d = 1; d < 16; d <<= 1)
#pragma unroll
    for (int r = 0; r < 4; ++r) l_r[r] += __shfl_xor(l_r[r], d);

#pragma unroll
  for (int r = 0; r < 4; ++r) {
    const float inv = 1.f / l_r[r];
    const size_t row = (size_t)(b * kS + wrow + lk * 4 + r) * (kH * kL);
#pragma unroll
    for (int cb = 0; cb < 4; ++cb)
      attn_out[row + h * kL + cb * 16 + lr] = f2bf(Of[cb][r] * inv);
  }
}

// ---------------------------------------------------------------------------
extern "C" void kernel_launch(void* const* d_in, const int* in_sizes, int n_in,
                              void* d_out, int out_size, void* d_ws, size_t ws_size,
                              hipStream_t stream) {
  const float* x    = (const float*)d_in[0];
  const int*   pos  = (const int*)d_in[1];
  const float* Wq   = (const float*)d_in[3];
  const float* Wk   = (const float*)d_in[4];
  const float* Wv   = (const float*)d_in[5];
  const float* Wql  = (const float*)d_in[6];
  const float* Wkl  = (const float*)d_in[7];
  const float* Wvl  = (const float*)d_in[8];
  const float* Wo   = (const float*)d_in[9];
  float* out = (float*)d_out;

  // Workspace carve (q_buf bf16 reuses d_out: 16 MB of its 32 MB)
  char* p = (char*)d_ws;
  short* x_bf  = (short*)p; p += (size_t)kTok * kHID * 2;        // 16 MB
  short* Wqkv  = (short*)p; p += (size_t)kNQKV * kHID * 2;       // 12.6 MB
  short* WoT   = (short*)p; p += (size_t)kHID * (kH * kL) * 2;   // 4 MB
  short* WqlT  = (short*)p; p += (size_t)kL * kD * 2;            // 16 KB
  short* WklT  = (short*)p; p += (size_t)kL * kD * 2;
  short* WvlT  = (short*)p; p += (size_t)kL * kD * 2;
  float* tbl   = (float*)p; p += (size_t)kTok * 128 * 4;         // 2 MB
  short* k_buf = (short*)p; p += (size_t)kTok * kHKV * kD * 2;   // 4 MB
  short* v_buf = (short*)p; p += (size_t)kTok * kHKV * kD * 2;   // 4 MB
  short* q_l   = (short*)p; p += (size_t)kB * kH * kS * kL * 2;  // 8 MB
  short* k_l   = (short*)p; p += (size_t)kB * kHKV * kS * kL * 2;
  short* v_lT  = (short*)p; p += (size_t)kB * kHKV * kS * kL * 2;
  short* attn  = (short*)p;                                      // 8 MB
  short* q_buf = (short*)d_out;   // bf16 scratch until final GEMM

  // 0) dtype prep
  cvt_bf16<<<kTok * kHID / 8 / 256, 256, 0, stream>>>(x, x_bf, kTok * kHID / 8);
  trig_table<<<kTok * 64 / 256, 256, 0, stream>>>(pos, tbl);
  transpose_qkv<<<dim3(kNQKV / 64, kHID / 64), 256, 0, stream>>>(
      Wq, Wk, Wv, Wqkv);
  transpose_cvt<true><<<dim3(kHID / 64, (kH * kL) / 64), 256, 0, stream>>>(
      Wo, WoT, kHID, kH * kL, 0, 1.0f);
  transpose_lat3<<<dim3(1, kD / 64, 3), 256, 0, stream>>>(
      Wql, Wkl, Wvl, WqlT, WklT, WvlT);

  // 1) Fused QKV projection — 256² 2-deep counted-vmcnt, register-blocked
  gemm_qkv8<<<dim3(kNQKV / 256, kTok / 256), 512, 0, stream>>>(
      x_bf, Wqkv, q_buf, k_buf, v_buf, kHID);

  // 2) Fused RoPE + latent projections — single dispatch
  rope_latent_all<<<dim3(kS / 64, 48), 256, 0, stream>>>(
      q_buf, k_buf, v_buf, WqlT, WklT, WvlT, tbl, q_l, k_l, v_lT);

  // 3) MFMA flash attention (T14 async dbuf, 1 barrier/tile, diag-hoist)
  flash_attn_mfma<<<dim3(kB * kH, kS / 128), 512, 0, stream>>>(
      q_l, k_l, v_lT, attn);

  // 4) Output GEMM — 256x128 2-deep, 256 blocks = 1/CU, fp32 out
  gemm_out8<<<dim3(kHID / 128, kTok / 256), 512, 0, stream>>>(
      attn, WoT, out, kTok, kHID, kH * kL);
}

// Round 13
// 194.058 us; speedup vs baseline: 1.3252x; 1.0310x over previous
//
#include <hip/hip_runtime.h>
#include <cstddef>

// Problem constants
constexpr int kB   = 2;
constexpr int kS   = 2048;
constexpr int kHID = 2048;
constexpr int kH   = 16;
constexpr int kHKV = 4;
constexpr int kD   = 128;
constexpr int kL   = 64;
constexpr int kTok = kB * kS;             // 4096 tokens
constexpr int kNQKV = kH * kD + 2 * kHKV * kD;  // 3072 fused QKV cols

typedef __attribute__((ext_vector_type(8))) short bf16x8;
typedef __attribute__((ext_vector_type(4))) float f32x4;

static __device__ __forceinline__ short f2bf(float f) {
  union { float f; unsigned u; } v{f};
  const unsigned r = (v.u + 0x7fff + ((v.u >> 16) & 1)) >> 16;
  return (short)r;
}
static __device__ __forceinline__ float bf2f(short s) {
  union { unsigned u; float f; } v;
  v.u = ((unsigned)(unsigned short)s) << 16;
  return v.f;
}

static __device__ __forceinline__ bf16x8 pack8(float4 a, float4 b) {
  bf16x8 r;
  r[0] = f2bf(a.x); r[1] = f2bf(a.y); r[2] = f2bf(a.z); r[3] = f2bf(a.w);
  r[4] = f2bf(b.x); r[5] = f2bf(b.y); r[6] = f2bf(b.z); r[7] = f2bf(b.w);
  return r;
}

// packed fp32x2 -> bf16x2 (exact RTN) — no builtin on gfx950, inline asm
static __device__ __forceinline__ unsigned cvt_pk_bf16(float lo, float hi) {
  unsigned r;
  asm("v_cvt_pk_bf16_f32 %0, %1, %2" : "=v"(r) : "v"(lo), "v"(hi));
  return r;
}

// async global->LDS, 16B per lane. LDS dest must be wave-uniform base + lane*16.
typedef __attribute__((address_space(3))) void       lds_void;
typedef __attribute__((address_space(1))) const void gm_void;
static __device__ __forceinline__ void gload16(const void* g, void* l) {
  __builtin_amdgcn_global_load_lds((gm_void*)g, (lds_void*)l, 16, 0, 0);
}

// T1: bijective XCD-aware block swizzle (requires nwg % 8 == 0)
static __device__ __forceinline__ int2 xcd_swz(int nx, int ny) {
  int wg = blockIdx.y * nx + blockIdx.x;
  const int cpx = (nx * ny) >> 3;
  wg = (wg & 7) * cpx + (wg >> 3);
  int2 r; r.x = wg % nx; r.y = wg / nx;
  return r;
}

// ---------------------------------------------------------------------------
// fp32 -> bf16 elementwise (8 elems / thread)
// ---------------------------------------------------------------------------
__global__ __launch_bounds__(256) void cvt_bf16(const float* __restrict__ in,
                                                short* __restrict__ out, int n8) {
  const int i = blockIdx.x * 256 + threadIdx.x;
  if (i >= n8) return;
  const float4 a = *(const float4*)&in[i * 8];
  const float4 b = *(const float4*)&in[i * 8 + 4];
  *(bf16x8*)&out[i * 8] = pack8(a, b);
}

// ---------------------------------------------------------------------------
// Per-token RoPE cos/sin table
// ---------------------------------------------------------------------------
__global__ __launch_bounds__(256) void trig_table(const int* __restrict__ pos,
                                                  float* __restrict__ tbl) {
  const int idx = blockIdx.x * 256 + threadIdx.x;
  if (idx >= kTok * 64) return;
  const int i = idx & 63, t = idx >> 6;
  const float p = (float)pos[t];
  const float inv_freq = expf(-(float)i * (9.210340371976184f / 64.0f));
  const float ang = p * inv_freq;
  tbl[t * 128 + i]      = cosf(ang);
  tbl[t * 128 + 64 + i] = sinf(ang);
}

// ---------------------------------------------------------------------------
// Fused QKV-weight transpose: out[n][k] (bf16, [3072][2048]) from the
// virtual concat(Wq,Wk,Wv, axis=1). grid (48, 32).
// ---------------------------------------------------------------------------
__global__ __launch_bounds__(256) void transpose_qkv(
    const float* __restrict__ Wq, const float* __restrict__ Wk,
    const float* __restrict__ Wv, short* __restrict__ out) {
  __shared__ float T[64][65];
  const int n0 = blockIdx.x * 64, k0 = blockIdx.y * 64;
  const float* in; int Nin, nl0;
  if (n0 < 2048)      { in = Wq; Nin = 2048; nl0 = n0; }
  else if (n0 < 2560) { in = Wk; Nin = 512;  nl0 = n0 - 2048; }
  else                { in = Wv; Nin = 512;  nl0 = n0 - 2560; }
  const int tid = threadIdx.x;
  const int rr = tid >> 4, cc = tid & 15;
#pragma unroll
  for (int ii = 0; ii < 4; ++ii) {
    const int kr = rr + ii * 16;
    const float4 v = *(const float4*)&in[(size_t)(k0 + kr) * Nin + nl0 + cc * 4];
    T[kr][cc * 4 + 0] = v.x; T[kr][cc * 4 + 1] = v.y;
    T[kr][cc * 4 + 2] = v.z; T[kr][cc * 4 + 3] = v.w;
  }
  __syncthreads();
#pragma unroll
  for (int ii = 0; ii < 4; ++ii) {
    const int n = rr + ii * 16;
    const short4 s4 = make_short4(f2bf(T[cc * 4 + 0][n]), f2bf(T[cc * 4 + 1][n]),
                                  f2bf(T[cc * 4 + 2][n]), f2bf(T[cc * 4 + 3][n]));
    *(short4*)&out[(size_t)(n0 + n) * kHID + k0 + cc * 4] = s4;
  }
}

// ---------------------------------------------------------------------------
// Transpose + convert + scale (kept for WoT): out[n][k] = in[rmap(k)][n]
// ---------------------------------------------------------------------------
template <bool REMAP>
__global__ __launch_bounds__(256) void transpose_cvt(
    const float* __restrict__ in, short* __restrict__ out,
    int Nin, int out_ld, int row_off, float scale) {
  __shared__ float T[64][65];
  const int tid = threadIdx.x;
  const int k0 = blockIdx.y * 64, n0 = blockIdx.x * 64;
  const int rr = tid >> 4;
  const int cc = tid & 15;
#pragma unroll
  for (int ii = 0; ii < 4; ++ii) {
    const int kr = rr + ii * 16;
    int gr = k0 + kr;
    if (REMAP) gr = ((gr >> 6) << 7) + (gr & 63);
    const float4 v = *(const float4*)&in[(size_t)gr * Nin + n0 + cc * 4];
    T[kr][cc * 4 + 0] = v.x * scale; T[kr][cc * 4 + 1] = v.y * scale;
    T[kr][cc * 4 + 2] = v.z * scale; T[kr][cc * 4 + 3] = v.w * scale;
  }
  __syncthreads();
#pragma unroll
  for (int ii = 0; ii < 4; ++ii) {
    const int n = rr + ii * 16;
    const short4 s4 = make_short4(f2bf(T[cc * 4 + 0][n]), f2bf(T[cc * 4 + 1][n]),
                                  f2bf(T[cc * 4 + 2][n]), f2bf(T[cc * 4 + 3][n]));
    *(short4*)&out[(size_t)(row_off + n0 + n) * out_ld + k0 + cc * 4] = s4;
  }
}

// ---------------------------------------------------------------------------
// Three small latent-weight transposes (128x64 each) in one dispatch.
// ---------------------------------------------------------------------------
__global__ __launch_bounds__(256) void transpose_lat3(
    const float* __restrict__ Wql, const float* __restrict__ Wkl,
    const float* __restrict__ Wvl, short* __restrict__ WqlT,
    short* __restrict__ WklT, short* __restrict__ WvlT) {
  __shared__ float T[64][65];
  const float* in; short* out; float scale;
  if (blockIdx.z == 0)      { in = Wql; out = WqlT; scale = 0.125f; }
  else if (blockIdx.z == 1) { in = Wkl; out = WklT; scale = 1.0f; }
  else                      { in = Wvl; out = WvlT; scale = 1.0f; }
  const int tid = threadIdx.x;
  const int k0 = blockIdx.y * 64;
  const int rr = tid >> 4, cc = tid & 15;
#pragma unroll
  for (int ii = 0; ii < 4; ++ii) {
    const int kr = rr + ii * 16;
    const float4 v = *(const float4*)&in[(size_t)(k0 + kr) * kL + cc * 4];
    T[kr][cc * 4 + 0] = v.x * scale; T[kr][cc * 4 + 1] = v.y * scale;
    T[kr][cc * 4 + 2] = v.z * scale; T[kr][cc * 4 + 3] = v.w * scale;
  }
  __syncthreads();
#pragma unroll
  for (int ii = 0; ii < 4; ++ii) {
    const int n = rr + ii * 16;
    const short4 s4 = make_short4(f2bf(T[cc * 4 + 0][n]), f2bf(T[cc * 4 + 1][n]),
                                  f2bf(T[cc * 4 + 2][n]), f2bf(T[cc * 4 + 3][n]));
    *(short4*)&out[(size_t)n * kD + k0 + cc * 4] = s4;
  }
}

// ---------------------------------------------------------------------------
// 256x256 2-deep pipelined bf16 MFMA GEMM for QKV (R10 structure, unchanged).
// ---------------------------------------------------------------------------
__global__ __launch_bounds__(512) void gemm_qkv8(
    const short* __restrict__ A, const short* __restrict__ Bt,
    short* __restrict__ C0, short* __restrict__ C1, short* __restrict__ C2,
    int K) {
  __shared__ short As[2][256 * 64];
  __shared__ short Bs[2][256 * 64];
  const int tid = threadIdx.x;
  const int lane = tid & 63, w = tid >> 6;
  const int lr = lane & 15, lk = lane >> 4;
  const int wm = w >> 2, wn = w & 3;
  const int2 sw = xcd_swz(kNQKV / 256, kTok / 256);   // 12 x 16 = 192 blocks
  const int row0 = sw.y * 256, col0 = sw.x * 256;
  const int NT = K >> 6;                               // 32

  auto stage = [&](int kt) {
    const int b = kt & 1;
    const int k0 = kt << 6;
#pragma unroll
    for (int j = 0; j < 4; ++j) {
      const int idx = j * 512 + tid;
      const int row = idx >> 3, blk = idx & 7;
      const int gcol = k0 + ((blk ^ (row & 7)) << 3);
      gload16(A + (size_t)(row0 + row) * K + gcol, &As[b][row * 64 + blk * 8]);
    }
#pragma unroll
    for (int j = 0; j < 4; ++j) {
      const int idx = j * 512 + tid;
      const int row = idx >> 3, blk = idx & 7;
      const int gcol = k0 + ((blk ^ (row & 7)) << 3);
      gload16(Bt + (size_t)(col0 + row) * K + gcol, &Bs[b][row * 64 + blk * 8]);
    }
  };

  f32x4 acc[8][4] = {};

  stage(0);
  for (int t = 0; t < NT; ++t) {
    const int b = t & 1;
    if (t + 1 < NT) {
      stage(t + 1);                                     // 2-deep prefetch
      asm volatile("s_waitcnt vmcnt(8)" ::: "memory");  // tile t drained
    } else {
      asm volatile("s_waitcnt vmcnt(0)" ::: "memory");
    }
    __builtin_amdgcn_s_barrier();                       // collective ready

    bf16x8 bb[4][2];
#pragma unroll
    for (int n = 0; n < 4; ++n) {
      const int row = wn * 64 + n * 16 + lr;
#pragma unroll
      for (int ch = 0; ch < 2; ++ch) {
        const int blk = (ch * 4 + lk) ^ (row & 7);
        bb[n][ch] = *(const bf16x8*)&Bs[b][row * 64 + blk * 8];
      }
    }
#pragma unroll
    for (int qm = 0; qm < 2; ++qm) {
      bf16x8 a[4][2];
#pragma unroll
      for (int j = 0; j < 4; ++j) {
        const int row = wm * 128 + (qm * 4 + j) * 16 + lr;
#pragma unroll
        for (int ch = 0; ch < 2; ++ch) {
          const int blk = (ch * 4 + lk) ^ (row & 7);
          a[j][ch] = *(const bf16x8*)&As[b][row * 64 + blk * 8];
        }
      }
      __builtin_amdgcn_s_setprio(1);
#pragma unroll
      for (int j = 0; j < 4; ++j)
#pragma unroll
        for (int n = 0; n < 4; ++n)
#pragma unroll
          for (int ch = 0; ch < 2; ++ch)
            acc[qm * 4 + j][n] = __builtin_amdgcn_mfma_f32_16x16x32_bf16(
                a[j][ch], bb[n][ch], acc[qm * 4 + j][n], 0, 0, 0);
      __builtin_amdgcn_s_setprio(0);
    }
    __builtin_amdgcn_s_barrier();
  }

  short* dst; int ld, cb;
  if (col0 < 2048)      { dst = C0; ld = 2048; cb = col0; }
  else if (col0 < 2560) { dst = C1; ld = 512;  cb = col0 - 2048; }
  else                  { dst = C2; ld = 512;  cb = col0 - 2560; }
  const int crow0 = row0 + wm * 128 + lk * 4;
  const int ccol0 = cb + wn * 64 + lr;
#pragma unroll
  for (int mf = 0; mf < 8; ++mf)
#pragma unroll
    for (int nf = 0; nf < 4; ++nf)
#pragma unroll
      for (int r = 0; r < 4; ++r)
        dst[(size_t)(crow0 + mf * 16 + r) * ld + ccol0 + nf * 16] =
            f2bf(acc[mf][nf][r]);
}

// ---------------------------------------------------------------------------
// 256(M)x128(N) 2-deep pipelined bf16 MFMA GEMM for the output projection.
// ---------------------------------------------------------------------------
__global__ __launch_bounds__(512) void gemm_out8(
    const short* __restrict__ A, const short* __restrict__ Bt,
    float* __restrict__ C, int M, int N, int K) {
  __shared__ short As[2][256 * 64];
  __shared__ short Bs[2][128 * 64];
  const int tid = threadIdx.x;
  const int lane = tid & 63, w = tid >> 6;
  const int lr = lane & 15, lk = lane >> 4;
  const int wm = w >> 2, wn = w & 3;
  const int2 sw = xcd_swz(N / 128, M / 256);          // 16 x 16 = 256 blocks
  const int row0 = sw.y * 256, col0 = sw.x * 128;
  const int NT = K >> 6;                               // 16

  auto stage = [&](int kt) {
    const int b = kt & 1;
    const int k0 = kt << 6;
#pragma unroll
    for (int j = 0; j < 4; ++j) {
      const int idx = j * 512 + tid;
      const int row = idx >> 3, blk = idx & 7;
      const int gcol = k0 + ((blk ^ (row & 7)) << 3);
      gload16(A + (size_t)(row0 + row) * K + gcol, &As[b][row * 64 + blk * 8]);
    }
#pragma unroll
    for (int j = 0; j < 2; ++j) {
      const int idx = j * 512 + tid;
      const int row = idx >> 3, blk = idx & 7;
      const int gcol = k0 + ((blk ^ (row & 7)) << 3);
      gload16(Bt + (size_t)(col0 + row) * K + gcol, &Bs[b][row * 64 + blk * 8]);
    }
  };

  f32x4 acc[8][2] = {};

  stage(0);
  for (int t = 0; t < NT; ++t) {
    const int b = t & 1;
    if (t + 1 < NT) {
      stage(t + 1);
      asm volatile("s_waitcnt vmcnt(6)" ::: "memory");
    } else {
      asm volatile("s_waitcnt vmcnt(0)" ::: "memory");
    }
    __builtin_amdgcn_s_barrier();

    bf16x8 bb[2][2];
#pragma unroll
    for (int n = 0; n < 2; ++n) {
      const int row = wn * 32 + n * 16 + lr;
#pragma unroll
      for (int ch = 0; ch < 2; ++ch) {
        const int blk = (ch * 4 + lk) ^ (row & 7);
        bb[n][ch] = *(const bf16x8*)&Bs[b][row * 64 + blk * 8];
      }
    }
#pragma unroll
    for (int qm = 0; qm < 2; ++qm) {
      bf16x8 a[4][2];
#pragma unroll
      for (int j = 0; j < 4; ++j) {
        const int row = wm * 128 + (qm * 4 + j) * 16 + lr;
#pragma unroll
        for (int ch = 0; ch < 2; ++ch) {
          const int blk = (ch * 4 + lk) ^ (row & 7);
          a[j][ch] = *(const bf16x8*)&As[b][row * 64 + blk * 8];
        }
      }
      __builtin_amdgcn_s_setprio(1);
#pragma unroll
      for (int j = 0; j < 4; ++j)
#pragma unroll
        for (int n = 0; n < 2; ++n)
#pragma unroll
          for (int ch = 0; ch < 2; ++ch)
            acc[qm * 4 + j][n] = __builtin_amdgcn_mfma_f32_16x16x32_bf16(
                a[j][ch], bb[n][ch], acc[qm * 4 + j][n], 0, 0, 0);
      __builtin_amdgcn_s_setprio(0);
    }
    __builtin_amdgcn_s_barrier();
  }

  const int crow0 = row0 + wm * 128 + lk * 4;
  const int ccol0 = col0 + wn * 32 + lr;
#pragma unroll
  for (int mf = 0; mf < 8; ++mf)
#pragma unroll
    for (int nf = 0; nf < 2; ++nf)
#pragma unroll
      for (int r = 0; r < 4; ++r)
        C[(size_t)(crow0 + mf * 16 + r) * N + ccol0 + nf * 16] = acc[mf][nf][r];
}

// ---------------------------------------------------------------------------
// Fused RoPE + latent projection (MFMA), bf16 input, all three tensors in
// one dispatch. grid = (kS/64, 48). Branches block-uniform.
// ---------------------------------------------------------------------------
__global__ __launch_bounds__(256) void rope_latent_all(
    const short* __restrict__ qb, const short* __restrict__ kb,
    const short* __restrict__ vb, const short* __restrict__ WqlT,
    const short* __restrict__ WklT, const short* __restrict__ WvlT,
    const float* __restrict__ tbl, short* __restrict__ q_l,
    short* __restrict__ k_l, short* __restrict__ v_lT) {
  __shared__ short Tw[4][1280];
  const int yz = blockIdx.y;
  const short* in; const short* WT; short* out; int nh; bool ROPE, TR;
  int bh;
  if (yz < 32)      { in = qb; WT = WqlT; out = q_l;  nh = kH;   ROPE = true;  TR = false; bh = yz; }
  else if (yz < 40) { in = kb; WT = WklT; out = k_l;  nh = kHKV; ROPE = true;  TR = false; bh = yz - 32; }
  else              { in = vb; WT = WvlT; out = v_lT; nh = kHKV; ROPE = false; TR = true;  bh = yz - 40; }

  const int tid = threadIdx.x;
  const int lane = tid & 63;
  const int w = tid >> 6;
  const int lr = lane & 15;
  const int lk = lane >> 4;
  const int b = bh / nh, h = bh % nh;
  const int s0 = blockIdx.x * 64;
  const int srow = s0 + w * 16 + lr;
  const int tok = b * kS + srow;

  const short* ip = in + ((size_t)tok * nh + h) * kD + lk * 8;
  bf16x8 raw[4];
#pragma unroll
  for (int ch = 0; ch < 4; ++ch) raw[ch] = *(const bf16x8*)(ip + ch * 32);

  bf16x8 af[4];
  if (ROPE) {
    float a[4][8];
#pragma unroll
    for (int ch = 0; ch < 4; ++ch)
#pragma unroll
      for (int i = 0; i < 8; ++i) a[ch][i] = bf2f(raw[ch][i]);
    const float* tb = tbl + (size_t)tok * 128;
    float c[2][8], sn[2][8];
#pragma unroll
    for (int g = 0; g < 2; ++g) {
      const float4 cA = *(const float4*)(tb + g * 32 + lk * 8);
      const float4 cB = *(const float4*)(tb + g * 32 + lk * 8 + 4);
      const float4 sA = *(const float4*)(tb + 64 + g * 32 + lk * 8);
      const float4 sB = *(const float4*)(tb + 64 + g * 32 + lk * 8 + 4);
      c[g][0] = cA.x; c[g][1] = cA.y; c[g][2] = cA.z; c[g][3] = cA.w;
      c[g][4] = cB.x; c[g][5] = cB.y; c[g][6] = cB.z; c[g][7] = cB.w;
      sn[g][0] = sA.x; sn[g][1] = sA.y; sn[g][2] = sA.z; sn[g][3] = sA.w;
      sn[g][4] = sB.x; sn[g][5] = sB.y; sn[g][6] = sB.z; sn[g][7] = sB.w;
    }
    float o[4][8];
#pragma unroll
    for (int g = 0; g < 2; ++g)
#pragma unroll
      for (int i = 0; i < 8; ++i) {
        o[g][i]     = a[g][i]     * c[g][i] - a[g + 2][i] * sn[g][i];
        o[g + 2][i] = a[g + 2][i] * c[g][i] + a[g][i]     * sn[g][i];
      }
#pragma unroll
    for (int ch = 0; ch < 4; ++ch)
#pragma unroll
      for (int i = 0; i < 8; ++i) af[ch][i] = f2bf(o[ch][i]);
  } else {
#pragma unroll
    for (int ch = 0; ch < 4; ++ch) af[ch] = raw[ch];
  }

  f32x4 acc[4] = {};
#pragma unroll
  for (int cb = 0; cb < 4; ++cb) {
#pragma unroll
    for (int ch = 0; ch < 4; ++ch) {
      const bf16x8 bfrag =
          *(const bf16x8*)&WT[(size_t)(cb * 16 + lr) * kD + ch * 32 + lk * 8];
      acc[cb] = __builtin_amdgcn_mfma_f32_16x16x32_bf16(af[ch], bfrag,
                                                        acc[cb], 0, 0, 0);
    }
  }

  short* T = Tw[w];
  if (!TR) {
#pragma unroll
    for (int cb = 0; cb < 4; ++cb)
#pragma unroll
      for (int r = 0; r < 4; ++r)
        T[(lk * 4 + r) * 72 + cb * 16 + lr] = f2bf(acc[cb][r]);
    asm volatile("s_waitcnt lgkmcnt(0)" ::: "memory");
#pragma unroll
    for (int it = 0; it < 2; ++it) {
      const int idx = it * 64 + lane;
      const int row = idx >> 3, c8 = (idx & 7) << 3;
      *(bf16x8*)&out[((size_t)bh * kS + s0 + w * 16 + row) * kL + c8] =
          *(const bf16x8*)&T[row * 72 + c8];
    }
  } else {
#pragma unroll
    for (int cb = 0; cb < 4; ++cb)
#pragma unroll
      for (int r = 0; r < 4; ++r)
        T[(cb * 16 + lr) * 20 + lk * 4 + r] = f2bf(acc[cb][r]);
    asm volatile("s_waitcnt lgkmcnt(0)" ::: "memory");
    const size_t orow = ((size_t)bh * kL + lane) * kS + s0 + w * 16;
#pragma unroll
    for (int c = 0; c < 4; ++c)
      *(short4*)&out[orow + c * 4] = *(const short4*)&T[lane * 20 + c * 4];
  }
}

// ---------------------------------------------------------------------------
// MFMA flash attention, causal, bf16 in/out (fp32 accumulate).
// SWAPPED QK^T (T12 core): S^T = mfma(K,Q) puts q lane-local (q = lane&15).
// - softmax max/sum: scalar m,l per lane, 2 shuffle stages (xor 16,32)
// - P -> PV B-operand: 16 in-register __shfl + 8 selects; NO LDS round-trip
// - PV: O^T = mfma(V^T, P^T); output write = 4x short4 per lane
// T14 async dbuf (1 barrier/tile), T13 defer-max, balanced grid.
// ---------------------------------------------------------------------------
__global__ __launch_bounds__(512) void flash_attn_mfma(
    const short* __restrict__ ql, const short* __restrict__ kl,
    const short* __restrict__ vlT, short* __restrict__ attn_out) {
  constexpr int LDK = 72;
  __shared__ short Kt[2][64 * LDK];
  __shared__ short Vt[2][64 * LDK];            // row = latent l, col = key

  const int tid = threadIdx.x;
  const int lane = tid & 63;
  const int w = tid >> 6;
  const int lr = lane & 15;
  const int lk = lane >> 4;
  const int bid = blockIdx.y;
  const int bx = (bid < 8) ? (2 * bid) : (31 - 2 * bid);   // load-balance remap
  const int q0 = bx * 128;
  const int bh = blockIdx.x;
  const int b = bh >> 4, h = bh & 15;
  const int hk = h >> 2;
  const int wrow = q0 + w * 16;

  const short* qrow = ql + ((size_t)bh * kS + wrow + lr) * kL;
  bf16x8 qf[2];
  qf[0] = *(const bf16x8*)(qrow + lk * 8);
  qf[1] = *(const bf16x8*)(qrow + 32 + lk * 8);

  f32x4 Of[4] = {};                            // O^T[l=lb*16+lk*4+r][q=lr]
  float m = -3.0e38f, l = 0.f;

  const size_t kbase = (size_t)(b * kHKV + hk) * kS * kL;
  const size_t vbase = (size_t)(b * kHKV + hk) * kL * kS;
  const int ntiles = q0 / 64 + 2;
  const int sr = tid >> 3, sc8 = (tid & 7) << 3;
  const short* kp = kl + kbase + (size_t)sr * kL + sc8;
  const short* vp = vlT + vbase + (size_t)sr * kS + sc8;

  *(bf16x8*)&Kt[0][sr * LDK + sc8] = *(const bf16x8*)kp;
  *(bf16x8*)&Vt[0][sr * LDK + sc8] = *(const bf16x8*)vp;
  __syncthreads();

  const int sl0 = lr + ((lane & 16) << 1);     // lr + 32*(lk&1)
  const bool hi = (lk >> 1) != 0;              // selects cb_src = 2ch+1

  int cur = 0;
  for (int t = 0; t < ntiles; ++t) {
    const int j0 = t * 64;
    const bool pre = (t + 1 < ntiles);
    bf16x8 krn, vrn;
    if (pre) {                                 // issue next-tile loads EARLY
      krn = *(const bf16x8*)(kp + (size_t)(j0 + 64) * kL);
      vrn = *(const bf16x8*)(vp + (j0 + 64));
    }

    if (j0 <= wrow) {                          // wave-uniform causal skip
      const short* Kc = &Kt[cur][0];
      const short* Vc = &Vt[cur][0];

      // S^T = K @ Q : Sf[cb][r] = S[key=j0+cb*16+lk*4+r][q=wrow+lr]
      f32x4 Sf[4];
      __builtin_amdgcn_s_setprio(1);
#pragma unroll
      for (int cb = 0; cb < 4; ++cb) {
        f32x4 acc = {};
#pragma unroll
        for (int ch = 0; ch < 2; ++ch) {
          const bf16x8 kf = *(const bf16x8*)&Kc[(cb * 16 + lr) * LDK + ch * 32 + lk * 8];
          acc = __builtin_amdgcn_mfma_f32_16x16x32_bf16(kf, qf[ch], acc, 0, 0, 0);
        }
        Sf[cb] = acc;
      }
      __builtin_amdgcn_s_setprio(0);

      // causal mask (diagonal tile only) + local max
      float mt = -3.0e38f;
      if (j0 + 63 > wrow) {
#pragma unroll
        for (int cb = 0; cb < 4; ++cb)
#pragma unroll
          for (int r = 0; r < 4; ++r) {
            float s = Sf[cb][r];
            if ((j0 + cb * 16 + lk * 4 + r) > (wrow + lr)) s = -3.0e38f;
            Sf[cb][r] = s;
            mt = fmaxf(mt, s);
          }
      } else {
#pragma unroll
        for (int cb = 0; cb < 4; ++cb)
#pragma unroll
          for (int r = 0; r < 4; ++r) mt = fmaxf(mt, Sf[cb][r]);
      }
      mt = fmaxf(mt, __shfl_xor(mt, 16));
      mt = fmaxf(mt, __shfl_xor(mt, 32));

      // T13 defer-max
      const bool resc = __any((int)(mt > m + 8.f));
      if (resc) {
        const float mnew = fmaxf(m, mt);
        const float corr = __expf(m - mnew);
        m = mnew;
        l *= corr;
#pragma unroll
        for (int lb = 0; lb < 4; ++lb)
#pragma unroll
          for (int r = 0; r < 4; ++r) Of[lb][r] *= corr;
      }

      // P = exp(S - m), packed bf16 pairs per cb
      unsigned pk[4][2];
#pragma unroll
      for (int cb = 0; cb < 4; ++cb) {
        const float p0 = __expf(Sf[cb][0] - m);
        const float p1 = __expf(Sf[cb][1] - m);
        const float p2 = __expf(Sf[cb][2] - m);
        const float p3 = __expf(Sf[cb][3] - m);
        l += (p0 + p1) + (p2 + p3);
        pk[cb][0] = cvt_pk_bf16(p0, p1);
        pk[cb][1] = cvt_pk_bf16(p2, p3);
      }

      // PV: per ch, build P^T B-fragment via in-register shuffles, then MFMA
#pragma unroll
      for (int ch = 0; ch < 2; ++ch) {
        const unsigned lo00 = __shfl(pk[2 * ch][0], sl0);
        const unsigned lo01 = __shfl(pk[2 * ch][1], sl0);
        const unsigned lo10 = __shfl(pk[2 * ch][0], sl0 + 16);
        const unsigned lo11 = __shfl(pk[2 * ch][1], sl0 + 16);
        const unsigned hi00 = __shfl(pk[2 * ch + 1][0], sl0);
        const unsigned hi01 = __shfl(pk[2 * ch + 1][1], sl0);
        const unsigned hi10 = __shfl(pk[2 * ch + 1][0], sl0 + 16);
        const unsigned hi11 = __shfl(pk[2 * ch + 1][1], sl0 + 16);
        union { unsigned u[4]; bf16x8 v; } pf;
        pf.u[0] = hi ? hi00 : lo00;
        pf.u[1] = hi ? hi01 : lo01;
        pf.u[2] = hi ? hi10 : lo10;
        pf.u[3] = hi ? hi11 : lo11;
        __builtin_amdgcn_s_setprio(1);
#pragma unroll
        for (int lb = 0; lb < 4; ++lb) {
          const bf16x8 vf = *(const bf16x8*)&Vc[(lb * 16 + lr) * LDK + ch * 32 + lk * 8];
          Of[lb] = __builtin_amdgcn_mfma_f32_16x16x32_bf16(vf, pf.v, Of[lb], 0, 0, 0);
        }
        __builtin_amdgcn_s_setprio(0);
      }
    }

    if (pre) {                                 // write-late into other buffer
      *(bf16x8*)&Kt[cur ^ 1][sr * LDK + sc8] = krn;
      *(bf16x8*)&Vt[cur ^ 1][sr * LDK + sc8] = vrn;
    }
    __syncthreads();                           // single barrier per tile
    cur ^= 1;
  }

  // final lsum reduce (over lk groups) + O^T write: 4x short4 per lane
  l += __shfl_xor(l, 16);
  l += __shfl_xor(l, 32);
  const float inv = 1.f / l;
  const size_t rowoff =
      (size_t)(b * kS + wrow + lr) * (kH * kL) + h * kL + lk * 4;
#pragma unroll
  for (int lb = 0; lb < 4; ++lb) {
    const short4 s4 = make_short4(f2bf(Of[lb][0] * inv), f2bf(Of[lb][1] * inv),
                                  f2bf(Of[lb][2] * inv), f2bf(Of[lb][3] * inv));
    *(short4*)&attn_out[rowoff + lb * 16] = s4;
  }
}

// ---------------------------------------------------------------------------
extern "C" void kernel_launch(void* const* d_in, const int* in_sizes, int n_in,
                              void* d_out, int out_size, void* d_ws, size_t ws_size,
                              hipStream_t stream) {
  const float* x    = (const float*)d_in[0];
  const int*   pos  = (const int*)d_in[1];
  const float* Wq   = (const float*)d_in[3];
  const float* Wk   = (const float*)d_in[4];
  const float* Wv   = (const float*)d_in[5];
  const float* Wql  = (const float*)d_in[6];
  const float* Wkl  = (const float*)d_in[7];
  const float* Wvl  = (const float*)d_in[8];
  const float* Wo   = (const float*)d_in[9];
  float* out = (float*)d_out;

  // Workspace carve (q_buf bf16 reuses d_out: 16 MB of its 32 MB)
  char* p = (char*)d_ws;
  short* x_bf  = (short*)p; p += (size_t)kTok * kHID * 2;        // 16 MB
  short* Wqkv  = (short*)p; p += (size_t)kNQKV * kHID * 2;       // 12.6 MB
  short* WoT   = (short*)p; p += (size_t)kHID * (kH * kL) * 2;   // 4 MB
  short* WqlT  = (short*)p; p += (size_t)kL * kD * 2;            // 16 KB
  short* WklT  = (short*)p; p += (size_t)kL * kD * 2;
  short* WvlT  = (short*)p; p += (size_t)kL * kD * 2;
  float* tbl   = (float*)p; p += (size_t)kTok * 128 * 4;         // 2 MB
  short* k_buf = (short*)p; p += (size_t)kTok * kHKV * kD * 2;   // 4 MB
  short* v_buf = (short*)p; p += (size_t)kTok * kHKV * kD * 2;   // 4 MB
  short* q_l   = (short*)p; p += (size_t)kB * kH * kS * kL * 2;  // 8 MB
  short* k_l   = (short*)p; p += (size_t)kB * kHKV * kS * kL * 2;
  short* v_lT  = (short*)p; p += (size_t)kB * kHKV * kS * kL * 2;
  short* attn  = (short*)p;                                      // 8 MB
  short* q_buf = (short*)d_out;   // bf16 scratch until final GEMM

  // 0) dtype prep
  cvt_bf16<<<kTok * kHID / 8 / 256, 256, 0, stream>>>(x, x_bf, kTok * kHID / 8);
  trig_table<<<kTok * 64 / 256, 256, 0, stream>>>(pos, tbl);
  transpose_qkv<<<dim3(kNQKV / 64, kHID / 64), 256, 0, stream>>>(
      Wq, Wk, Wv, Wqkv);
  transpose_cvt<true><<<dim3(kHID / 64, (kH * kL) / 64), 256, 0, stream>>>(
      Wo, WoT, kHID, kH * kL, 0, 1.0f);
  transpose_lat3<<<dim3(1, kD / 64, 3), 256, 0, stream>>>(
      Wql, Wkl, Wvl, WqlT, WklT, WvlT);

  // 1) Fused QKV projection — 256² 2-deep counted-vmcnt, register-blocked
  gemm_qkv8<<<dim3(kNQKV / 256, kTok / 256), 512, 0, stream>>>(
      x_bf, Wqkv, q_buf, k_buf, v_buf, kHID);

  // 2) Fused RoPE + latent projections — single dispatch
  rope_latent_all<<<dim3(kS / 64, 48), 256, 0, stream>>>(
      q_buf, k_buf, v_buf, WqlT, WklT, WvlT, tbl, q_l, k_l, v_lT);

  // 3) MFMA flash attention (swapped QK^T, in-register P, dbuf)
  flash_attn_mfma<<<dim3(kB * kH, kS / 128), 512, 0, stream>>>(
      q_l, k_l, v_lT, attn);

  // 4) Output GEMM — 256x128 2-deep, 256 blocks = 1/CU, fp32 out
  gemm_out8<<<dim3(kHID / 128, kTok / 256), 512, 0, stream>>>(
      attn, WoT, out, kTok, kHID, kH * kL);
}

// Round 14
// 180.893 us; speedup vs baseline: 1.4216x; 1.0728x over previous
//
#include <hip/hip_runtime.h>
#include <cstddef>

// Problem constants
constexpr int kB   = 2;
constexpr int kS   = 2048;
constexpr int kHID = 2048;
constexpr int kH   = 16;
constexpr int kHKV = 4;
constexpr int kD   = 128;
constexpr int kL   = 64;
constexpr int kTok = kB * kS;             // 4096 tokens
constexpr int kNQKV = kH * kD + 2 * kHKV * kD;  // 3072 fused QKV cols

typedef __attribute__((ext_vector_type(8))) short bf16x8;
typedef __attribute__((ext_vector_type(4))) float f32x4;

static __device__ __forceinline__ short f2bf(float f) {
  union { float f; unsigned u; } v{f};
  const unsigned r = (v.u + 0x7fff + ((v.u >> 16) & 1)) >> 16;
  return (short)r;
}
static __device__ __forceinline__ float bf2f(short s) {
  union { unsigned u; float f; } v;
  v.u = ((unsigned)(unsigned short)s) << 16;
  return v.f;
}

static __device__ __forceinline__ bf16x8 pack8(float4 a, float4 b) {
  bf16x8 r;
  r[0] = f2bf(a.x); r[1] = f2bf(a.y); r[2] = f2bf(a.z); r[3] = f2bf(a.w);
  r[4] = f2bf(b.x); r[5] = f2bf(b.y); r[6] = f2bf(b.z); r[7] = f2bf(b.w);
  return r;
}

// packed fp32x2 -> bf16x2 (exact RTN) — no builtin on gfx950, inline asm
static __device__ __forceinline__ unsigned cvt_pk_bf16(float lo, float hi) {
  unsigned r;
  asm("v_cvt_pk_bf16_f32 %0, %1, %2" : "=v"(r) : "v"(lo), "v"(hi));
  return r;
}

// async global->LDS, 16B per lane. LDS dest must be wave-uniform base + lane*16.
typedef __attribute__((address_space(3))) void       lds_void;
typedef __attribute__((address_space(1))) const void gm_void;
static __device__ __forceinline__ void gload16(const void* g, void* l) {
  __builtin_amdgcn_global_load_lds((gm_void*)g, (lds_void*)l, 16, 0, 0);
}

// T1: bijective XCD-aware block swizzle (requires nwg % 8 == 0)
static __device__ __forceinline__ int2 xcd_swz(int nx, int ny) {
  int wg = blockIdx.y * nx + blockIdx.x;
  const int cpx = (nx * ny) >> 3;
  wg = (wg & 7) * cpx + (wg >> 3);
  int2 r; r.x = wg % nx; r.y = wg / nx;
  return r;
}

// ---------------------------------------------------------------------------
// Fused prep: one dispatch replacing 5 small kernels (block-uniform branches)
//  [0, 4096)            : x fp32 -> bf16 (8 elems/thread)
//  [4096, 5120)         : RoPE trig table
//  [5120, 6656)         : transpose concat(Wq,Wk,Wv) -> Wqkv [3072][2048]
//  [6656, 7168)         : transpose Wo (zero-pad remap) -> WoT [2048][1024]
//  [7168, 7174)         : 3 latent-weight transposes (Wql scaled 1/8)
// ---------------------------------------------------------------------------
__global__ __launch_bounds__(256) void prep_all(
    const float* __restrict__ x, const int* __restrict__ pos,
    const float* __restrict__ Wq, const float* __restrict__ Wk,
    const float* __restrict__ Wv, const float* __restrict__ Wo,
    const float* __restrict__ Wql, const float* __restrict__ Wkl,
    const float* __restrict__ Wvl, short* __restrict__ x_bf,
    float* __restrict__ tbl, short* __restrict__ Wqkv,
    short* __restrict__ WoT, short* __restrict__ WqlT,
    short* __restrict__ WklT, short* __restrict__ WvlT) {
  __shared__ float T[64][65];
  const int bidg = blockIdx.x;
  const int tid = threadIdx.x;

  if (bidg < 4096) {                       // A: x -> bf16
    const int i = bidg * 256 + tid;
    const float4 a = *(const float4*)&x[(size_t)i * 8];
    const float4 b = *(const float4*)&x[(size_t)i * 8 + 4];
    *(bf16x8*)&x_bf[(size_t)i * 8] = pack8(a, b);
    return;
  }
  if (bidg < 5120) {                       // B: trig table
    const int idx = (bidg - 4096) * 256 + tid;
    const int i = idx & 63, t = idx >> 6;
    const float p = (float)pos[t];
    const float inv_freq = expf(-(float)i * (9.210340371976184f / 64.0f));
    const float ang = p * inv_freq;
    tbl[t * 128 + i]      = cosf(ang);
    tbl[t * 128 + 64 + i] = sinf(ang);
    return;
  }
  const int rr = tid >> 4, cc = tid & 15;
  if (bidg < 6656) {                       // C: QKV weight transpose
    const int idx = bidg - 5120;
    const int n0 = (idx % 48) * 64, k0 = (idx / 48) * 64;
    const float* in; int Nin, nl0;
    if (n0 < 2048)      { in = Wq; Nin = 2048; nl0 = n0; }
    else if (n0 < 2560) { in = Wk; Nin = 512;  nl0 = n0 - 2048; }
    else                { in = Wv; Nin = 512;  nl0 = n0 - 2560; }
#pragma unroll
    for (int ii = 0; ii < 4; ++ii) {
      const int kr = rr + ii * 16;
      const float4 v = *(const float4*)&in[(size_t)(k0 + kr) * Nin + nl0 + cc * 4];
      T[kr][cc * 4 + 0] = v.x; T[kr][cc * 4 + 1] = v.y;
      T[kr][cc * 4 + 2] = v.z; T[kr][cc * 4 + 3] = v.w;
    }
    __syncthreads();
#pragma unroll
    for (int ii = 0; ii < 4; ++ii) {
      const int n = rr + ii * 16;
      const short4 s4 = make_short4(f2bf(T[cc*4+0][n]), f2bf(T[cc*4+1][n]),
                                    f2bf(T[cc*4+2][n]), f2bf(T[cc*4+3][n]));
      *(short4*)&Wqkv[(size_t)(n0 + n) * kHID + k0 + cc * 4] = s4;
    }
    return;
  }
  if (bidg < 7168) {                       // D: Wo transpose (pad remap)
    const int idx = bidg - 6656;
    const int n0 = (idx % 32) * 64, k0 = (idx / 32) * 64;
#pragma unroll
    for (int ii = 0; ii < 4; ++ii) {
      const int kr = rr + ii * 16;
      const int gr = (((k0 + kr) >> 6) << 7) + ((k0 + kr) & 63);
      const float4 v = *(const float4*)&Wo[(size_t)gr * kHID + n0 + cc * 4];
      T[kr][cc * 4 + 0] = v.x; T[kr][cc * 4 + 1] = v.y;
      T[kr][cc * 4 + 2] = v.z; T[kr][cc * 4 + 3] = v.w;
    }
    __syncthreads();
#pragma unroll
    for (int ii = 0; ii < 4; ++ii) {
      const int n = rr + ii * 16;
      const short4 s4 = make_short4(f2bf(T[cc*4+0][n]), f2bf(T[cc*4+1][n]),
                                    f2bf(T[cc*4+2][n]), f2bf(T[cc*4+3][n]));
      *(short4*)&WoT[(size_t)(n0 + n) * (kH * kL) + k0 + cc * 4] = s4;
    }
    return;
  }
  {                                        // E: latent weight transposes
    const int idx = bidg - 7168;
    const int k0 = (idx & 1) * 64;
    const int z = idx >> 1;
    const float* in; short* out; float scale;
    if (z == 0)      { in = Wql; out = WqlT; scale = 0.125f; }
    else if (z == 1) { in = Wkl; out = WklT; scale = 1.0f; }
    else             { in = Wvl; out = WvlT; scale = 1.0f; }
#pragma unroll
    for (int ii = 0; ii < 4; ++ii) {
      const int kr = rr + ii * 16;
      const float4 v = *(const float4*)&in[(size_t)(k0 + kr) * kL + cc * 4];
      T[kr][cc * 4 + 0] = v.x * scale; T[kr][cc * 4 + 1] = v.y * scale;
      T[kr][cc * 4 + 2] = v.z * scale; T[kr][cc * 4 + 3] = v.w * scale;
    }
    __syncthreads();
#pragma unroll
    for (int ii = 0; ii < 4; ++ii) {
      const int n = rr + ii * 16;
      const short4 s4 = make_short4(f2bf(T[cc*4+0][n]), f2bf(T[cc*4+1][n]),
                                    f2bf(T[cc*4+2][n]), f2bf(T[cc*4+3][n]));
      *(short4*)&out[(size_t)n * kD + k0 + cc * 4] = s4;
    }
  }
}

// ---------------------------------------------------------------------------
// 256x256 2-deep pipelined bf16 MFMA GEMM for QKV (R10 structure, unchanged).
// ---------------------------------------------------------------------------
__global__ __launch_bounds__(512) void gemm_qkv8(
    const short* __restrict__ A, const short* __restrict__ Bt,
    short* __restrict__ C0, short* __restrict__ C1, short* __restrict__ C2,
    int K) {
  __shared__ short As[2][256 * 64];
  __shared__ short Bs[2][256 * 64];
  const int tid = threadIdx.x;
  const int lane = tid & 63, w = tid >> 6;
  const int lr = lane & 15, lk = lane >> 4;
  const int wm = w >> 2, wn = w & 3;
  const int2 sw = xcd_swz(kNQKV / 256, kTok / 256);   // 12 x 16 = 192 blocks
  const int row0 = sw.y * 256, col0 = sw.x * 256;
  const int NT = K >> 6;                               // 32

  auto stage = [&](int kt) {
    const int b = kt & 1;
    const int k0 = kt << 6;
#pragma unroll
    for (int j = 0; j < 4; ++j) {
      const int idx = j * 512 + tid;
      const int row = idx >> 3, blk = idx & 7;
      const int gcol = k0 + ((blk ^ (row & 7)) << 3);
      gload16(A + (size_t)(row0 + row) * K + gcol, &As[b][row * 64 + blk * 8]);
    }
#pragma unroll
    for (int j = 0; j < 4; ++j) {
      const int idx = j * 512 + tid;
      const int row = idx >> 3, blk = idx & 7;
      const int gcol = k0 + ((blk ^ (row & 7)) << 3);
      gload16(Bt + (size_t)(col0 + row) * K + gcol, &Bs[b][row * 64 + blk * 8]);
    }
  };

  f32x4 acc[8][4] = {};

  stage(0);
  for (int t = 0; t < NT; ++t) {
    const int b = t & 1;
    if (t + 1 < NT) {
      stage(t + 1);                                     // 2-deep prefetch
      asm volatile("s_waitcnt vmcnt(8)" ::: "memory");  // tile t drained
    } else {
      asm volatile("s_waitcnt vmcnt(0)" ::: "memory");
    }
    __builtin_amdgcn_s_barrier();                       // collective ready

    bf16x8 bb[4][2];
#pragma unroll
    for (int n = 0; n < 4; ++n) {
      const int row = wn * 64 + n * 16 + lr;
#pragma unroll
      for (int ch = 0; ch < 2; ++ch) {
        const int blk = (ch * 4 + lk) ^ (row & 7);
        bb[n][ch] = *(const bf16x8*)&Bs[b][row * 64 + blk * 8];
      }
    }
#pragma unroll
    for (int qm = 0; qm < 2; ++qm) {
      bf16x8 a[4][2];
#pragma unroll
      for (int j = 0; j < 4; ++j) {
        const int row = wm * 128 + (qm * 4 + j) * 16 + lr;
#pragma unroll
        for (int ch = 0; ch < 2; ++ch) {
          const int blk = (ch * 4 + lk) ^ (row & 7);
          a[j][ch] = *(const bf16x8*)&As[b][row * 64 + blk * 8];
        }
      }
      __builtin_amdgcn_s_setprio(1);
#pragma unroll
      for (int j = 0; j < 4; ++j)
#pragma unroll
        for (int n = 0; n < 4; ++n)
#pragma unroll
          for (int ch = 0; ch < 2; ++ch)
            acc[qm * 4 + j][n] = __builtin_amdgcn_mfma_f32_16x16x32_bf16(
                a[j][ch], bb[n][ch], acc[qm * 4 + j][n], 0, 0, 0);
      __builtin_amdgcn_s_setprio(0);
    }
    __builtin_amdgcn_s_barrier();
  }

  short* dst; int ld, cb;
  if (col0 < 2048)      { dst = C0; ld = 2048; cb = col0; }
  else if (col0 < 2560) { dst = C1; ld = 512;  cb = col0 - 2048; }
  else                  { dst = C2; ld = 512;  cb = col0 - 2560; }
  const int crow0 = row0 + wm * 128 + lk * 4;
  const int ccol0 = cb + wn * 64 + lr;
#pragma unroll
  for (int mf = 0; mf < 8; ++mf)
#pragma unroll
    for (int nf = 0; nf < 4; ++nf)
#pragma unroll
      for (int r = 0; r < 4; ++r)
        dst[(size_t)(crow0 + mf * 16 + r) * ld + ccol0 + nf * 16] =
            f2bf(acc[mf][nf][r]);
}

// ---------------------------------------------------------------------------
// 256(M)x128(N) 2-deep pipelined bf16 MFMA GEMM for the output projection.
// ---------------------------------------------------------------------------
__global__ __launch_bounds__(512) void gemm_out8(
    const short* __restrict__ A, const short* __restrict__ Bt,
    float* __restrict__ C, int M, int N, int K) {
  __shared__ short As[2][256 * 64];
  __shared__ short Bs[2][128 * 64];
  const int tid = threadIdx.x;
  const int lane = tid & 63, w = tid >> 6;
  const int lr = lane & 15, lk = lane >> 4;
  const int wm = w >> 2, wn = w & 3;
  const int2 sw = xcd_swz(N / 128, M / 256);          // 16 x 16 = 256 blocks
  const int row0 = sw.y * 256, col0 = sw.x * 128;
  const int NT = K >> 6;                               // 16

  auto stage = [&](int kt) {
    const int b = kt & 1;
    const int k0 = kt << 6;
#pragma unroll
    for (int j = 0; j < 4; ++j) {
      const int idx = j * 512 + tid;
      const int row = idx >> 3, blk = idx & 7;
      const int gcol = k0 + ((blk ^ (row & 7)) << 3);
      gload16(A + (size_t)(row0 + row) * K + gcol, &As[b][row * 64 + blk * 8]);
    }
#pragma unroll
    for (int j = 0; j < 2; ++j) {
      const int idx = j * 512 + tid;
      const int row = idx >> 3, blk = idx & 7;
      const int gcol = k0 + ((blk ^ (row & 7)) << 3);
      gload16(Bt + (size_t)(col0 + row) * K + gcol, &Bs[b][row * 64 + blk * 8]);
    }
  };

  f32x4 acc[8][2] = {};

  stage(0);
  for (int t = 0; t < NT; ++t) {
    const int b = t & 1;
    if (t + 1 < NT) {
      stage(t + 1);
      asm volatile("s_waitcnt vmcnt(6)" ::: "memory");
    } else {
      asm volatile("s_waitcnt vmcnt(0)" ::: "memory");
    }
    __builtin_amdgcn_s_barrier();

    bf16x8 bb[2][2];
#pragma unroll
    for (int n = 0; n < 2; ++n) {
      const int row = wn * 32 + n * 16 + lr;
#pragma unroll
      for (int ch = 0; ch < 2; ++ch) {
        const int blk = (ch * 4 + lk) ^ (row & 7);
        bb[n][ch] = *(const bf16x8*)&Bs[b][row * 64 + blk * 8];
      }
    }
#pragma unroll
    for (int qm = 0; qm < 2; ++qm) {
      bf16x8 a[4][2];
#pragma unroll
      for (int j = 0; j < 4; ++j) {
        const int row = wm * 128 + (qm * 4 + j) * 16 + lr;
#pragma unroll
        for (int ch = 0; ch < 2; ++ch) {
          const int blk = (ch * 4 + lk) ^ (row & 7);
          a[j][ch] = *(const bf16x8*)&As[b][row * 64 + blk * 8];
        }
      }
      __builtin_amdgcn_s_setprio(1);
#pragma unroll
      for (int j = 0; j < 4; ++j)
#pragma unroll
        for (int n = 0; n < 2; ++n)
#pragma unroll
          for (int ch = 0; ch < 2; ++ch)
            acc[qm * 4 + j][n] = __builtin_amdgcn_mfma_f32_16x16x32_bf16(
                a[j][ch], bb[n][ch], acc[qm * 4 + j][n], 0, 0, 0);
      __builtin_amdgcn_s_setprio(0);
    }
    __builtin_amdgcn_s_barrier();
  }

  const int crow0 = row0 + wm * 128 + lk * 4;
  const int ccol0 = col0 + wn * 32 + lr;
#pragma unroll
  for (int mf = 0; mf < 8; ++mf)
#pragma unroll
    for (int nf = 0; nf < 2; ++nf)
#pragma unroll
      for (int r = 0; r < 4; ++r)
        C[(size_t)(crow0 + mf * 16 + r) * N + ccol0 + nf * 16] = acc[mf][nf][r];
}

// ---------------------------------------------------------------------------
// Fused RoPE + latent projection (MFMA), bf16 input, all three tensors in
// one dispatch. grid = (kS/64, 48). Branches block-uniform.
// ---------------------------------------------------------------------------
__global__ __launch_bounds__(256) void rope_latent_all(
    const short* __restrict__ qb, const short* __restrict__ kb,
    const short* __restrict__ vb, const short* __restrict__ WqlT,
    const short* __restrict__ WklT, const short* __restrict__ WvlT,
    const float* __restrict__ tbl, short* __restrict__ q_l,
    short* __restrict__ k_l, short* __restrict__ v_lT) {
  __shared__ short Tw[4][1280];
  const int yz = blockIdx.y;
  const short* in; const short* WT; short* out; int nh; bool ROPE, TR;
  int bh;
  if (yz < 32)      { in = qb; WT = WqlT; out = q_l;  nh = kH;   ROPE = true;  TR = false; bh = yz; }
  else if (yz < 40) { in = kb; WT = WklT; out = k_l;  nh = kHKV; ROPE = true;  TR = false; bh = yz - 32; }
  else              { in = vb; WT = WvlT; out = v_lT; nh = kHKV; ROPE = false; TR = true;  bh = yz - 40; }

  const int tid = threadIdx.x;
  const int lane = tid & 63;
  const int w = tid >> 6;
  const int lr = lane & 15;
  const int lk = lane >> 4;
  const int b = bh / nh, h = bh % nh;
  const int s0 = blockIdx.x * 64;
  const int srow = s0 + w * 16 + lr;
  const int tok = b * kS + srow;

  const short* ip = in + ((size_t)tok * nh + h) * kD + lk * 8;
  bf16x8 raw[4];
#pragma unroll
  for (int ch = 0; ch < 4; ++ch) raw[ch] = *(const bf16x8*)(ip + ch * 32);

  bf16x8 af[4];
  if (ROPE) {
    float a[4][8];
#pragma unroll
    for (int ch = 0; ch < 4; ++ch)
#pragma unroll
      for (int i = 0; i < 8; ++i) a[ch][i] = bf2f(raw[ch][i]);
    const float* tb = tbl + (size_t)tok * 128;
    float c[2][8], sn[2][8];
#pragma unroll
    for (int g = 0; g < 2; ++g) {
      const float4 cA = *(const float4*)(tb + g * 32 + lk * 8);
      const float4 cB = *(const float4*)(tb + g * 32 + lk * 8 + 4);
      const float4 sA = *(const float4*)(tb + 64 + g * 32 + lk * 8);
      const float4 sB = *(const float4*)(tb + 64 + g * 32 + lk * 8 + 4);
      c[g][0] = cA.x; c[g][1] = cA.y; c[g][2] = cA.z; c[g][3] = cA.w;
      c[g][4] = cB.x; c[g][5] = cB.y; c[g][6] = cB.z; c[g][7] = cB.w;
      sn[g][0] = sA.x; sn[g][1] = sA.y; sn[g][2] = sA.z; sn[g][3] = sA.w;
      sn[g][4] = sB.x; sn[g][5] = sB.y; sn[g][6] = sB.z; sn[g][7] = sB.w;
    }
    float o[4][8];
#pragma unroll
    for (int g = 0; g < 2; ++g)
#pragma unroll
      for (int i = 0; i < 8; ++i) {
        o[g][i]     = a[g][i]     * c[g][i] - a[g + 2][i] * sn[g][i];
        o[g + 2][i] = a[g + 2][i] * c[g][i] + a[g][i]     * sn[g][i];
      }
#pragma unroll
    for (int ch = 0; ch < 4; ++ch)
#pragma unroll
      for (int i = 0; i < 8; ++i) af[ch][i] = f2bf(o[ch][i]);
  } else {
#pragma unroll
    for (int ch = 0; ch < 4; ++ch) af[ch] = raw[ch];
  }

  f32x4 acc[4] = {};
#pragma unroll
  for (int cb = 0; cb < 4; ++cb) {
#pragma unroll
    for (int ch = 0; ch < 4; ++ch) {
      const bf16x8 bfrag =
          *(const bf16x8*)&WT[(size_t)(cb * 16 + lr) * kD + ch * 32 + lk * 8];
      acc[cb] = __builtin_amdgcn_mfma_f32_16x16x32_bf16(af[ch], bfrag,
                                                        acc[cb], 0, 0, 0);
    }
  }

  short* T = Tw[w];
  if (!TR) {
#pragma unroll
    for (int cb = 0; cb < 4; ++cb)
#pragma unroll
      for (int r = 0; r < 4; ++r)
        T[(lk * 4 + r) * 72 + cb * 16 + lr] = f2bf(acc[cb][r]);
    asm volatile("s_waitcnt lgkmcnt(0)" ::: "memory");
#pragma unroll
    for (int it = 0; it < 2; ++it) {
      const int idx = it * 64 + lane;
      const int row = idx >> 3, c8 = (idx & 7) << 3;
      *(bf16x8*)&out[((size_t)bh * kS + s0 + w * 16 + row) * kL + c8] =
          *(const bf16x8*)&T[row * 72 + c8];
    }
  } else {
#pragma unroll
    for (int cb = 0; cb < 4; ++cb)
#pragma unroll
      for (int r = 0; r < 4; ++r)
        T[(cb * 16 + lr) * 20 + lk * 4 + r] = f2bf(acc[cb][r]);
    asm volatile("s_waitcnt lgkmcnt(0)" ::: "memory");
    const size_t orow = ((size_t)bh * kL + lane) * kS + s0 + w * 16;
#pragma unroll
    for (int c = 0; c < 4; ++c)
      *(short4*)&out[orow + c * 4] = *(const short4*)&T[lane * 20 + c * 4];
  }
}

// ---------------------------------------------------------------------------
// MFMA flash attention, causal, bf16 in/out (fp32 accumulate).
// Swapped QK^T (q lane-local), in-register P via shuffles, T13 defer-max.
// 128-KEY double-buffered K/V tiles: two 64-key compute subtiles per staged
// tile -> HALF the barriers (avg 8.5/block vs 17). One barrier per 128 keys.
// ---------------------------------------------------------------------------
__global__ __launch_bounds__(512) void flash_attn_mfma(
    const short* __restrict__ ql, const short* __restrict__ kl,
    const short* __restrict__ vlT, short* __restrict__ attn_out) {
  constexpr int LDK = 72;                      // K rows: 64 lat + 8 pad
  constexpr int LDV = 136;                     // V rows: 128 keys + 8 pad
  __shared__ short Kt[2][128 * LDK];
  __shared__ short Vt[2][64 * LDV];            // row = latent l, col = key

  const int tid = threadIdx.x;
  const int lane = tid & 63;
  const int w = tid >> 6;
  const int lr = lane & 15;
  const int lk = lane >> 4;
  const int bid = blockIdx.y;
  const int bx = (bid < 8) ? (2 * bid) : (31 - 2 * bid);   // load-balance remap
  const int q0 = bx * 128;
  const int bh = blockIdx.x;
  const int b = bh >> 4, h = bh & 15;
  const int hk = h >> 2;
  const int wrow = q0 + w * 16;

  const short* qrow = ql + ((size_t)bh * kS + wrow + lr) * kL;
  bf16x8 qf[2];
  qf[0] = *(const bf16x8*)(qrow + lk * 8);
  qf[1] = *(const bf16x8*)(qrow + 32 + lk * 8);

  f32x4 Of[4] = {};                            // O^T[l=lb*16+lk*4+r][q=lr]
  float m = -3.0e38f, l = 0.f;

  const short* kgp = kl + (size_t)(b * kHKV + hk) * kS * kL;
  const short* vgp = vlT + (size_t)(b * kHKV + hk) * kL * kS;
  const int ntiles = bx + 1;                   // 128-key tiles

  // staging coords: K chunks idx = j*512+tid -> row idx>>3 (0..127),
  // col ((idx&7)<<3); V chunks -> row idx>>4 (0..63), col ((idx&15)<<3)
  const int kr0 = tid >> 3,          kc0 = (tid & 7) << 3;
  const int kr1 = (512 + tid) >> 3,  kc1 = (tid & 7) << 3;
  const int vr0 = tid >> 4,          vc0 = (tid & 15) << 3;
  const int vr1 = (512 + tid) >> 4,  vc1 = (tid & 15) << 3;

  // prologue: stage tile 0 (keys 0..127) into buffer 0
  *(bf16x8*)&Kt[0][kr0 * LDK + kc0] = *(const bf16x8*)(kgp + (size_t)kr0 * kL + kc0);
  *(bf16x8*)&Kt[0][kr1 * LDK + kc1] = *(const bf16x8*)(kgp + (size_t)kr1 * kL + kc1);
  *(bf16x8*)&Vt[0][vr0 * LDV + vc0] = *(const bf16x8*)(vgp + (size_t)vr0 * kS + vc0);
  *(bf16x8*)&Vt[0][vr1 * LDV + vc1] = *(const bf16x8*)(vgp + (size_t)vr1 * kS + vc1);
  __syncthreads();

  const int sl0 = lr + ((lane & 16) << 1);     // lr + 32*(lk&1)
  const bool hisel = (lk >> 1) != 0;

  int cur = 0;
  for (int t = 0; t < ntiles; ++t) {
    const int j0 = t * 128;
    const bool pre = (t + 1 < ntiles);
    bf16x8 krn0, krn1, vrn0, vrn1;
    if (pre) {                                 // issue next-tile loads EARLY
      const int jn = j0 + 128;
      krn0 = *(const bf16x8*)(kgp + (size_t)(jn + kr0) * kL + kc0);
      krn1 = *(const bf16x8*)(kgp + (size_t)(jn + kr1) * kL + kc1);
      vrn0 = *(const bf16x8*)(vgp + (size_t)vr0 * kS + jn + vc0);
      vrn1 = *(const bf16x8*)(vgp + (size_t)vr1 * kS + jn + vc1);
    }

    const short* Kc = &Kt[cur][0];
    const short* Vc = &Vt[cur][0];
#pragma unroll
    for (int sub = 0; sub < 2; ++sub) {
      const int js = j0 + sub * 64;
      if (js > wrow) continue;                 // wave-uniform causal skip

      // S^T = K @ Q : Sf[cb][r] = S[key=js+cb*16+lk*4+r][q=wrow+lr]
      f32x4 Sf[4];
      __builtin_amdgcn_s_setprio(1);
#pragma unroll
      for (int cb = 0; cb < 4; ++cb) {
        f32x4 acc = {};
#pragma unroll
        for (int ch = 0; ch < 2; ++ch) {
          const bf16x8 kf = *(const bf16x8*)
              &Kc[(sub * 64 + cb * 16 + lr) * LDK + ch * 32 + lk * 8];
          acc = __builtin_amdgcn_mfma_f32_16x16x32_bf16(kf, qf[ch], acc, 0, 0, 0);
        }
        Sf[cb] = acc;
      }
      __builtin_amdgcn_s_setprio(0);

      // causal mask (diagonal subtile only) + local max
      float mt = -3.0e38f;
      if (js + 63 > wrow) {
#pragma unroll
        for (int cb = 0; cb < 4; ++cb)
#pragma unroll
          for (int r = 0; r < 4; ++r) {
            float s = Sf[cb][r];
            if ((js + cb * 16 + lk * 4 + r) > (wrow + lr)) s = -3.0e38f;
            Sf[cb][r] = s;
            mt = fmaxf(mt, s);
          }
      } else {
#pragma unroll
        for (int cb = 0; cb < 4; ++cb)
#pragma unroll
          for (int r = 0; r < 4; ++r) mt = fmaxf(mt, Sf[cb][r]);
      }
      mt = fmaxf(mt, __shfl_xor(mt, 16));
      mt = fmaxf(mt, __shfl_xor(mt, 32));

      // T13 defer-max
      const bool resc = __any((int)(mt > m + 8.f));
      if (resc) {
        const float mnew = fmaxf(m, mt);
        const float corr = __expf(m - mnew);
        m = mnew;
        l *= corr;
#pragma unroll
        for (int lb = 0; lb < 4; ++lb)
#pragma unroll
          for (int r = 0; r < 4; ++r) Of[lb][r] *= corr;
      }

      // P = exp(S - m), packed bf16 pairs per cb
      unsigned pk[4][2];
#pragma unroll
      for (int cb = 0; cb < 4; ++cb) {
        const float p0 = __expf(Sf[cb][0] - m);
        const float p1 = __expf(Sf[cb][1] - m);
        const float p2 = __expf(Sf[cb][2] - m);
        const float p3 = __expf(Sf[cb][3] - m);
        l += (p0 + p1) + (p2 + p3);
        pk[cb][0] = cvt_pk_bf16(p0, p1);
        pk[cb][1] = cvt_pk_bf16(p2, p3);
      }

      // PV: per ch, build P^T B-fragment via in-register shuffles, then MFMA
#pragma unroll
      for (int ch = 0; ch < 2; ++ch) {
        const unsigned lo00 = __shfl(pk[2 * ch][0], sl0);
        const unsigned lo01 = __shfl(pk[2 * ch][1], sl0);
        const unsigned lo10 = __shfl(pk[2 * ch][0], sl0 + 16);
        const unsigned lo11 = __shfl(pk[2 * ch][1], sl0 + 16);
        const unsigned hi00 = __shfl(pk[2 * ch + 1][0], sl0);
        const unsigned hi01 = __shfl(pk[2 * ch + 1][1], sl0);
        const unsigned hi10 = __shfl(pk[2 * ch + 1][0], sl0 + 16);
        const unsigned hi11 = __shfl(pk[2 * ch + 1][1], sl0 + 16);
        union { unsigned u[4]; bf16x8 v; } pf;
        pf.u[0] = hisel ? hi00 : lo00;
        pf.u[1] = hisel ? hi01 : lo01;
        pf.u[2] = hisel ? hi10 : lo10;
        pf.u[3] = hisel ? hi11 : lo11;
        __builtin_amdgcn_s_setprio(1);
#pragma unroll
        for (int lb = 0; lb < 4; ++lb) {
          const bf16x8 vf = *(const bf16x8*)
              &Vc[(lb * 16 + lr) * LDV + sub * 64 + ch * 32 + lk * 8];
          Of[lb] = __builtin_amdgcn_mfma_f32_16x16x32_bf16(vf, pf.v, Of[lb], 0, 0, 0);
        }
        __builtin_amdgcn_s_setprio(0);
      }
    }

    if (pre) {                                 // write-late into other buffer
      *(bf16x8*)&Kt[cur ^ 1][kr0 * LDK + kc0] = krn0;
      *(bf16x8*)&Kt[cur ^ 1][kr1 * LDK + kc1] = krn1;
      *(bf16x8*)&Vt[cur ^ 1][vr0 * LDV + vc0] = vrn0;
      *(bf16x8*)&Vt[cur ^ 1][vr1 * LDV + vc1] = vrn1;
    }
    __syncthreads();                           // ONE barrier per 128 keys
    cur ^= 1;
  }

  // final lsum reduce (over lk groups) + O^T write: 4x short4 per lane
  l += __shfl_xor(l, 16);
  l += __shfl_xor(l, 32);
  const float inv = 1.f / l;
  const size_t rowoff =
      (size_t)(b * kS + wrow + lr) * (kH * kL) + h * kL + lk * 4;
#pragma unroll
  for (int lb = 0; lb < 4; ++lb) {
    const short4 s4 = make_short4(f2bf(Of[lb][0] * inv), f2bf(Of[lb][1] * inv),
                                  f2bf(Of[lb][2] * inv), f2bf(Of[lb][3] * inv));
    *(short4*)&attn_out[rowoff + lb * 16] = s4;
  }
}

// ---------------------------------------------------------------------------
extern "C" void kernel_launch(void* const* d_in, const int* in_sizes, int n_in,
                              void* d_out, int out_size, void* d_ws, size_t ws_size,
                              hipStream_t stream) {
  const float* x    = (const float*)d_in[0];
  const int*   pos  = (const int*)d_in[1];
  const float* Wq   = (const float*)d_in[3];
  const float* Wk   = (const float*)d_in[4];
  const float* Wv   = (const float*)d_in[5];
  const float* Wql  = (const float*)d_in[6];
  const float* Wkl  = (const float*)d_in[7];
  const float* Wvl  = (const float*)d_in[8];
  const float* Wo   = (const float*)d_in[9];
  float* out = (float*)d_out;

  // Workspace carve (q_buf bf16 reuses d_out: 16 MB of its 32 MB)
  char* p = (char*)d_ws;
  short* x_bf  = (short*)p; p += (size_t)kTok * kHID * 2;        // 16 MB
  short* Wqkv  = (short*)p; p += (size_t)kNQKV * kHID * 2;       // 12.6 MB
  short* WoT   = (short*)p; p += (size_t)kHID * (kH * kL) * 2;   // 4 MB
  short* WqlT  = (short*)p; p += (size_t)kL * kD * 2;            // 16 KB
  short* WklT  = (short*)p; p += (size_t)kL * kD * 2;
  short* WvlT  = (short*)p; p += (size_t)kL * kD * 2;
  float* tbl   = (float*)p; p += (size_t)kTok * 128 * 4;         // 2 MB
  short* k_buf = (short*)p; p += (size_t)kTok * kHKV * kD * 2;   // 4 MB
  short* v_buf = (short*)p; p += (size_t)kTok * kHKV * kD * 2;   // 4 MB
  short* q_l   = (short*)p; p += (size_t)kB * kH * kS * kL * 2;  // 8 MB
  short* k_l   = (short*)p; p += (size_t)kB * kHKV * kS * kL * 2;
  short* v_lT  = (short*)p; p += (size_t)kB * kHKV * kS * kL * 2;
  short* attn  = (short*)p;                                      // 8 MB
  short* q_buf = (short*)d_out;   // bf16 scratch until final GEMM

  // 0) fused prep — one dispatch (cvt + trig + 3 weight transposes)
  prep_all<<<7174, 256, 0, stream>>>(x, pos, Wq, Wk, Wv, Wo, Wql, Wkl, Wvl,
                                     x_bf, tbl, Wqkv, WoT, WqlT, WklT, WvlT);

  // 1) Fused QKV projection — 256² 2-deep counted-vmcnt, register-blocked
  gemm_qkv8<<<dim3(kNQKV / 256, kTok / 256), 512, 0, stream>>>(
      x_bf, Wqkv, q_buf, k_buf, v_buf, kHID);

  // 2) Fused RoPE + latent projections — single dispatch
  rope_latent_all<<<dim3(kS / 64, 48), 256, 0, stream>>>(
      q_buf, k_buf, v_buf, WqlT, WklT, WvlT, tbl, q_l, k_l, v_lT);

  // 3) MFMA flash attention (swapped QK^T, 128-key dbuf tiles)
  flash_attn_mfma<<<dim3(kB * kH, kS / 128), 512, 0, stream>>>(
      q_l, k_l, v_lT, attn);

  // 4) Output GEMM — 256x128 2-deep, 256 blocks = 1/CU, fp32 out
  gemm_out8<<<dim3(kHID / 128, kTok / 256), 512, 0, stream>>>(
      attn, WoT, out, kTok, kHID, kH * kL);
}